// Round 1
// baseline (696.704 us; speedup 1.0000x reference)
//
#include <hip/hip_runtime.h>
#include <hip/hip_bf16.h>

// FactoredHmmLm forward on MI355X.
// Pipeline:
//  1. emb + residual MLPs (bf16 MFMA GEMMs, 8192x256x256) -> sh, x, nse, ph
//  2. start head logits + full-8192 logsumexp
//  3. transition row-logsumexp: streaming 8192x8192x256 GEMM (no 268MB matrix)
//  4. emission: CSR cluster->words, per-state masked lse + all (word,state) logits
//  5. per-(n,t) 64x64 linear-domain step matrices A = exp(tr + emit - m), bf16, transposed
//  6. 16-block serial scan in linear domain with running log-offset

using u16 = unsigned short;
typedef __attribute__((ext_vector_type(8))) short bh8;     // 8 bf16 (4 VGPRs)
typedef __attribute__((ext_vector_type(4))) float f32x4;
typedef __attribute__((ext_vector_type(8))) unsigned short u16x8;

#define HD 256
#define TT 256
#define NB 16
#define KCL 128
#define CS 8192
#define VV 10000

__device__ __forceinline__ u16 f2bf(float v) {
  union { float f; unsigned int i; } u; u.f = v;
  unsigned int r = u.i + 0x7fffu + ((u.i >> 16) & 1u);   // RNE
  return (u16)(r >> 16);
}
__device__ __forceinline__ float bf2f(u16 u) {
  union { unsigned int i; float f; } x; x.i = ((unsigned int)u) << 16; return x.f;
}

// ---------------- small utility kernels ----------------

__global__ void cvt_k(const float* __restrict__ src, u16* __restrict__ dst, int n) {
  int i = blockIdx.x * 256 + threadIdx.x;
  if (i < n) dst[i] = f2bf(src[i]);
}

// E[k*64+s][h] = ec[k][h] + es[s][h]; writes f32 + bf16
__global__ void emb_k(const float* __restrict__ ec, const float* __restrict__ es,
                      float* __restrict__ ef, u16* __restrict__ ebf) {
  int idx = blockIdx.x * 256 + threadIdx.x;   // CS*HD total
  int h = idx & 255, row = idx >> 8;
  int k = row >> 6, s = row & 63;
  float v = ec[k * HD + h] + es[s * HD + h];
  ef[idx] = v;
  ebf[idx] = f2bf(v);
}

__global__ void log_k(const float* __restrict__ in, float* __restrict__ out, int n) {
  int i = blockIdx.x * 256 + threadIdx.x;
  if (i < n) out[i] = logf(in[i]);
}

// ---------------- CSR: cluster -> word list ----------------

__global__ void count_k(const int* __restrict__ w2c, int* __restrict__ counts) {
  int w = blockIdx.x * 256 + threadIdx.x;
  if (w < VV) atomicAdd(&counts[w2c[w]], 1);
}
__global__ void csr_scan_k(const int* __restrict__ counts, int* __restrict__ offs,
                           int* __restrict__ curs) {
  if (threadIdx.x == 0) {
    int acc = 0;
    for (int c = 0; c < KCL; ++c) { offs[c] = acc; curs[c] = acc; acc += counts[c]; }
    offs[KCL] = acc;
  }
}
__global__ void fill_k(const int* __restrict__ w2c, int* __restrict__ curs,
                       int* __restrict__ wlist) {
  int w = blockIdx.x * 256 + threadIdx.x;
  if (w < VV) { int p = atomicAdd(&curs[w2c[w]], 1); wlist[p] = w; }
}

// ---------------- MFMA GEMM: C[m,n] = sum_k A[m,k]*B[n,k], 64x64 tile ----------------
// MODE 0: out = relu(acc + bias[n] (+ skip[m*256+n])) -> f32 and/or bf16
// MODE 1: row_sumexp[m] += sum_n exp(acc)  (transition row-lse partials)
// MODE 2: per-(n,t) block: A_lin = exp(acc - row_lse[m] + emit[n,t,j] - max), store bf16 transposed

template<int MODE>
__global__ __launch_bounds__(256) void gemm64(
    const u16* __restrict__ A, const u16* __restrict__ B,
    int M, int N, int K,
    const float* __restrict__ bias, const float* __restrict__ skip,
    float* __restrict__ outf, u16* __restrict__ outbf,
    float* __restrict__ row_sumexp,
    const float* __restrict__ row_lse, const float* __restrict__ emitb,
    const int* __restrict__ text, const int* __restrict__ w2c,
    u16* __restrict__ At, float* __restrict__ Ascale) {
  __shared__ char lds[16384];
  __shared__ float wmax[4];
  const int tid = threadIdx.x;
  const int lane = tid & 63;
  const int wid = tid >> 6;

  int rm, cn, bi = 0, nn = 0, ttv = 0;
  if (MODE == 2) {
    bi = blockIdx.x;
    nn = bi / (TT - 1);
    ttv = bi % (TT - 1) + 1;
    const int wp = text[nn * TT + ttv - 1];
    const int wc = text[nn * TT + ttv];
    rm = w2c[wp] * 64;
    cn = w2c[wc] * 64;
  } else {
    rm = blockIdx.y * 64;
    cn = blockIdx.x * 64;
  }
  const u16* Ag = A + (size_t)rm * K;
  const u16* Bg = B + (size_t)cn * K;

  f32x4 acc[4];
#pragma unroll
  for (int i = 0; i < 4; ++i) acc[i] = (f32x4){0.f, 0.f, 0.f, 0.f};

  const int sr = tid >> 3;          // staging row 0..31 (+32 for rep 1)
  const int scb = (tid & 7) * 16;   // staging byte-col within 128B row
  const int ra = wid * 16 + (lane & 15);
  const int rb0 = lane & 15;
  const int ko = (lane >> 4) * 8;   // fragment k-offset (elements)

  for (int kc = 0; kc < K; kc += 64) {
#pragma unroll
    for (int rep = 0; rep < 2; ++rep) {
      const int r = rep * 32 + sr;
      const bh8 va = *reinterpret_cast<const bh8*>(Ag + r * K + kc + (scb >> 1));
      *reinterpret_cast<bh8*>(&lds[r * 128 + (scb ^ ((r & 7) << 4))]) = va;
      const bh8 vb = *reinterpret_cast<const bh8*>(Bg + r * K + kc + (scb >> 1));
      *reinterpret_cast<bh8*>(&lds[8192 + r * 128 + (scb ^ ((r & 7) << 4))]) = vb;
    }
    __syncthreads();
#pragma unroll
    for (int kk = 0; kk < 64; kk += 32) {
      const int kb = (kk + ko) * 2;
      const bh8 af = *reinterpret_cast<const bh8*>(&lds[ra * 128 + (kb ^ ((ra & 7) << 4))]);
#pragma unroll
      for (int nj = 0; nj < 4; ++nj) {
        const int rb = nj * 16 + rb0;
        const bh8 bf = *reinterpret_cast<const bh8*>(&lds[8192 + rb * 128 + (kb ^ ((rb & 7) << 4))]);
        acc[nj] = __builtin_amdgcn_mfma_f32_16x16x32_bf16(af, bf, acc[nj], 0, 0, 0);
      }
    }
    __syncthreads();
  }

  // epilogues; C/D frag: col = lane&15, row = (lane>>4)*4 + reg
  const int g = lane >> 4, c0 = lane & 15;

  if (MODE == 0) {
#pragma unroll
    for (int nj = 0; nj < 4; ++nj) {
      const int nidx = cn + nj * 16 + c0;
      const float bv = bias ? bias[nidx] : 0.f;
#pragma unroll
      for (int reg = 0; reg < 4; ++reg) {
        const int midx = rm + wid * 16 + g * 4 + reg;
        float v = acc[nj][reg] + bv;
        if (skip) v += skip[(size_t)midx * 256 + nidx];
        v = fmaxf(v, 0.f);
        if (outf) outf[(size_t)midx * N + nidx] = v;
        if (outbf) outbf[(size_t)midx * N + nidx] = f2bf(v);
      }
    }
  } else if (MODE == 1) {
    float rs[4] = {0.f, 0.f, 0.f, 0.f};
#pragma unroll
    for (int nj = 0; nj < 4; ++nj)
#pragma unroll
      for (int reg = 0; reg < 4; ++reg)
        rs[reg] += expf(acc[nj][reg]);
#pragma unroll
    for (int off = 1; off < 16; off <<= 1)
#pragma unroll
      for (int reg = 0; reg < 4; ++reg)
        rs[reg] += __shfl_xor(rs[reg], off, 64);
    if (c0 == 0) {
#pragma unroll
      for (int reg = 0; reg < 4; ++reg)
        atomicAdd(&row_sumexp[rm + wid * 16 + g * 4 + reg], rs[reg]);
    }
  } else {  // MODE 2
    float L[4][4];
    float mx = -1e30f;
#pragma unroll
    for (int nj = 0; nj < 4; ++nj) {
      const float ev = emitb[((size_t)(nn * TT + ttv)) * 64 + nj * 16 + c0];
#pragma unroll
      for (int reg = 0; reg < 4; ++reg) {
        const float l = acc[nj][reg] - row_lse[rm + wid * 16 + g * 4 + reg] + ev;
        L[nj][reg] = l;
        mx = fmaxf(mx, l);
      }
    }
#pragma unroll
    for (int off = 1; off < 64; off <<= 1) mx = fmaxf(mx, __shfl_xor(mx, off, 64));
    if (lane == 0) wmax[wid] = mx;
    __syncthreads();
    const float m = fmaxf(fmaxf(wmax[0], wmax[1]), fmaxf(wmax[2], wmax[3]));
    float* ftile = reinterpret_cast<float*>(lds);
#pragma unroll
    for (int nj = 0; nj < 4; ++nj)
#pragma unroll
      for (int reg = 0; reg < 4; ++reg)
        ftile[(wid * 16 + g * 4 + reg) * 64 + nj * 16 + c0] = expf(L[nj][reg] - m);
    __syncthreads();
    // transposed bf16 store: At[bi*4096 + j*64 + i] = A_lin[i][j]
    const int jj = tid >> 2;
    const int ib0 = (tid & 3) * 16;
    u16x8 o0, o1;
#pragma unroll
    for (int ii = 0; ii < 8; ++ii) o0[ii] = f2bf(ftile[(ib0 + ii) * 64 + jj]);
#pragma unroll
    for (int ii = 0; ii < 8; ++ii) o1[ii] = f2bf(ftile[(ib0 + 8 + ii) * 64 + jj]);
    u16* dst = At + (size_t)bi * 4096 + jj * 64 + ib0;
    *reinterpret_cast<u16x8*>(dst) = o0;
    *reinterpret_cast<u16x8*>(dst + 8) = o1;
    if (tid == 0) Ascale[bi] = m;
  }
}

// ---------------- start head ----------------

__global__ __launch_bounds__(256) void head_dot_k(const float* __restrict__ sh,
                                                  const float* __restrict__ wv,
                                                  const float* __restrict__ bv,
                                                  float* __restrict__ logits) {
  const int tid = threadIdx.x, lane = tid & 63, wid = tid >> 6;
  const int row = blockIdx.x * 4 + wid;
  float s = 0.f;
#pragma unroll
  for (int q = 0; q < 4; ++q)
    s += sh[(size_t)row * HD + q * 64 + lane] * wv[q * 64 + lane];
  for (int off = 32; off; off >>= 1) s += __shfl_xor(s, off, 64);
  if (lane == 0) logits[row] = s + bv[0];
}

__global__ __launch_bounds__(1024) void head_lse_k(const float* __restrict__ logits,
                                                   float* __restrict__ out_lse) {
  __shared__ float red[16];
  __shared__ float mshared;
  const int tid = threadIdx.x;
  float m = -1e30f;
  for (int i = tid; i < CS; i += 1024) m = fmaxf(m, logits[i]);
  for (int off = 32; off; off >>= 1) m = fmaxf(m, __shfl_xor(m, off, 64));
  if ((tid & 63) == 0) red[tid >> 6] = m;
  __syncthreads();
  if (tid == 0) {
    float x = red[0];
    for (int i = 1; i < 16; ++i) x = fmaxf(x, red[i]);
    mshared = x;
  }
  __syncthreads();
  const float M = mshared;
  float s = 0.f;
  for (int i = tid; i < CS; i += 1024) s += expf(logits[i] - M);
  for (int off = 32; off; off >>= 1) s += __shfl_xor(s, off, 64);
  if ((tid & 63) == 0) red[tid >> 6] = s;
  __syncthreads();
  if (tid == 0) {
    float x = 0.f;
    for (int i = 0; i < 16; ++i) x += red[i];
    out_lse[0] = M + logf(x);
  }
}

// ---------------- emission: per-cluster masked lse + all (word,state) logits ----------------
// block c: 256 threads, thread (s = tid>>2, q = tid&3) keeps ph[c*64+s][q*64..+64] in regs.

__global__ __launch_bounds__(256) void term_k(const float* __restrict__ ph,
                                              const float* __restrict__ Wp,
                                              const float* __restrict__ bp,
                                              const int* __restrict__ offs,
                                              const int* __restrict__ wlist,
                                              float* __restrict__ lse_term,
                                              float* __restrict__ logits_all) {
  const int c = blockIdx.x, tid = threadIdx.x;
  const int s = tid >> 2, q = tid & 3;
  float pr[64];
  const float* src = ph + ((size_t)(c * 64 + s)) * HD + q * 64;
#pragma unroll
  for (int k = 0; k < 64; k += 4) {
    float4 v = *reinterpret_cast<const float4*>(src + k);
    pr[k] = v.x; pr[k + 1] = v.y; pr[k + 2] = v.z; pr[k + 3] = v.w;
  }
  const int st = offs[c], en = offs[c + 1];
  float acc_sum = 0.f;
  for (int kk = st; kk < en; ++kk) {
    const int wd = wlist[kk];
    const float* wr = Wp + (size_t)wd * HD + q * 64;
    float d = 0.f;
#pragma unroll
    for (int k = 0; k < 64; k += 4) {
      float4 wv = *reinterpret_cast<const float4*>(wr + k);
      d += wv.x * pr[k] + wv.y * pr[k + 1] + wv.z * pr[k + 2] + wv.w * pr[k + 3];
    }
    d += __shfl_xor(d, 1, 64);
    d += __shfl_xor(d, 2, 64);
    if (q == 0) {
      const float lg = d + bp[wd];
      logits_all[(size_t)wd * 64 + s] = lg;
      acc_sum += expf(lg);
    }
  }
  if (q == 0) lse_term[c * 64 + s] = logf(acc_sum);
}

__global__ void emit_k(const int* __restrict__ text, const int* __restrict__ w2c,
                       const float* __restrict__ lall, const float* __restrict__ lterm,
                       float* __restrict__ emitb) {
  const int idx = blockIdx.x * 256 + threadIdx.x;  // NB*TT*64
  const int s = idx & 63, nt = idx >> 6;
  const int w = text[nt];
  emitb[idx] = lall[(size_t)w * 64 + s] - lterm[w2c[w] * 64 + s];
}

// ---------------- forward scan (linear domain, per-step renorm) ----------------

__global__ __launch_bounds__(64) void scan_k(const u16* __restrict__ At,
                                             const float* __restrict__ Ascale,
                                             const float* __restrict__ hlog,
                                             const float* __restrict__ hlse,
                                             const float* __restrict__ emitb,
                                             const int* __restrict__ text,
                                             const int* __restrict__ w2c,
                                             float* __restrict__ out) {
  const int n = blockIdx.x, j = threadIdx.x;
  __shared__ float alpha[64];
  const int w0 = text[n * TT];
  float a0 = hlog[w2c[w0] * 64 + j] - hlse[0] + emitb[((size_t)(n * TT)) * 64 + j];
  float m = a0;
  for (int off = 32; off; off >>= 1) m = fmaxf(m, __shfl_xor(m, off, 64));
  const float lin = expf(a0 - m);
  float tot = lin;
  for (int off = 32; off; off >>= 1) tot += __shfl_xor(tot, off, 64);
  alpha[j] = lin / tot;
  float log_off = m + logf(tot);

  const u16* Ab = At + (size_t)n * (TT - 1) * 4096;
  u16x8 cur[8];
  {
    const u16x8* rp = reinterpret_cast<const u16x8*>(Ab + j * 64);
#pragma unroll
    for (int ib = 0; ib < 8; ++ib) cur[ib] = rp[ib];
  }
  __syncthreads();

  for (int t = 1; t < TT; ++t) {
    u16x8 nxt[8];
    if (t < TT - 1) {
      const u16x8* rp = reinterpret_cast<const u16x8*>(Ab + (size_t)t * 4096 + j * 64);
#pragma unroll
      for (int ib = 0; ib < 8; ++ib) nxt[ib] = rp[ib];
    }
    float s = 0.f;
#pragma unroll
    for (int ib = 0; ib < 8; ++ib) {
#pragma unroll
      for (int e = 0; e < 8; ++e)
        s += alpha[ib * 8 + e] * bf2f(cur[ib][e]);
    }
    float tot2 = s;
    for (int off = 32; off; off >>= 1) tot2 += __shfl_xor(tot2, off, 64);
    log_off += Ascale[n * (TT - 1) + t - 1] + logf(tot2);
    __syncthreads();
    alpha[j] = s / tot2;
    __syncthreads();
    if (t < TT - 1) {
#pragma unroll
      for (int ib = 0; ib < 8; ++ib) cur[ib] = nxt[ib];
    }
  }
  if (j == 0) out[n] = log_off;
}

// ---------------- host orchestration ----------------

extern "C" void kernel_launch(void* const* d_in, const int* in_sizes, int n_in,
                              void* d_out, int out_size, void* d_ws, size_t ws_size,
                              hipStream_t stream) {
  (void)in_sizes; (void)n_in; (void)out_size; (void)ws_size;
  const int* text = (const int*)d_in[0];
  const int* w2c  = (const int*)d_in[1];
  const float* sec = (const float*)d_in[2];
  const float* ses = (const float*)d_in[3];
  const float* stc = (const float*)d_in[4];
  const float* sts = (const float*)d_in[5];
  const float* nec = (const float*)d_in[6];
  const float* nes = (const float*)d_in[7];
  const float* pec = (const float*)d_in[8];
  const float* pes = (const float*)d_in[9];
  const float* srw1 = (const float*)d_in[10];
  const float* srb1 = (const float*)d_in[11];
  const float* srw2 = (const float*)d_in[12];
  const float* srb2 = (const float*)d_in[13];
  const float* trw1 = (const float*)d_in[14];
  const float* trb1 = (const float*)d_in[15];
  const float* trw2 = (const float*)d_in[16];
  const float* trb2 = (const float*)d_in[17];
  const float* tew1 = (const float*)d_in[18];
  const float* teb1 = (const float*)d_in[19];
  const float* tew2 = (const float*)d_in[20];
  const float* teb2 = (const float*)d_in[21];
  const float* sow = (const float*)d_in[22];
  const float* sob = (const float*)d_in[23];
  const float* tpw = (const float*)d_in[24];
  const float* tpb = (const float*)d_in[25];
  float* out = (float*)d_out;

  char* p = (char*)d_ws;
  auto carve = [&](size_t bytes) -> char* {
    char* r = p; p += (bytes + 255) & ~(size_t)255; return r;
  };
  float* Ef   = (float*)carve((size_t)CS * HD * 4);
  u16*   Ebf  = (u16*)  carve((size_t)CS * HD * 2);
  u16*   Hbf  = (u16*)  carve((size_t)CS * HD * 2);
  float* SHf  = (float*)carve((size_t)CS * HD * 4);
  u16*   Xbf  = (u16*)  carve((size_t)CS * HD * 2);
  u16*   NSEb = (u16*)  carve((size_t)CS * HD * 2);
  float* PHf  = (float*)carve((size_t)CS * HD * 4);
  u16*   Wb[6];
  for (int i = 0; i < 6; ++i) Wb[i] = (u16*)carve((size_t)HD * HD * 2);
  float* hlog  = (float*)carve(CS * 4);
  float* hlse  = (float*)carve(256);
  float* rsum  = (float*)carve(CS * 4);
  float* rlse  = (float*)carve(CS * 4);
  int* counts  = (int*)carve(KCL * 4);
  int* offs    = (int*)carve((KCL + 1) * 4);
  int* curs    = (int*)carve(KCL * 4);
  int* wlist   = (int*)carve(VV * 4);
  float* lterm = (float*)carve(CS * 4);
  float* lall  = (float*)carve((size_t)VV * 64 * 4);
  float* emitb = (float*)carve((size_t)NB * TT * 64 * 4);
  u16*   At    = (u16*)carve((size_t)NB * (TT - 1) * 4096 * 2);
  float* Asc   = (float*)carve((size_t)NB * (TT - 1) * 4);

  hipMemsetAsync(rsum, 0, CS * 4, stream);
  hipMemsetAsync(counts, 0, KCL * 4, stream);

  // weight conversions
  const float* wsrc[6] = {srw1, srw2, trw1, trw2, tew1, tew2};
  for (int i = 0; i < 6; ++i)
    cvt_k<<<(HD * HD + 255) / 256, 256, 0, stream>>>(wsrc[i], Wb[i], HD * HD);

  // CSR cluster->words
  count_k<<<(VV + 255) / 256, 256, 0, stream>>>(w2c, counts);
  csr_scan_k<<<1, 64, 0, stream>>>(counts, offs, curs);
  fill_k<<<(VV + 255) / 256, 256, 0, stream>>>(w2c, curs, wlist);

  const dim3 gMLP(4, 128);

  // start: sh = residual(emb) ; head logits ; lse
  emb_k<<<CS * HD / 256, 256, 0, stream>>>(sec, ses, Ef, Ebf);
  gemm64<0><<<gMLP, 256, 0, stream>>>(Ebf, Wb[0], CS, HD, HD, srb1, nullptr,
      nullptr, Hbf, nullptr, nullptr, nullptr, nullptr, nullptr, nullptr, nullptr);
  gemm64<0><<<gMLP, 256, 0, stream>>>(Hbf, Wb[1], CS, HD, HD, srb2, Ef,
      SHf, nullptr, nullptr, nullptr, nullptr, nullptr, nullptr, nullptr, nullptr);
  head_dot_k<<<CS / 4, 256, 0, stream>>>(SHf, sow, sob, hlog);
  head_lse_k<<<1, 1024, 0, stream>>>(hlog, hlse);

  // trans: x = residual(emb(state)); nse = emb(next)
  emb_k<<<CS * HD / 256, 256, 0, stream>>>(stc, sts, Ef, Ebf);
  gemm64<0><<<gMLP, 256, 0, stream>>>(Ebf, Wb[2], CS, HD, HD, trb1, nullptr,
      nullptr, Hbf, nullptr, nullptr, nullptr, nullptr, nullptr, nullptr, nullptr);
  gemm64<0><<<gMLP, 256, 0, stream>>>(Hbf, Wb[3], CS, HD, HD, trb2, Ef,
      nullptr, Xbf, nullptr, nullptr, nullptr, nullptr, nullptr, nullptr, nullptr);
  emb_k<<<CS * HD / 256, 256, 0, stream>>>(nec, nes, Ef, NSEb);  // Ef is scratch here

  // term: ph = residual(emb(pre))
  emb_k<<<CS * HD / 256, 256, 0, stream>>>(pec, pes, Ef, Ebf);
  gemm64<0><<<gMLP, 256, 0, stream>>>(Ebf, Wb[4], CS, HD, HD, teb1, nullptr,
      nullptr, Hbf, nullptr, nullptr, nullptr, nullptr, nullptr, nullptr, nullptr);
  gemm64<0><<<gMLP, 256, 0, stream>>>(Hbf, Wb[5], CS, HD, HD, teb2, Ef,
      PHf, nullptr, nullptr, nullptr, nullptr, nullptr, nullptr, nullptr, nullptr);

  // transition row-logsumexp (streaming 8192x8192x256)
  gemm64<1><<<dim3(128, 128), 256, 0, stream>>>(Xbf, NSEb, CS, CS, HD, nullptr,
      nullptr, nullptr, nullptr, rsum, nullptr, nullptr, nullptr, nullptr, nullptr, nullptr);
  log_k<<<CS / 256, 256, 0, stream>>>(rsum, rlse, CS);

  // emission
  term_k<<<KCL, 256, 0, stream>>>(PHf, tpw, tpb, offs, wlist, lterm, lall);
  emit_k<<<NB * TT * 64 / 256, 256, 0, stream>>>(text, w2c, lall, lterm, emitb);

  // per-(n,t) linear-domain step matrices
  gemm64<2><<<dim3(NB * (TT - 1)), 256, 0, stream>>>(Xbf, NSEb, CS, CS, HD, nullptr,
      nullptr, nullptr, nullptr, nullptr, rlse, emitb, text, w2c, At, Asc);

  // sequential forward scan
  scan_k<<<NB, 64, 0, stream>>>(At, Asc, hlog, hlse, emitb, text, w2c, out);
}

// Round 2
// 523.802 us; speedup vs baseline: 1.3301x; 1.3301x over previous
//
#include <hip/hip_runtime.h>
#include <hip/hip_bf16.h>

// FactoredHmmLm forward on MI355X.
// Pipeline:
//  1. emb + residual MLPs (bf16 MFMA GEMMs, 8192x256x256) -> sh, x, nse, ph
//  2. start head logits + full-8192 logsumexp
//  3. transition row-logsumexp: streaming 8192x8192x256 GEMM (no 268MB matrix)
//  4. emission: CSR cluster->words, MFMA 64x64 tiles (gathered Wp rows) + atomic exp-sum lse
//  5. per-(n,t) 64x64 linear-domain step matrices A = exp(tr + emit - m), bf16, transposed
//  6. 16-block serial scan in linear domain with running log-offset

using u16 = unsigned short;
typedef __attribute__((ext_vector_type(8))) short bh8;     // 8 bf16 (4 VGPRs)
typedef __attribute__((ext_vector_type(4))) float f32x4;
typedef __attribute__((ext_vector_type(8))) unsigned short u16x8;

#define HD 256
#define TT 256
#define NB 16
#define KCL 128
#define CS 8192
#define VV 10000
#define MAXB 320   // >= sum_c ceil(cnt_c/64) <= 10000/64 + 128 = 283

__device__ __forceinline__ u16 f2bf(float v) {
  union { float f; unsigned int i; } u; u.f = v;
  unsigned int r = u.i + 0x7fffu + ((u.i >> 16) & 1u);   // RNE
  return (u16)(r >> 16);
}
__device__ __forceinline__ float bf2f(u16 u) {
  union { unsigned int i; float f; } x; x.i = ((unsigned int)u) << 16; return x.f;
}

// ---------------- small utility kernels ----------------

__global__ void cvt_k(const float* __restrict__ src, u16* __restrict__ dst, int n) {
  int i = blockIdx.x * 256 + threadIdx.x;
  if (i < n) dst[i] = f2bf(src[i]);
}

// E[k*64+s][h] = ec[k][h] + es[s][h]; writes f32 + bf16
__global__ void emb_k(const float* __restrict__ ec, const float* __restrict__ es,
                      float* __restrict__ ef, u16* __restrict__ ebf) {
  int idx = blockIdx.x * 256 + threadIdx.x;   // CS*HD total
  int h = idx & 255, row = idx >> 8;
  int k = row >> 6, s = row & 63;
  float v = ec[k * HD + h] + es[s * HD + h];
  ef[idx] = v;
  ebf[idx] = f2bf(v);
}

__global__ void log_k(const float* __restrict__ in, float* __restrict__ out, int n) {
  int i = blockIdx.x * 256 + threadIdx.x;
  if (i < n) out[i] = logf(in[i]);
}

// ---------------- CSR: cluster -> word list ----------------

__global__ void count_k(const int* __restrict__ w2c, int* __restrict__ counts) {
  int w = blockIdx.x * 256 + threadIdx.x;
  if (w < VV) atomicAdd(&counts[w2c[w]], 1);
}
__global__ void csr_scan_k(const int* __restrict__ counts, int* __restrict__ offs,
                           int* __restrict__ curs) {
  if (threadIdx.x == 0) {
    int acc = 0;
    for (int c = 0; c < KCL; ++c) { offs[c] = acc; curs[c] = acc; acc += counts[c]; }
    offs[KCL] = acc;
  }
}
__global__ void fill_k(const int* __restrict__ w2c, int* __restrict__ curs,
                       int* __restrict__ wlist) {
  int w = blockIdx.x * 256 + threadIdx.x;
  if (w < VV) { int p = atomicAdd(&curs[w2c[w]], 1); wlist[p] = w; }
}
// block list: entry = (c<<8)|blk_within_cluster, -1 past end
__global__ void map_k(const int* __restrict__ offs, int* __restrict__ map) {
  if (threadIdx.x == 0) {
    int idx = 0;
    for (int c = 0; c < KCL; ++c) {
      int nb = (offs[c + 1] - offs[c] + 63) >> 6;
      for (int b = 0; b < nb; ++b) map[idx++] = (c << 8) | b;
    }
    for (; idx < MAXB; ++idx) map[idx] = -1;
  }
}

// ---------------- MFMA GEMM: C[m,n] = sum_k A[m,k]*B[n,k], 64x64 tile ----------------
// MODE 0: out = relu(acc + bias[n] (+ skip[m*256+n])) -> f32 and/or bf16
// MODE 1: row_sumexp[m] += sum_n exp(acc)  (transition row-lse partials)
// MODE 2: per-(n,t) block: A_lin = exp(acc - row_lse[m] + emit[n,t,j] - max), store bf16 transposed

template<int MODE>
__global__ __launch_bounds__(256) void gemm64(
    const u16* __restrict__ A, const u16* __restrict__ B,
    int M, int N, int K,
    const float* __restrict__ bias, const float* __restrict__ skip,
    float* __restrict__ outf, u16* __restrict__ outbf,
    float* __restrict__ row_sumexp,
    const float* __restrict__ row_lse, const float* __restrict__ emitb,
    const int* __restrict__ text, const int* __restrict__ w2c,
    u16* __restrict__ At, float* __restrict__ Ascale) {
  __shared__ char lds[16384];
  __shared__ float wmax[4];
  const int tid = threadIdx.x;
  const int lane = tid & 63;
  const int wid = tid >> 6;

  int rm, cn, bi = 0, nn = 0, ttv = 0;
  if (MODE == 2) {
    bi = blockIdx.x;
    nn = bi / (TT - 1);
    ttv = bi % (TT - 1) + 1;
    const int wp = text[nn * TT + ttv - 1];
    const int wc = text[nn * TT + ttv];
    rm = w2c[wp] * 64;
    cn = w2c[wc] * 64;
  } else {
    rm = blockIdx.y * 64;
    cn = blockIdx.x * 64;
  }
  const u16* Ag = A + (size_t)rm * K;
  const u16* Bg = B + (size_t)cn * K;

  f32x4 acc[4];
#pragma unroll
  for (int i = 0; i < 4; ++i) acc[i] = (f32x4){0.f, 0.f, 0.f, 0.f};

  const int sr = tid >> 3;          // staging row 0..31 (+32 for rep 1)
  const int scb = (tid & 7) * 16;   // staging byte-col within 128B row
  const int ra = wid * 16 + (lane & 15);
  const int rb0 = lane & 15;
  const int ko = (lane >> 4) * 8;   // fragment k-offset (elements)

  for (int kc = 0; kc < K; kc += 64) {
#pragma unroll
    for (int rep = 0; rep < 2; ++rep) {
      const int r = rep * 32 + sr;
      const bh8 va = *reinterpret_cast<const bh8*>(Ag + r * K + kc + (scb >> 1));
      *reinterpret_cast<bh8*>(&lds[r * 128 + (scb ^ ((r & 7) << 4))]) = va;
      const bh8 vb = *reinterpret_cast<const bh8*>(Bg + r * K + kc + (scb >> 1));
      *reinterpret_cast<bh8*>(&lds[8192 + r * 128 + (scb ^ ((r & 7) << 4))]) = vb;
    }
    __syncthreads();
#pragma unroll
    for (int kk = 0; kk < 64; kk += 32) {
      const int kb = (kk + ko) * 2;
      const bh8 af = *reinterpret_cast<const bh8*>(&lds[ra * 128 + (kb ^ ((ra & 7) << 4))]);
#pragma unroll
      for (int nj = 0; nj < 4; ++nj) {
        const int rb = nj * 16 + rb0;
        const bh8 bf = *reinterpret_cast<const bh8*>(&lds[8192 + rb * 128 + (kb ^ ((rb & 7) << 4))]);
        acc[nj] = __builtin_amdgcn_mfma_f32_16x16x32_bf16(af, bf, acc[nj], 0, 0, 0);
      }
    }
    __syncthreads();
  }

  // epilogues; C/D frag: col = lane&15, row = (lane>>4)*4 + reg
  const int g = lane >> 4, c0 = lane & 15;

  if (MODE == 0) {
#pragma unroll
    for (int nj = 0; nj < 4; ++nj) {
      const int nidx = cn + nj * 16 + c0;
      const float bv = bias ? bias[nidx] : 0.f;
#pragma unroll
      for (int reg = 0; reg < 4; ++reg) {
        const int midx = rm + wid * 16 + g * 4 + reg;
        float v = acc[nj][reg] + bv;
        if (skip) v += skip[(size_t)midx * 256 + nidx];
        v = fmaxf(v, 0.f);
        if (outf) outf[(size_t)midx * N + nidx] = v;
        if (outbf) outbf[(size_t)midx * N + nidx] = f2bf(v);
      }
    }
  } else if (MODE == 1) {
    float rs[4] = {0.f, 0.f, 0.f, 0.f};
#pragma unroll
    for (int nj = 0; nj < 4; ++nj)
#pragma unroll
      for (int reg = 0; reg < 4; ++reg)
        rs[reg] += expf(acc[nj][reg]);
#pragma unroll
    for (int off = 1; off < 16; off <<= 1)
#pragma unroll
      for (int reg = 0; reg < 4; ++reg)
        rs[reg] += __shfl_xor(rs[reg], off, 64);
    if (c0 == 0) {
#pragma unroll
      for (int reg = 0; reg < 4; ++reg)
        atomicAdd(&row_sumexp[rm + wid * 16 + g * 4 + reg], rs[reg]);
    }
  } else {  // MODE 2
    float L[4][4];
    float mx = -1e30f;
#pragma unroll
    for (int nj = 0; nj < 4; ++nj) {
      const float ev = emitb[((size_t)(nn * TT + ttv)) * 64 + nj * 16 + c0];
#pragma unroll
      for (int reg = 0; reg < 4; ++reg) {
        const float l = acc[nj][reg] - row_lse[rm + wid * 16 + g * 4 + reg] + ev;
        L[nj][reg] = l;
        mx = fmaxf(mx, l);
      }
    }
#pragma unroll
    for (int off = 1; off < 64; off <<= 1) mx = fmaxf(mx, __shfl_xor(mx, off, 64));
    if (lane == 0) wmax[wid] = mx;
    __syncthreads();
    const float m = fmaxf(fmaxf(wmax[0], wmax[1]), fmaxf(wmax[2], wmax[3]));
    float* ftile = reinterpret_cast<float*>(lds);
#pragma unroll
    for (int nj = 0; nj < 4; ++nj)
#pragma unroll
      for (int reg = 0; reg < 4; ++reg)
        ftile[(wid * 16 + g * 4 + reg) * 64 + nj * 16 + c0] = expf(L[nj][reg] - m);
    __syncthreads();
    // transposed bf16 store: At[bi*4096 + j*64 + i] = A_lin[i][j]
    const int jj = tid >> 2;
    const int ib0 = (tid & 3) * 16;
    u16x8 o0, o1;
#pragma unroll
    for (int ii = 0; ii < 8; ++ii) o0[ii] = f2bf(ftile[(ib0 + ii) * 64 + jj]);
#pragma unroll
    for (int ii = 0; ii < 8; ++ii) o1[ii] = f2bf(ftile[(ib0 + 8 + ii) * 64 + jj]);
    u16* dst = At + (size_t)bi * 4096 + jj * 64 + ib0;
    *reinterpret_cast<u16x8*>(dst) = o0;
    *reinterpret_cast<u16x8*>(dst + 8) = o1;
    if (tid == 0) Ascale[bi] = m;
  }
}

// ---------------- emission GEMM: per 64-word block of a cluster ----------------
// block b -> (c, blk). A rows: gathered Wp[wlist[offs[c]+blk*64+r]] (bf16),
// B rows: ph[c*64 .. +64) (bf16). logit = acc + bp[w]; write logits_all[w*64+s],
// atomicAdd exp(logit) into esum[c*64+s].

__global__ __launch_bounds__(256) void emis_k(
    const u16* __restrict__ Wpb, const u16* __restrict__ PHb,
    const float* __restrict__ bp,
    const int* __restrict__ offs, const int* __restrict__ wlist,
    const int* __restrict__ map,
    float* __restrict__ esum, float* __restrict__ logits_all) {
  const int ent = map[blockIdx.x];
  if (ent < 0) return;
  const int c = ent >> 8, blk = ent & 255;
  __shared__ char lds[16384];
  __shared__ int wid_s[64];
  const int tid = threadIdx.x, lane = tid & 63, wid = tid >> 6;
  const int st = offs[c], cnt = offs[c + 1] - st;
  if (tid < 64) {
    const int idx = blk * 64 + tid;
    wid_s[tid] = (idx < cnt) ? wlist[st + idx] : -1;
  }
  __syncthreads();

  f32x4 acc[4];
#pragma unroll
  for (int i = 0; i < 4; ++i) acc[i] = (f32x4){0.f, 0.f, 0.f, 0.f};

  const int sr = tid >> 3;
  const int scb = (tid & 7) * 16;
  const int ra = wid * 16 + (lane & 15);
  const int rb0 = lane & 15;
  const int ko = (lane >> 4) * 8;
  const u16* Bg = PHb + (size_t)(c * 64) * HD;

  for (int kc = 0; kc < HD; kc += 64) {
#pragma unroll
    for (int rep = 0; rep < 2; ++rep) {
      const int r = rep * 32 + sr;
      const int w = max(wid_s[r], 0);
      const bh8 va = *reinterpret_cast<const bh8*>(Wpb + (size_t)w * HD + kc + (scb >> 1));
      *reinterpret_cast<bh8*>(&lds[r * 128 + (scb ^ ((r & 7) << 4))]) = va;
      const bh8 vb = *reinterpret_cast<const bh8*>(Bg + r * HD + kc + (scb >> 1));
      *reinterpret_cast<bh8*>(&lds[8192 + r * 128 + (scb ^ ((r & 7) << 4))]) = vb;
    }
    __syncthreads();
#pragma unroll
    for (int kk = 0; kk < 64; kk += 32) {
      const int kb = (kk + ko) * 2;
      const bh8 af = *reinterpret_cast<const bh8*>(&lds[ra * 128 + (kb ^ ((ra & 7) << 4))]);
#pragma unroll
      for (int nj = 0; nj < 4; ++nj) {
        const int rb = nj * 16 + rb0;
        const bh8 bf = *reinterpret_cast<const bh8*>(&lds[8192 + rb * 128 + (kb ^ ((rb & 7) << 4))]);
        acc[nj] = __builtin_amdgcn_mfma_f32_16x16x32_bf16(af, bf, acc[nj], 0, 0, 0);
      }
    }
    __syncthreads();
  }

  const int g = lane >> 4, c0 = lane & 15;
#pragma unroll
  for (int nj = 0; nj < 4; ++nj) {
    float se = 0.f;
#pragma unroll
    for (int reg = 0; reg < 4; ++reg) {
      const int row = wid * 16 + g * 4 + reg;
      const int w = wid_s[row];
      if (w >= 0) {
        const float lg = acc[nj][reg] + bp[w];
        logits_all[(size_t)w * 64 + nj * 16 + c0] = lg;
        se += expf(lg);
      }
    }
    se += __shfl_xor(se, 16, 64);
    se += __shfl_xor(se, 32, 64);
    if (g == 0) atomicAdd(&esum[c * 64 + nj * 16 + c0], se);
  }
}

// ---------------- start head ----------------

__global__ __launch_bounds__(256) void head_dot_k(const float* __restrict__ sh,
                                                  const float* __restrict__ wv,
                                                  const float* __restrict__ bv,
                                                  float* __restrict__ logits) {
  const int tid = threadIdx.x, lane = tid & 63, wid = tid >> 6;
  const int row = blockIdx.x * 4 + wid;
  float s = 0.f;
#pragma unroll
  for (int q = 0; q < 4; ++q)
    s += sh[(size_t)row * HD + q * 64 + lane] * wv[q * 64 + lane];
  for (int off = 32; off; off >>= 1) s += __shfl_xor(s, off, 64);
  if (lane == 0) logits[row] = s + bv[0];
}

__global__ __launch_bounds__(1024) void head_lse_k(const float* __restrict__ logits,
                                                   float* __restrict__ out_lse) {
  __shared__ float red[16];
  __shared__ float mshared;
  const int tid = threadIdx.x;
  float m = -1e30f;
  for (int i = tid; i < CS; i += 1024) m = fmaxf(m, logits[i]);
  for (int off = 32; off; off >>= 1) m = fmaxf(m, __shfl_xor(m, off, 64));
  if ((tid & 63) == 0) red[tid >> 6] = m;
  __syncthreads();
  if (tid == 0) {
    float x = red[0];
    for (int i = 1; i < 16; ++i) x = fmaxf(x, red[i]);
    mshared = x;
  }
  __syncthreads();
  const float M = mshared;
  float s = 0.f;
  for (int i = tid; i < CS; i += 1024) s += expf(logits[i] - M);
  for (int off = 32; off; off >>= 1) s += __shfl_xor(s, off, 64);
  if ((tid & 63) == 0) red[tid >> 6] = s;
  __syncthreads();
  if (tid == 0) {
    float x = 0.f;
    for (int i = 0; i < 16; ++i) x += red[i];
    out_lse[0] = M + logf(x);
  }
}

__global__ void emit_k(const int* __restrict__ text, const int* __restrict__ w2c,
                       const float* __restrict__ lall, const float* __restrict__ lterm,
                       float* __restrict__ emitb) {
  const int idx = blockIdx.x * 256 + threadIdx.x;  // NB*TT*64
  const int s = idx & 63, nt = idx >> 6;
  const int w = text[nt];
  emitb[idx] = lall[(size_t)w * 64 + s] - lterm[w2c[w] * 64 + s];
}

// ---------------- forward scan (linear domain, per-step renorm) ----------------

__global__ __launch_bounds__(64) void scan_k(const u16* __restrict__ At,
                                             const float* __restrict__ Ascale,
                                             const float* __restrict__ hlog,
                                             const float* __restrict__ hlse,
                                             const float* __restrict__ emitb,
                                             const int* __restrict__ text,
                                             const int* __restrict__ w2c,
                                             float* __restrict__ out) {
  const int n = blockIdx.x, j = threadIdx.x;
  __shared__ float alpha[64];
  const int w0 = text[n * TT];
  float a0 = hlog[w2c[w0] * 64 + j] - hlse[0] + emitb[((size_t)(n * TT)) * 64 + j];
  float m = a0;
  for (int off = 32; off; off >>= 1) m = fmaxf(m, __shfl_xor(m, off, 64));
  const float lin = expf(a0 - m);
  float tot = lin;
  for (int off = 32; off; off >>= 1) tot += __shfl_xor(tot, off, 64);
  alpha[j] = lin / tot;
  float log_off = m + logf(tot);

  const u16* Ab = At + (size_t)n * (TT - 1) * 4096;
  u16x8 cur[8];
  {
    const u16x8* rp = reinterpret_cast<const u16x8*>(Ab + j * 64);
#pragma unroll
    for (int ib = 0; ib < 8; ++ib) cur[ib] = rp[ib];
  }
  __syncthreads();

  for (int t = 1; t < TT; ++t) {
    u16x8 nxt[8];
    if (t < TT - 1) {
      const u16x8* rp = reinterpret_cast<const u16x8*>(Ab + (size_t)t * 4096 + j * 64);
#pragma unroll
      for (int ib = 0; ib < 8; ++ib) nxt[ib] = rp[ib];
    }
    float s = 0.f;
#pragma unroll
    for (int ib = 0; ib < 8; ++ib) {
#pragma unroll
      for (int e = 0; e < 8; ++e)
        s += alpha[ib * 8 + e] * bf2f(cur[ib][e]);
    }
    float tot2 = s;
    for (int off = 32; off; off >>= 1) tot2 += __shfl_xor(tot2, off, 64);
    log_off += Ascale[n * (TT - 1) + t - 1] + logf(tot2);
    __syncthreads();
    alpha[j] = s / tot2;
    __syncthreads();
    if (t < TT - 1) {
#pragma unroll
      for (int ib = 0; ib < 8; ++ib) cur[ib] = nxt[ib];
    }
  }
  if (j == 0) out[n] = log_off;
}

// ---------------- host orchestration ----------------

extern "C" void kernel_launch(void* const* d_in, const int* in_sizes, int n_in,
                              void* d_out, int out_size, void* d_ws, size_t ws_size,
                              hipStream_t stream) {
  (void)in_sizes; (void)n_in; (void)out_size; (void)ws_size;
  const int* text = (const int*)d_in[0];
  const int* w2c  = (const int*)d_in[1];
  const float* sec = (const float*)d_in[2];
  const float* ses = (const float*)d_in[3];
  const float* stc = (const float*)d_in[4];
  const float* sts = (const float*)d_in[5];
  const float* nec = (const float*)d_in[6];
  const float* nes = (const float*)d_in[7];
  const float* pec = (const float*)d_in[8];
  const float* pes = (const float*)d_in[9];
  const float* srw1 = (const float*)d_in[10];
  const float* srb1 = (const float*)d_in[11];
  const float* srw2 = (const float*)d_in[12];
  const float* srb2 = (const float*)d_in[13];
  const float* trw1 = (const float*)d_in[14];
  const float* trb1 = (const float*)d_in[15];
  const float* trw2 = (const float*)d_in[16];
  const float* trb2 = (const float*)d_in[17];
  const float* tew1 = (const float*)d_in[18];
  const float* teb1 = (const float*)d_in[19];
  const float* tew2 = (const float*)d_in[20];
  const float* teb2 = (const float*)d_in[21];
  const float* sow = (const float*)d_in[22];
  const float* sob = (const float*)d_in[23];
  const float* tpw = (const float*)d_in[24];
  const float* tpb = (const float*)d_in[25];
  float* out = (float*)d_out;

  char* p = (char*)d_ws;
  auto carve = [&](size_t bytes) -> char* {
    char* r = p; p += (bytes + 255) & ~(size_t)255; return r;
  };
  float* Ef   = (float*)carve((size_t)CS * HD * 4);
  u16*   Ebf  = (u16*)  carve((size_t)CS * HD * 2);
  u16*   Hbf  = (u16*)  carve((size_t)CS * HD * 2);
  float* SHf  = (float*)carve((size_t)CS * HD * 4);
  u16*   Xbf  = (u16*)  carve((size_t)CS * HD * 2);
  u16*   NSEb = (u16*)  carve((size_t)CS * HD * 2);
  u16*   PHb  = (u16*)  carve((size_t)CS * HD * 2);
  u16*   Wpb  = (u16*)  carve((size_t)VV * HD * 2);
  u16*   Wb[6];
  for (int i = 0; i < 6; ++i) Wb[i] = (u16*)carve((size_t)HD * HD * 2);
  float* hlog  = (float*)carve(CS * 4);
  float* hlse  = (float*)carve(256);
  float* rsum  = (float*)carve(CS * 4);
  float* rlse  = (float*)carve(CS * 4);
  int* counts  = (int*)carve(KCL * 4);
  int* offs    = (int*)carve((KCL + 1) * 4);
  int* curs    = (int*)carve(KCL * 4);
  int* wlist   = (int*)carve(VV * 4);
  int* bmap    = (int*)carve(MAXB * 4);
  float* esum  = (float*)carve(CS * 4);
  float* lterm = (float*)carve(CS * 4);
  float* lall  = (float*)carve((size_t)VV * 64 * 4);
  float* emitb = (float*)carve((size_t)NB * TT * 64 * 4);
  u16*   At    = (u16*)carve((size_t)NB * (TT - 1) * 4096 * 2);
  float* Asc   = (float*)carve((size_t)NB * (TT - 1) * 4);

  hipMemsetAsync(rsum, 0, CS * 4, stream);
  hipMemsetAsync(esum, 0, CS * 4, stream);
  hipMemsetAsync(counts, 0, KCL * 4, stream);

  // weight conversions
  const float* wsrc[6] = {srw1, srw2, trw1, trw2, tew1, tew2};
  for (int i = 0; i < 6; ++i)
    cvt_k<<<(HD * HD + 255) / 256, 256, 0, stream>>>(wsrc[i], Wb[i], HD * HD);
  cvt_k<<<(VV * HD + 255) / 256, 256, 0, stream>>>(tpw, Wpb, VV * HD);

  // CSR cluster->words + block map
  count_k<<<(VV + 255) / 256, 256, 0, stream>>>(w2c, counts);
  csr_scan_k<<<1, 64, 0, stream>>>(counts, offs, curs);
  fill_k<<<(VV + 255) / 256, 256, 0, stream>>>(w2c, curs, wlist);
  map_k<<<1, 64, 0, stream>>>(offs, bmap);

  const dim3 gMLP(4, 128);

  // start: sh = residual(emb) ; head logits ; lse
  emb_k<<<CS * HD / 256, 256, 0, stream>>>(sec, ses, Ef, Ebf);
  gemm64<0><<<gMLP, 256, 0, stream>>>(Ebf, Wb[0], CS, HD, HD, srb1, nullptr,
      nullptr, Hbf, nullptr, nullptr, nullptr, nullptr, nullptr, nullptr, nullptr);
  gemm64<0><<<gMLP, 256, 0, stream>>>(Hbf, Wb[1], CS, HD, HD, srb2, Ef,
      SHf, nullptr, nullptr, nullptr, nullptr, nullptr, nullptr, nullptr, nullptr);
  head_dot_k<<<CS / 4, 256, 0, stream>>>(SHf, sow, sob, hlog);
  head_lse_k<<<1, 1024, 0, stream>>>(hlog, hlse);

  // trans: x = residual(emb(state)); nse = emb(next)
  emb_k<<<CS * HD / 256, 256, 0, stream>>>(stc, sts, Ef, Ebf);
  gemm64<0><<<gMLP, 256, 0, stream>>>(Ebf, Wb[2], CS, HD, HD, trb1, nullptr,
      nullptr, Hbf, nullptr, nullptr, nullptr, nullptr, nullptr, nullptr, nullptr);
  gemm64<0><<<gMLP, 256, 0, stream>>>(Hbf, Wb[3], CS, HD, HD, trb2, Ef,
      nullptr, Xbf, nullptr, nullptr, nullptr, nullptr, nullptr, nullptr, nullptr);
  emb_k<<<CS * HD / 256, 256, 0, stream>>>(nec, nes, Ef, NSEb);  // Ef is scratch here

  // term: ph = residual(emb(pre)) -> bf16
  emb_k<<<CS * HD / 256, 256, 0, stream>>>(pec, pes, Ef, Ebf);
  gemm64<0><<<gMLP, 256, 0, stream>>>(Ebf, Wb[4], CS, HD, HD, teb1, nullptr,
      nullptr, Hbf, nullptr, nullptr, nullptr, nullptr, nullptr, nullptr, nullptr);
  gemm64<0><<<gMLP, 256, 0, stream>>>(Hbf, Wb[5], CS, HD, HD, teb2, Ef,
      nullptr, PHb, nullptr, nullptr, nullptr, nullptr, nullptr, nullptr, nullptr);

  // transition row-logsumexp (streaming 8192x8192x256)
  gemm64<1><<<dim3(128, 128), 256, 0, stream>>>(Xbf, NSEb, CS, CS, HD, nullptr,
      nullptr, nullptr, nullptr, rsum, nullptr, nullptr, nullptr, nullptr, nullptr, nullptr);
  log_k<<<CS / 256, 256, 0, stream>>>(rsum, rlse, CS);

  // emission: MFMA tiles + masked lse
  emis_k<<<MAXB, 256, 0, stream>>>(Wpb, PHb, tpb, offs, wlist, bmap, esum, lall);
  log_k<<<CS / 256, 256, 0, stream>>>(esum, lterm, CS);
  emit_k<<<NB * TT * 64 / 256, 256, 0, stream>>>(text, w2c, lall, lterm, emitb);

  // per-(n,t) linear-domain step matrices
  gemm64<2><<<dim3(NB * (TT - 1)), 256, 0, stream>>>(Xbf, NSEb, CS, CS, HD, nullptr,
      nullptr, nullptr, nullptr, nullptr, rlse, emitb, text, w2c, At, Asc);

  // sequential forward scan
  scan_k<<<NB, 64, 0, stream>>>(At, Asc, hlog, hlse, emitb, text, w2c, out);
}

// Round 3
// 372.579 us; speedup vs baseline: 1.8700x; 1.4059x over previous
//
#include <hip/hip_runtime.h>
#include <hip/hip_bf16.h>

// FactoredHmmLm forward on MI355X.
// Pipeline:
//  1. emb + residual MLPs (bf16 MFMA GEMMs, 8192x256x256) -> sh, x, nse, ph
//  2. start head logits + full-8192 logsumexp
//  3. transition row-logsumexp: streaming 8192x8192x256 GEMM (no 268MB matrix)
//  4. emission: CSR cluster->words, MFMA 64x64 tiles (gathered Wp rows) + atomic exp-sum lse
//  5. per-(n,t) 64x64 linear-domain leaf matrices M_t = exp(tr + emit - m), bf16
//  6. balanced-tree product reduction (8 levels of 64x64x64 MFMA matmuls, per-level renorm)
//     replaces the 255-step serial scan. Leaf/node layout by parity: even index = row-major
//     (left operand), odd index = transposed (right operand).

using u16 = unsigned short;
typedef __attribute__((ext_vector_type(8))) short bh8;     // 8 bf16 (4 VGPRs)
typedef __attribute__((ext_vector_type(4))) float f32x4;
typedef __attribute__((ext_vector_type(8))) unsigned short u16x8;

#define HD 256
#define TT 256
#define NB 16
#define KCL 128
#define CS 8192
#define VV 10000
#define MAXB 320   // >= sum_c ceil(cnt_c/64) <= 10000/64 + 128 = 283

__device__ __forceinline__ u16 f2bf(float v) {
  union { float f; unsigned int i; } u; u.f = v;
  unsigned int r = u.i + 0x7fffu + ((u.i >> 16) & 1u);   // RNE
  return (u16)(r >> 16);
}
__device__ __forceinline__ float bf2f(u16 u) {
  union { unsigned int i; float f; } x; x.i = ((unsigned int)u) << 16; return x.f;
}

// ---------------- small utility kernels ----------------

__global__ void cvt_k(const float* __restrict__ src, u16* __restrict__ dst, int n) {
  int i = blockIdx.x * 256 + threadIdx.x;
  if (i < n) dst[i] = f2bf(src[i]);
}

// E[k*64+s][h] = ec[k][h] + es[s][h]; writes f32 + bf16
__global__ void emb_k(const float* __restrict__ ec, const float* __restrict__ es,
                      float* __restrict__ ef, u16* __restrict__ ebf) {
  int idx = blockIdx.x * 256 + threadIdx.x;   // CS*HD total
  int h = idx & 255, row = idx >> 8;
  int k = row >> 6, s = row & 63;
  float v = ec[k * HD + h] + es[s * HD + h];
  ef[idx] = v;
  ebf[idx] = f2bf(v);
}

__global__ void log_k(const float* __restrict__ in, float* __restrict__ out, int n) {
  int i = blockIdx.x * 256 + threadIdx.x;
  if (i < n) out[i] = logf(in[i]);
}

// ---------------- CSR: cluster -> word list ----------------

__global__ void count_k(const int* __restrict__ w2c, int* __restrict__ counts) {
  int w = blockIdx.x * 256 + threadIdx.x;
  if (w < VV) atomicAdd(&counts[w2c[w]], 1);
}
__global__ void csr_scan_k(const int* __restrict__ counts, int* __restrict__ offs,
                           int* __restrict__ curs) {
  if (threadIdx.x == 0) {
    int acc = 0;
    for (int c = 0; c < KCL; ++c) { offs[c] = acc; curs[c] = acc; acc += counts[c]; }
    offs[KCL] = acc;
  }
}
__global__ void fill_k(const int* __restrict__ w2c, int* __restrict__ curs,
                       int* __restrict__ wlist) {
  int w = blockIdx.x * 256 + threadIdx.x;
  if (w < VV) { int p = atomicAdd(&curs[w2c[w]], 1); wlist[p] = w; }
}
// block list: entry = (c<<8)|blk_within_cluster, -1 past end
__global__ void map_k(const int* __restrict__ offs, int* __restrict__ map) {
  if (threadIdx.x == 0) {
    int idx = 0;
    for (int c = 0; c < KCL; ++c) {
      int nb = (offs[c + 1] - offs[c] + 63) >> 6;
      for (int b = 0; b < nb; ++b) map[idx++] = (c << 8) | b;
    }
    for (; idx < MAXB; ++idx) map[idx] = -1;
  }
}

// identity leaf at position 255 of each sequence (odd index -> transposed layout; I^T = I)
__global__ void idleaf_k(u16* __restrict__ buf, float* __restrict__ sc) {
  const int n = blockIdx.x, t = threadIdx.x;   // 64 threads, row t
  u16* node = buf + ((size_t)n * 256 + 255) * 4096;
  for (int c = 0; c < 64; ++c) node[t * 64 + c] = (c == t) ? (u16)0x3F80 : (u16)0;
  if (t == 0) sc[n * 256 + 255] = 0.f;
}

// ---------------- MFMA GEMM: C[m,n] = sum_k A[m,k]*B[n,k], 64x64 tile ----------------
// MODE 0: out = relu(acc + bias[n] (+ skip[m*256+n])) -> f32 and/or bf16
// MODE 1: row_sumexp[m] += sum_n exp(acc)  (transition row-lse partials)
// MODE 2: per-(n,t) leaf: M = exp(acc - row_lse[m] + emit[n,t,j] - max), bf16, layout by parity

template<int MODE>
__global__ __launch_bounds__(256) void gemm64(
    const u16* __restrict__ A, const u16* __restrict__ B,
    int M, int N, int K,
    const float* __restrict__ bias, const float* __restrict__ skip,
    float* __restrict__ outf, u16* __restrict__ outbf,
    float* __restrict__ row_sumexp,
    const float* __restrict__ row_lse, const float* __restrict__ emitb,
    const int* __restrict__ text, const int* __restrict__ w2c,
    u16* __restrict__ leafb, float* __restrict__ leafsc) {
  __shared__ char lds[16384];
  __shared__ float wmax[4];
  const int tid = threadIdx.x;
  const int lane = tid & 63;
  const int wid = tid >> 6;

  int rm, cn, nn = 0, ttv = 0;
  if (MODE == 2) {
    const int bi = blockIdx.x;
    nn = bi / (TT - 1);
    ttv = bi % (TT - 1) + 1;
    const int wp = text[nn * TT + ttv - 1];
    const int wc = text[nn * TT + ttv];
    rm = w2c[wp] * 64;
    cn = w2c[wc] * 64;
  } else {
    rm = blockIdx.y * 64;
    cn = blockIdx.x * 64;
  }
  const u16* Ag = A + (size_t)rm * K;
  const u16* Bg = B + (size_t)cn * K;

  f32x4 acc[4];
#pragma unroll
  for (int i = 0; i < 4; ++i) acc[i] = (f32x4){0.f, 0.f, 0.f, 0.f};

  const int sr = tid >> 3;          // staging row 0..31 (+32 for rep 1)
  const int scb = (tid & 7) * 16;   // staging byte-col within 128B row
  const int ra = wid * 16 + (lane & 15);
  const int rb0 = lane & 15;
  const int ko = (lane >> 4) * 8;   // fragment k-offset (elements)

  for (int kc = 0; kc < K; kc += 64) {
#pragma unroll
    for (int rep = 0; rep < 2; ++rep) {
      const int r = rep * 32 + sr;
      const bh8 va = *reinterpret_cast<const bh8*>(Ag + r * K + kc + (scb >> 1));
      *reinterpret_cast<bh8*>(&lds[r * 128 + (scb ^ ((r & 7) << 4))]) = va;
      const bh8 vb = *reinterpret_cast<const bh8*>(Bg + r * K + kc + (scb >> 1));
      *reinterpret_cast<bh8*>(&lds[8192 + r * 128 + (scb ^ ((r & 7) << 4))]) = vb;
    }
    __syncthreads();
#pragma unroll
    for (int kk = 0; kk < 64; kk += 32) {
      const int kb = (kk + ko) * 2;
      const bh8 af = *reinterpret_cast<const bh8*>(&lds[ra * 128 + (kb ^ ((ra & 7) << 4))]);
#pragma unroll
      for (int nj = 0; nj < 4; ++nj) {
        const int rb = nj * 16 + rb0;
        const bh8 bf = *reinterpret_cast<const bh8*>(&lds[8192 + rb * 128 + (kb ^ ((rb & 7) << 4))]);
        acc[nj] = __builtin_amdgcn_mfma_f32_16x16x32_bf16(af, bf, acc[nj], 0, 0, 0);
      }
    }
    __syncthreads();
  }

  // epilogues; C/D frag: col = lane&15, row = (lane>>4)*4 + reg
  const int g = lane >> 4, c0 = lane & 15;

  if (MODE == 0) {
#pragma unroll
    for (int nj = 0; nj < 4; ++nj) {
      const int nidx = cn + nj * 16 + c0;
      const float bv = bias ? bias[nidx] : 0.f;
#pragma unroll
      for (int reg = 0; reg < 4; ++reg) {
        const int midx = rm + wid * 16 + g * 4 + reg;
        float v = acc[nj][reg] + bv;
        if (skip) v += skip[(size_t)midx * 256 + nidx];
        v = fmaxf(v, 0.f);
        if (outf) outf[(size_t)midx * N + nidx] = v;
        if (outbf) outbf[(size_t)midx * N + nidx] = f2bf(v);
      }
    }
  } else if (MODE == 1) {
    float rs[4] = {0.f, 0.f, 0.f, 0.f};
#pragma unroll
    for (int nj = 0; nj < 4; ++nj)
#pragma unroll
      for (int reg = 0; reg < 4; ++reg)
        rs[reg] += expf(acc[nj][reg]);
#pragma unroll
    for (int off = 1; off < 16; off <<= 1)
#pragma unroll
      for (int reg = 0; reg < 4; ++reg)
        rs[reg] += __shfl_xor(rs[reg], off, 64);
    if (c0 == 0) {
#pragma unroll
      for (int reg = 0; reg < 4; ++reg)
        atomicAdd(&row_sumexp[rm + wid * 16 + g * 4 + reg], rs[reg]);
    }
  } else {  // MODE 2: leaf matrix, layout by parity of leaf index (ttv-1)
    float L[4][4];
    float mx = -1e30f;
#pragma unroll
    for (int nj = 0; nj < 4; ++nj) {
      const float ev = emitb[((size_t)(nn * TT + ttv)) * 64 + nj * 16 + c0];
#pragma unroll
      for (int reg = 0; reg < 4; ++reg) {
        const float l = acc[nj][reg] - row_lse[rm + wid * 16 + g * 4 + reg] + ev;
        L[nj][reg] = l;
        mx = fmaxf(mx, l);
      }
    }
#pragma unroll
    for (int off = 1; off < 64; off <<= 1) mx = fmaxf(mx, __shfl_xor(mx, off, 64));
    if (lane == 0) wmax[wid] = mx;
    __syncthreads();
    const float m = fmaxf(fmaxf(wmax[0], wmax[1]), fmaxf(wmax[2], wmax[3]));
    float* ftile = reinterpret_cast<float*>(lds);
#pragma unroll
    for (int nj = 0; nj < 4; ++nj)
#pragma unroll
      for (int reg = 0; reg < 4; ++reg)
        ftile[(wid * 16 + g * 4 + reg) * 64 + nj * 16 + c0] = expf(L[nj][reg] - m);
    __syncthreads();
    const int leaf = ttv - 1;                 // 0..254
    u16* node = leafb + ((size_t)nn * 256 + leaf) * 4096;
    const int rr = tid >> 2, cb = (tid & 3) * 16;
    u16x8 o0, o1;
    if ((leaf & 1) == 0) {                    // even -> row-major (left operand)
#pragma unroll
      for (int e = 0; e < 8; ++e) o0[e] = f2bf(ftile[rr * 64 + cb + e]);
#pragma unroll
      for (int e = 0; e < 8; ++e) o1[e] = f2bf(ftile[rr * 64 + cb + 8 + e]);
    } else {                                  // odd -> transposed (right operand)
#pragma unroll
      for (int e = 0; e < 8; ++e) o0[e] = f2bf(ftile[(cb + e) * 64 + rr]);
#pragma unroll
      for (int e = 0; e < 8; ++e) o1[e] = f2bf(ftile[(cb + 8 + e) * 64 + rr]);
    }
    *reinterpret_cast<u16x8*>(node + rr * 64 + cb) = o0;
    *reinterpret_cast<u16x8*>(node + rr * 64 + cb + 8) = o1;
    if (tid == 0) leafsc[nn * 256 + leaf] = m;
  }
}

// ---------------- tree combine: C = M_left * M_right (64x64x64), renorm, layout by parity ----
// src: 2U nodes/seq (even=row-major, odd=transposed). dst: U nodes/seq.

__global__ __launch_bounds__(256) void comb_k(const u16* __restrict__ src,
                                              const float* __restrict__ scs,
                                              u16* __restrict__ dst,
                                              float* __restrict__ scd, int U) {
  const int n = blockIdx.x / U, u = blockIdx.x % U;
  __shared__ char lds[16384];
  __shared__ float wmax[4];
  const int tid = threadIdx.x, lane = tid & 63, wid = tid >> 6;
  const u16* Anode = src + ((size_t)(n * 2 * U + 2 * u)) * 4096;
  const u16* Bnode = src + ((size_t)(n * 2 * U + 2 * u + 1)) * 4096;

  const int sr = tid >> 3, scb = (tid & 7) * 16;
#pragma unroll
  for (int rep = 0; rep < 2; ++rep) {
    const int r = rep * 32 + sr;
    const bh8 va = *reinterpret_cast<const bh8*>(Anode + r * 64 + (scb >> 1));
    *reinterpret_cast<bh8*>(&lds[r * 128 + (scb ^ ((r & 7) << 4))]) = va;
    const bh8 vb = *reinterpret_cast<const bh8*>(Bnode + r * 64 + (scb >> 1));
    *reinterpret_cast<bh8*>(&lds[8192 + r * 128 + (scb ^ ((r & 7) << 4))]) = vb;
  }
  __syncthreads();

  f32x4 acc[4];
#pragma unroll
  for (int i = 0; i < 4; ++i) acc[i] = (f32x4){0.f, 0.f, 0.f, 0.f};
  const int ra = wid * 16 + (lane & 15), rb0 = lane & 15, ko = (lane >> 4) * 8;
#pragma unroll
  for (int kk = 0; kk < 64; kk += 32) {
    const int kb = (kk + ko) * 2;
    const bh8 af = *reinterpret_cast<const bh8*>(&lds[ra * 128 + (kb ^ ((ra & 7) << 4))]);
#pragma unroll
    for (int nj = 0; nj < 4; ++nj) {
      const int rb = nj * 16 + rb0;
      const bh8 bf = *reinterpret_cast<const bh8*>(&lds[8192 + rb * 128 + (kb ^ ((rb & 7) << 4))]);
      acc[nj] = __builtin_amdgcn_mfma_f32_16x16x32_bf16(af, bf, acc[nj], 0, 0, 0);
    }
  }
  __syncthreads();

  const int g = lane >> 4, c0 = lane & 15;
  float mx = 0.f;
#pragma unroll
  for (int nj = 0; nj < 4; ++nj)
#pragma unroll
    for (int reg = 0; reg < 4; ++reg) mx = fmaxf(mx, acc[nj][reg]);
#pragma unroll
  for (int off = 1; off < 64; off <<= 1) mx = fmaxf(mx, __shfl_xor(mx, off, 64));
  if (lane == 0) wmax[wid] = mx;
  __syncthreads();
  const float m = fmaxf(fmaxf(wmax[0], wmax[1]), fmaxf(wmax[2], wmax[3]));
  const float inv = 1.0f / m;
  float* ftile = reinterpret_cast<float*>(lds);
#pragma unroll
  for (int nj = 0; nj < 4; ++nj)
#pragma unroll
    for (int reg = 0; reg < 4; ++reg)
      ftile[(wid * 16 + g * 4 + reg) * 64 + nj * 16 + c0] = acc[nj][reg] * inv;
  __syncthreads();

  u16* node = dst + ((size_t)(n * U + u)) * 4096;
  const int rr = tid >> 2, cb = (tid & 3) * 16;
  u16x8 o0, o1;
  if ((u & 1) == 0) {
#pragma unroll
    for (int e = 0; e < 8; ++e) o0[e] = f2bf(ftile[rr * 64 + cb + e]);
#pragma unroll
    for (int e = 0; e < 8; ++e) o1[e] = f2bf(ftile[rr * 64 + cb + 8 + e]);
  } else {
#pragma unroll
    for (int e = 0; e < 8; ++e) o0[e] = f2bf(ftile[(cb + e) * 64 + rr]);
#pragma unroll
    for (int e = 0; e < 8; ++e) o1[e] = f2bf(ftile[(cb + 8 + e) * 64 + rr]);
  }
  *reinterpret_cast<u16x8*>(node + rr * 64 + cb) = o0;
  *reinterpret_cast<u16x8*>(node + rr * 64 + cb + 8) = o1;
  if (tid == 0)
    scd[n * U + u] = scs[n * 2 * U + 2 * u] + scs[n * 2 * U + 2 * u + 1] + logf(m);
}

// ---------------- final: out[n] = m0 + scale + log(sum_i a0lin[i] * rowsum_i(P)) -------------

__global__ __launch_bounds__(64) void final_k(const u16* __restrict__ root,
                                              const float* __restrict__ rsc,
                                              const float* __restrict__ hlog,
                                              const float* __restrict__ hlse,
                                              const float* __restrict__ emitb,
                                              const int* __restrict__ text,
                                              const int* __restrict__ w2c,
                                              float* __restrict__ out) {
  const int n = blockIdx.x, i = threadIdx.x;
  const int w0 = text[n * TT];
  float a0 = hlog[w2c[w0] * 64 + i] - hlse[0] + emitb[((size_t)(n * TT)) * 64 + i];
  float m0 = a0;
  for (int off = 32; off; off >>= 1) m0 = fmaxf(m0, __shfl_xor(m0, off, 64));
  const float lin = expf(a0 - m0);
  const u16* row = root + (size_t)n * 4096 + i * 64;   // root: row-major (even index)
  float rs = 0.f;
#pragma unroll
  for (int e8 = 0; e8 < 8; ++e8) {
    const u16x8 v = *reinterpret_cast<const u16x8*>(row + e8 * 8);
#pragma unroll
    for (int e = 0; e < 8; ++e) rs += bf2f(v[e]);
  }
  float v = lin * rs;
  for (int off = 32; off; off >>= 1) v += __shfl_xor(v, off, 64);
  if (i == 0) out[n] = m0 + rsc[n] + logf(v);
}

// ---------------- emission GEMM: per 64-word block of a cluster ----------------

__global__ __launch_bounds__(256) void emis_k(
    const u16* __restrict__ Wpb, const u16* __restrict__ PHb,
    const float* __restrict__ bp,
    const int* __restrict__ offs, const int* __restrict__ wlist,
    const int* __restrict__ map,
    float* __restrict__ esum, float* __restrict__ logits_all) {
  const int ent = map[blockIdx.x];
  if (ent < 0) return;
  const int c = ent >> 8, blk = ent & 255;
  __shared__ char lds[16384];
  __shared__ int wid_s[64];
  const int tid = threadIdx.x, lane = tid & 63, wid = tid >> 6;
  const int st = offs[c], cnt = offs[c + 1] - st;
  if (tid < 64) {
    const int idx = blk * 64 + tid;
    wid_s[tid] = (idx < cnt) ? wlist[st + idx] : -1;
  }
  __syncthreads();

  f32x4 acc[4];
#pragma unroll
  for (int i = 0; i < 4; ++i) acc[i] = (f32x4){0.f, 0.f, 0.f, 0.f};

  const int sr = tid >> 3;
  const int scb = (tid & 7) * 16;
  const int ra = wid * 16 + (lane & 15);
  const int rb0 = lane & 15;
  const int ko = (lane >> 4) * 8;
  const u16* Bg = PHb + (size_t)(c * 64) * HD;

  for (int kc = 0; kc < HD; kc += 64) {
#pragma unroll
    for (int rep = 0; rep < 2; ++rep) {
      const int r = rep * 32 + sr;
      const int w = max(wid_s[r], 0);
      const bh8 va = *reinterpret_cast<const bh8*>(Wpb + (size_t)w * HD + kc + (scb >> 1));
      *reinterpret_cast<bh8*>(&lds[r * 128 + (scb ^ ((r & 7) << 4))]) = va;
      const bh8 vb = *reinterpret_cast<const bh8*>(Bg + r * HD + kc + (scb >> 1));
      *reinterpret_cast<bh8*>(&lds[8192 + r * 128 + (scb ^ ((r & 7) << 4))]) = vb;
    }
    __syncthreads();
#pragma unroll
    for (int kk = 0; kk < 64; kk += 32) {
      const int kb = (kk + ko) * 2;
      const bh8 af = *reinterpret_cast<const bh8*>(&lds[ra * 128 + (kb ^ ((ra & 7) << 4))]);
#pragma unroll
      for (int nj = 0; nj < 4; ++nj) {
        const int rb = nj * 16 + rb0;
        const bh8 bf = *reinterpret_cast<const bh8*>(&lds[8192 + rb * 128 + (kb ^ ((rb & 7) << 4))]);
        acc[nj] = __builtin_amdgcn_mfma_f32_16x16x32_bf16(af, bf, acc[nj], 0, 0, 0);
      }
    }
    __syncthreads();
  }

  const int g = lane >> 4, c0 = lane & 15;
#pragma unroll
  for (int nj = 0; nj < 4; ++nj) {
    float se = 0.f;
#pragma unroll
    for (int reg = 0; reg < 4; ++reg) {
      const int row = wid * 16 + g * 4 + reg;
      const int w = wid_s[row];
      if (w >= 0) {
        const float lg = acc[nj][reg] + bp[w];
        logits_all[(size_t)w * 64 + nj * 16 + c0] = lg;
        se += expf(lg);
      }
    }
    se += __shfl_xor(se, 16, 64);
    se += __shfl_xor(se, 32, 64);
    if (g == 0) atomicAdd(&esum[c * 64 + nj * 16 + c0], se);
  }
}

// ---------------- start head ----------------

__global__ __launch_bounds__(256) void head_dot_k(const float* __restrict__ sh,
                                                  const float* __restrict__ wv,
                                                  const float* __restrict__ bv,
                                                  float* __restrict__ logits) {
  const int tid = threadIdx.x, lane = tid & 63, wid = tid >> 6;
  const int row = blockIdx.x * 4 + wid;
  float s = 0.f;
#pragma unroll
  for (int q = 0; q < 4; ++q)
    s += sh[(size_t)row * HD + q * 64 + lane] * wv[q * 64 + lane];
  for (int off = 32; off; off >>= 1) s += __shfl_xor(s, off, 64);
  if (lane == 0) logits[row] = s + bv[0];
}

__global__ __launch_bounds__(1024) void head_lse_k(const float* __restrict__ logits,
                                                   float* __restrict__ out_lse) {
  __shared__ float red[16];
  __shared__ float mshared;
  const int tid = threadIdx.x;
  float m = -1e30f;
  for (int i = tid; i < CS; i += 1024) m = fmaxf(m, logits[i]);
  for (int off = 32; off; off >>= 1) m = fmaxf(m, __shfl_xor(m, off, 64));
  if ((tid & 63) == 0) red[tid >> 6] = m;
  __syncthreads();
  if (tid == 0) {
    float x = red[0];
    for (int i = 1; i < 16; ++i) x = fmaxf(x, red[i]);
    mshared = x;
  }
  __syncthreads();
  const float M = mshared;
  float s = 0.f;
  for (int i = tid; i < CS; i += 1024) s += expf(logits[i] - M);
  for (int off = 32; off; off >>= 1) s += __shfl_xor(s, off, 64);
  if ((tid & 63) == 0) red[tid >> 6] = s;
  __syncthreads();
  if (tid == 0) {
    float x = 0.f;
    for (int i = 0; i < 16; ++i) x += red[i];
    out_lse[0] = M + logf(x);
  }
}

__global__ void emit_k(const int* __restrict__ text, const int* __restrict__ w2c,
                       const float* __restrict__ lall, const float* __restrict__ lterm,
                       float* __restrict__ emitb) {
  const int idx = blockIdx.x * 256 + threadIdx.x;  // NB*TT*64
  const int s = idx & 63, nt = idx >> 6;
  const int w = text[nt];
  emitb[idx] = lall[(size_t)w * 64 + s] - lterm[w2c[w] * 64 + s];
}

// ---------------- host orchestration ----------------

extern "C" void kernel_launch(void* const* d_in, const int* in_sizes, int n_in,
                              void* d_out, int out_size, void* d_ws, size_t ws_size,
                              hipStream_t stream) {
  (void)in_sizes; (void)n_in; (void)out_size; (void)ws_size;
  const int* text = (const int*)d_in[0];
  const int* w2c  = (const int*)d_in[1];
  const float* sec = (const float*)d_in[2];
  const float* ses = (const float*)d_in[3];
  const float* stc = (const float*)d_in[4];
  const float* sts = (const float*)d_in[5];
  const float* nec = (const float*)d_in[6];
  const float* nes = (const float*)d_in[7];
  const float* pec = (const float*)d_in[8];
  const float* pes = (const float*)d_in[9];
  const float* srw1 = (const float*)d_in[10];
  const float* srb1 = (const float*)d_in[11];
  const float* srw2 = (const float*)d_in[12];
  const float* srb2 = (const float*)d_in[13];
  const float* trw1 = (const float*)d_in[14];
  const float* trb1 = (const float*)d_in[15];
  const float* trw2 = (const float*)d_in[16];
  const float* trb2 = (const float*)d_in[17];
  const float* tew1 = (const float*)d_in[18];
  const float* teb1 = (const float*)d_in[19];
  const float* tew2 = (const float*)d_in[20];
  const float* teb2 = (const float*)d_in[21];
  const float* sow = (const float*)d_in[22];
  const float* sob = (const float*)d_in[23];
  const float* tpw = (const float*)d_in[24];
  const float* tpb = (const float*)d_in[25];
  float* out = (float*)d_out;

  char* p = (char*)d_ws;
  auto carve = [&](size_t bytes) -> char* {
    char* r = p; p += (bytes + 255) & ~(size_t)255; return r;
  };
  float* Ef   = (float*)carve((size_t)CS * HD * 4);
  u16*   Ebf  = (u16*)  carve((size_t)CS * HD * 2);
  u16*   Hbf  = (u16*)  carve((size_t)CS * HD * 2);
  float* SHf  = (float*)carve((size_t)CS * HD * 4);
  u16*   Xbf  = (u16*)  carve((size_t)CS * HD * 2);
  u16*   NSEb = (u16*)  carve((size_t)CS * HD * 2);
  u16*   PHb  = (u16*)  carve((size_t)CS * HD * 2);
  u16*   Wpb  = (u16*)  carve((size_t)VV * HD * 2);
  u16*   Wb[6];
  for (int i = 0; i < 6; ++i) Wb[i] = (u16*)carve((size_t)HD * HD * 2);
  float* hlog  = (float*)carve(CS * 4);
  float* hlse  = (float*)carve(256);
  float* rsum  = (float*)carve(CS * 4);
  float* rlse  = (float*)carve(CS * 4);
  int* counts  = (int*)carve(KCL * 4);
  int* offs    = (int*)carve((KCL + 1) * 4);
  int* curs    = (int*)carve(KCL * 4);
  int* wlist   = (int*)carve(VV * 4);
  int* bmap    = (int*)carve(MAXB * 4);
  float* esum  = (float*)carve(CS * 4);
  float* lterm = (float*)carve(CS * 4);
  float* lall  = (float*)carve((size_t)VV * 64 * 4);
  float* emitb = (float*)carve((size_t)NB * TT * 64 * 4);
  u16*   bufA  = (u16*)carve((size_t)NB * 256 * 4096 * 2);   // tree ping (leaves)
  u16*   bufB  = (u16*)carve((size_t)NB * 128 * 4096 * 2);   // tree pong
  float* scA   = (float*)carve((size_t)NB * 256 * 4);
  float* scB   = (float*)carve((size_t)NB * 128 * 4);

  hipMemsetAsync(rsum, 0, CS * 4, stream);
  hipMemsetAsync(esum, 0, CS * 4, stream);
  hipMemsetAsync(counts, 0, KCL * 4, stream);

  // weight conversions
  const float* wsrc[6] = {srw1, srw2, trw1, trw2, tew1, tew2};
  for (int i = 0; i < 6; ++i)
    cvt_k<<<(HD * HD + 255) / 256, 256, 0, stream>>>(wsrc[i], Wb[i], HD * HD);
  cvt_k<<<(VV * HD + 255) / 256, 256, 0, stream>>>(tpw, Wpb, VV * HD);

  // CSR cluster->words + block map
  count_k<<<(VV + 255) / 256, 256, 0, stream>>>(w2c, counts);
  csr_scan_k<<<1, 64, 0, stream>>>(counts, offs, curs);
  fill_k<<<(VV + 255) / 256, 256, 0, stream>>>(w2c, curs, wlist);
  map_k<<<1, 64, 0, stream>>>(offs, bmap);

  const dim3 gMLP(4, 128);

  // start: sh = residual(emb) ; head logits ; lse
  emb_k<<<CS * HD / 256, 256, 0, stream>>>(sec, ses, Ef, Ebf);
  gemm64<0><<<gMLP, 256, 0, stream>>>(Ebf, Wb[0], CS, HD, HD, srb1, nullptr,
      nullptr, Hbf, nullptr, nullptr, nullptr, nullptr, nullptr, nullptr, nullptr);
  gemm64<0><<<gMLP, 256, 0, stream>>>(Hbf, Wb[1], CS, HD, HD, srb2, Ef,
      SHf, nullptr, nullptr, nullptr, nullptr, nullptr, nullptr, nullptr, nullptr);
  head_dot_k<<<CS / 4, 256, 0, stream>>>(SHf, sow, sob, hlog);
  head_lse_k<<<1, 1024, 0, stream>>>(hlog, hlse);

  // trans: x = residual(emb(state)); nse = emb(next)
  emb_k<<<CS * HD / 256, 256, 0, stream>>>(stc, sts, Ef, Ebf);
  gemm64<0><<<gMLP, 256, 0, stream>>>(Ebf, Wb[2], CS, HD, HD, trb1, nullptr,
      nullptr, Hbf, nullptr, nullptr, nullptr, nullptr, nullptr, nullptr, nullptr);
  gemm64<0><<<gMLP, 256, 0, stream>>>(Hbf, Wb[3], CS, HD, HD, trb2, Ef,
      nullptr, Xbf, nullptr, nullptr, nullptr, nullptr, nullptr, nullptr, nullptr);
  emb_k<<<CS * HD / 256, 256, 0, stream>>>(nec, nes, Ef, NSEb);  // Ef is scratch here

  // term: ph = residual(emb(pre)) -> bf16
  emb_k<<<CS * HD / 256, 256, 0, stream>>>(pec, pes, Ef, Ebf);
  gemm64<0><<<gMLP, 256, 0, stream>>>(Ebf, Wb[4], CS, HD, HD, teb1, nullptr,
      nullptr, Hbf, nullptr, nullptr, nullptr, nullptr, nullptr, nullptr, nullptr);
  gemm64<0><<<gMLP, 256, 0, stream>>>(Hbf, Wb[5], CS, HD, HD, teb2, Ef,
      nullptr, PHb, nullptr, nullptr, nullptr, nullptr, nullptr, nullptr, nullptr);

  // transition row-logsumexp (streaming 8192x8192x256)
  gemm64<1><<<dim3(128, 128), 256, 0, stream>>>(Xbf, NSEb, CS, CS, HD, nullptr,
      nullptr, nullptr, nullptr, rsum, nullptr, nullptr, nullptr, nullptr, nullptr, nullptr);
  log_k<<<CS / 256, 256, 0, stream>>>(rsum, rlse, CS);

  // emission: MFMA tiles + masked lse
  emis_k<<<MAXB, 256, 0, stream>>>(Wpb, PHb, tpb, offs, wlist, bmap, esum, lall);
  log_k<<<CS / 256, 256, 0, stream>>>(esum, lterm, CS);
  emit_k<<<NB * TT * 64 / 256, 256, 0, stream>>>(text, w2c, lall, lterm, emitb);

  // leaves: 255 real + 1 identity per sequence
  idleaf_k<<<NB, 64, 0, stream>>>(bufA, scA);
  gemm64<2><<<dim3(NB * (TT - 1)), 256, 0, stream>>>(Xbf, NSEb, CS, CS, HD, nullptr,
      nullptr, nullptr, nullptr, nullptr, rlse, emitb, text, w2c, bufA, scA);

  // balanced-tree product reduction: 256 -> 1 per sequence
  u16* s = bufA;  float* ss = scA;
  u16* d = bufB;  float* ds = scB;
  for (int U = 128; U >= 1; U >>= 1) {
    comb_k<<<NB * U, 256, 0, stream>>>(s, ss, d, ds, U);
    u16* tn = s; s = d; d = tn;
    float* tf = ss; ss = ds; ds = tf;
  }
  final_k<<<NB, 64, 0, stream>>>(s, ss, hlog, hlse, emitb, text, w2c, out);
}

// Round 4
// 314.448 us; speedup vs baseline: 2.2156x; 1.1849x over previous
//
#include <hip/hip_runtime.h>
#include <hip/hip_bf16.h>

// FactoredHmmLm forward on MI355X.
// Pipeline:
//  1. emb + residual MLPs (bf16 MFMA GEMMs, 8192x256x256) -> sh, x, nse, ph
//  2. start head logits + full-8192 logsumexp
//  3. transition row-logsumexp: dedicated 128x128-tile GEMM (global_load_lds staging,
//     XCD swizzle, exp2 epilogue, per-colblock partials + reduce)
//  4. emission: CSR cluster->words, MFMA 64x64 tiles (gathered Wp rows) + atomic exp-sum lse
//  5. per-(n,t) 64x64 linear-domain leaf matrices M_t = exp(tr + emit - m), bf16
//  6. balanced-tree product reduction (8 levels of 64x64x64 MFMA matmuls, per-level renorm)

using u16 = unsigned short;
typedef __attribute__((ext_vector_type(8))) short bh8;     // 8 bf16 (4 VGPRs)
typedef __attribute__((ext_vector_type(4))) float f32x4;
typedef __attribute__((ext_vector_type(8))) unsigned short u16x8;

#define HD 256
#define TT 256
#define NB 16
#define KCL 128
#define CS 8192
#define VV 10000
#define MAXB 320   // >= sum_c ceil(cnt_c/64) <= 10000/64 + 128 = 283
#define LOG2E 1.44269504f

__device__ __forceinline__ u16 f2bf(float v) {
  union { float f; unsigned int i; } u; u.f = v;
  unsigned int r = u.i + 0x7fffu + ((u.i >> 16) & 1u);   // RNE
  return (u16)(r >> 16);
}
__device__ __forceinline__ float bf2f(u16 u) {
  union { unsigned int i; float f; } x; x.i = ((unsigned int)u) << 16; return x.f;
}
__device__ __forceinline__ void gl2lds16(const u16* g, u16* l) {
  __builtin_amdgcn_global_load_lds(
      (const __attribute__((address_space(1))) unsigned int*)g,
      (__attribute__((address_space(3))) unsigned int*)l, 16, 0, 0);
}

// ---------------- small utility kernels ----------------

__global__ void cvt_k(const float* __restrict__ src, u16* __restrict__ dst, int n) {
  int i = blockIdx.x * 256 + threadIdx.x;
  if (i < n) dst[i] = f2bf(src[i]);
}

// E[k*64+s][h] = ec[k][h] + es[s][h]; writes f32 + bf16
__global__ void emb_k(const float* __restrict__ ec, const float* __restrict__ es,
                      float* __restrict__ ef, u16* __restrict__ ebf) {
  int idx = blockIdx.x * 256 + threadIdx.x;   // CS*HD total
  int h = idx & 255, row = idx >> 8;
  int k = row >> 6, s = row & 63;
  float v = ec[k * HD + h] + es[s * HD + h];
  ef[idx] = v;
  ebf[idx] = f2bf(v);
}

__global__ void log_k(const float* __restrict__ in, float* __restrict__ out, int n) {
  int i = blockIdx.x * 256 + threadIdx.x;
  if (i < n) out[i] = logf(in[i]);
}

// ---------------- CSR: cluster -> word list ----------------

__global__ void count_k(const int* __restrict__ w2c, int* __restrict__ counts) {
  int w = blockIdx.x * 256 + threadIdx.x;
  if (w < VV) atomicAdd(&counts[w2c[w]], 1);
}
__global__ void csr_scan_k(const int* __restrict__ counts, int* __restrict__ offs,
                           int* __restrict__ curs) {
  if (threadIdx.x == 0) {
    int acc = 0;
    for (int c = 0; c < KCL; ++c) { offs[c] = acc; curs[c] = acc; acc += counts[c]; }
    offs[KCL] = acc;
  }
}
__global__ void fill_k(const int* __restrict__ w2c, int* __restrict__ curs,
                       int* __restrict__ wlist) {
  int w = blockIdx.x * 256 + threadIdx.x;
  if (w < VV) { int p = atomicAdd(&curs[w2c[w]], 1); wlist[p] = w; }
}
// block list: entry = (c<<8)|blk_within_cluster, -1 past end
__global__ void map_k(const int* __restrict__ offs, int* __restrict__ map) {
  if (threadIdx.x == 0) {
    int idx = 0;
    for (int c = 0; c < KCL; ++c) {
      int nb = (offs[c + 1] - offs[c] + 63) >> 6;
      for (int b = 0; b < nb; ++b) map[idx++] = (c << 8) | b;
    }
    for (; idx < MAXB; ++idx) map[idx] = -1;
  }
}

// identity leaf at position 255 of each sequence (odd index -> transposed layout; I^T = I)
__global__ void idleaf_k(u16* __restrict__ buf, float* __restrict__ sc) {
  const int n = blockIdx.x, t = threadIdx.x;   // 64 threads, row t
  u16* node = buf + ((size_t)n * 256 + 255) * 4096;
  for (int c = 0; c < 64; ++c) node[t * 64 + c] = (c == t) ? (u16)0x3F80 : (u16)0;
  if (t == 0) sc[n * 256 + 255] = 0.f;
}

// ---------------- transition row-lse: 128x128-tile GEMM over [8192,8192,256] ----------
// part[bx][row] = sum over this block's 128 cols of exp(x_row . nse_col)

__global__ __launch_bounds__(256) void rlse_k(const u16* __restrict__ A,
                                              const u16* __restrict__ B,
                                              float* __restrict__ part) {
  __shared__ char lds[32768];          // A tile [128][64] @0, B tile @16384
  const int tid = threadIdx.x;
  const int lane = tid & 63, w = tid >> 6;
  const int wr = w >> 1, wc = w & 1;
  const int c0 = lane & 15, g = lane >> 4;

  int bid = blockIdx.x;                 // 4096 = 64x64 tiles; nwg%8==0 -> bijective
  bid = (bid & 7) * 512 + (bid >> 3);   // XCD-contiguous chunks
  const int by = bid >> 6, bx = bid & 63;
  const int rm = by * 128, cn = bx * 128;

  f32x4 acc[4][4];
#pragma unroll
  for (int i = 0; i < 4; ++i)
#pragma unroll
    for (int j = 0; j < 4; ++j) acc[i][j] = (f32x4){0.f, 0.f, 0.f, 0.f};

  for (int kc = 0; kc < HD; kc += 64) {
    if (kc) __syncthreads();
    // stage: LDS[r][cb] = global[r][cb ^ (r&7)] (16B chunk units) -> linear dest,
    // inverse-swizzled source; reads below XOR the same pattern.
#pragma unroll
    for (int i = 0; i < 4; ++i) {
      const int c = i * 256 + tid;            // chunk 0..1023
      const int r = c >> 3, cb = c & 7;
      const int gq = cb ^ (r & 7);
      gl2lds16(A + (size_t)(rm + r) * HD + kc + gq * 8, (u16*)&lds[c * 16]);
      gl2lds16(B + (size_t)(cn + r) * HD + kc + gq * 8, (u16*)&lds[16384 + c * 16]);
    }
    __syncthreads();
#pragma unroll
    for (int kk = 0; kk < 64; kk += 32) {
      const int kb = (kk + g * 8) * 2;
      bh8 af[4], bf[4];
#pragma unroll
      for (int mi = 0; mi < 4; ++mi) {
        const int ar = wr * 64 + mi * 16 + c0;
        af[mi] = *reinterpret_cast<const bh8*>(&lds[ar * 128 + (kb ^ ((ar & 7) << 4))]);
      }
#pragma unroll
      for (int nj = 0; nj < 4; ++nj) {
        const int br = wc * 64 + nj * 16 + c0;
        bf[nj] = *reinterpret_cast<const bh8*>(&lds[16384 + br * 128 + (kb ^ ((br & 7) << 4))]);
      }
#pragma unroll
      for (int mi = 0; mi < 4; ++mi)
#pragma unroll
        for (int nj = 0; nj < 4; ++nj)
          acc[mi][nj] = __builtin_amdgcn_mfma_f32_16x16x32_bf16(af[mi], bf[nj], acc[mi][nj], 0, 0, 0);
    }
  }

  // epilogue: row sums of exp over this block's 128 cols
  float rs[4][4];   // [mi][reg]
#pragma unroll
  for (int mi = 0; mi < 4; ++mi)
#pragma unroll
    for (int reg = 0; reg < 4; ++reg) {
      float s = 0.f;
#pragma unroll
      for (int nj = 0; nj < 4; ++nj) s += exp2f(acc[mi][nj][reg] * LOG2E);
      rs[mi][reg] = s;
    }
#pragma unroll
  for (int off = 1; off < 16; off <<= 1)
#pragma unroll
    for (int mi = 0; mi < 4; ++mi)
#pragma unroll
      for (int reg = 0; reg < 4; ++reg)
        rs[mi][reg] += __shfl_xor(rs[mi][reg], off, 64);
  __syncthreads();
  float* Lf = reinterpret_cast<float*>(lds);   // [128][2]
  if (c0 == 0) {
#pragma unroll
    for (int mi = 0; mi < 4; ++mi)
#pragma unroll
      for (int reg = 0; reg < 4; ++reg)
        Lf[(wr * 64 + mi * 16 + g * 4 + reg) * 2 + wc] = rs[mi][reg];
  }
  __syncthreads();
  if (tid < 128)
    part[(size_t)bx * CS + rm + tid] = Lf[tid * 2] + Lf[tid * 2 + 1];
}

// rlse[i] = log(sum_b part[b][i])
__global__ void rred_k(const float* __restrict__ part, float* __restrict__ rlse) {
  const int i = blockIdx.x * 256 + threadIdx.x;
  float s = 0.f;
#pragma unroll 8
  for (int b = 0; b < 64; ++b) s += part[(size_t)b * CS + i];
  rlse[i] = logf(s);
}

// ---------------- MFMA GEMM: C[m,n] = sum_k A[m,k]*B[n,k], 64x64 tile ----------------
// MODE 0: out = relu(acc + bias[n] (+ skip[m*256+n])) -> f32 and/or bf16
// MODE 2: per-(n,t) leaf: M = exp(acc - row_lse[m] + emit[n,t,j] - max), bf16, layout by parity

template<int MODE>
__global__ __launch_bounds__(256) void gemm64(
    const u16* __restrict__ A, const u16* __restrict__ B,
    int M, int N, int K,
    const float* __restrict__ bias, const float* __restrict__ skip,
    float* __restrict__ outf, u16* __restrict__ outbf,
    const float* __restrict__ row_lse, const float* __restrict__ emitb,
    const int* __restrict__ text, const int* __restrict__ w2c,
    u16* __restrict__ leafb, float* __restrict__ leafsc) {
  __shared__ char lds[16384];
  __shared__ float wmax[4];
  const int tid = threadIdx.x;
  const int lane = tid & 63;
  const int wid = tid >> 6;

  int rm, cn, nn = 0, ttv = 0;
  if (MODE == 2) {
    const int bi = blockIdx.x;
    nn = bi / (TT - 1);
    ttv = bi % (TT - 1) + 1;
    const int wp = text[nn * TT + ttv - 1];
    const int wc = text[nn * TT + ttv];
    rm = w2c[wp] * 64;
    cn = w2c[wc] * 64;
  } else {
    rm = blockIdx.y * 64;
    cn = blockIdx.x * 64;
  }
  const u16* Ag = A + (size_t)rm * K;
  const u16* Bg = B + (size_t)cn * K;

  f32x4 acc[4];
#pragma unroll
  for (int i = 0; i < 4; ++i) acc[i] = (f32x4){0.f, 0.f, 0.f, 0.f};

  const int sr = tid >> 3;          // staging row 0..31 (+32 for rep 1)
  const int scb = (tid & 7) * 16;   // staging byte-col within 128B row
  const int ra = wid * 16 + (lane & 15);
  const int rb0 = lane & 15;
  const int ko = (lane >> 4) * 8;   // fragment k-offset (elements)

  for (int kc = 0; kc < K; kc += 64) {
#pragma unroll
    for (int rep = 0; rep < 2; ++rep) {
      const int r = rep * 32 + sr;
      const bh8 va = *reinterpret_cast<const bh8*>(Ag + r * K + kc + (scb >> 1));
      *reinterpret_cast<bh8*>(&lds[r * 128 + (scb ^ ((r & 7) << 4))]) = va;
      const bh8 vb = *reinterpret_cast<const bh8*>(Bg + r * K + kc + (scb >> 1));
      *reinterpret_cast<bh8*>(&lds[8192 + r * 128 + (scb ^ ((r & 7) << 4))]) = vb;
    }
    __syncthreads();
#pragma unroll
    for (int kk = 0; kk < 64; kk += 32) {
      const int kb = (kk + ko) * 2;
      const bh8 af = *reinterpret_cast<const bh8*>(&lds[ra * 128 + (kb ^ ((ra & 7) << 4))]);
#pragma unroll
      for (int nj = 0; nj < 4; ++nj) {
        const int rb = nj * 16 + rb0;
        const bh8 bf = *reinterpret_cast<const bh8*>(&lds[8192 + rb * 128 + (kb ^ ((rb & 7) << 4))]);
        acc[nj] = __builtin_amdgcn_mfma_f32_16x16x32_bf16(af, bf, acc[nj], 0, 0, 0);
      }
    }
    __syncthreads();
  }

  // epilogues; C/D frag: col = lane&15, row = (lane>>4)*4 + reg
  const int g = lane >> 4, c0 = lane & 15;

  if (MODE == 0) {
#pragma unroll
    for (int nj = 0; nj < 4; ++nj) {
      const int nidx = cn + nj * 16 + c0;
      const float bv = bias ? bias[nidx] : 0.f;
#pragma unroll
      for (int reg = 0; reg < 4; ++reg) {
        const int midx = rm + wid * 16 + g * 4 + reg;
        float v = acc[nj][reg] + bv;
        if (skip) v += skip[(size_t)midx * 256 + nidx];
        v = fmaxf(v, 0.f);
        if (outf) outf[(size_t)midx * N + nidx] = v;
        if (outbf) outbf[(size_t)midx * N + nidx] = f2bf(v);
      }
    }
  } else {  // MODE 2: leaf matrix, layout by parity of leaf index (ttv-1)
    float L[4][4];
    float mx = -1e30f;
#pragma unroll
    for (int nj = 0; nj < 4; ++nj) {
      const float ev = emitb[((size_t)(nn * TT + ttv)) * 64 + nj * 16 + c0];
#pragma unroll
      for (int reg = 0; reg < 4; ++reg) {
        const float l = acc[nj][reg] - row_lse[rm + wid * 16 + g * 4 + reg] + ev;
        L[nj][reg] = l;
        mx = fmaxf(mx, l);
      }
    }
#pragma unroll
    for (int off = 1; off < 64; off <<= 1) mx = fmaxf(mx, __shfl_xor(mx, off, 64));
    if (lane == 0) wmax[wid] = mx;
    __syncthreads();
    const float m = fmaxf(fmaxf(wmax[0], wmax[1]), fmaxf(wmax[2], wmax[3]));
    float* ftile = reinterpret_cast<float*>(lds);
#pragma unroll
    for (int nj = 0; nj < 4; ++nj)
#pragma unroll
      for (int reg = 0; reg < 4; ++reg)
        ftile[(wid * 16 + g * 4 + reg) * 64 + nj * 16 + c0] = exp2f((L[nj][reg] - m) * LOG2E);
    __syncthreads();
    const int leaf = ttv - 1;                 // 0..254
    u16* node = leafb + ((size_t)nn * 256 + leaf) * 4096;
    const int rr = tid >> 2, cb = (tid & 3) * 16;
    u16x8 o0, o1;
    if ((leaf & 1) == 0) {                    // even -> row-major (left operand)
#pragma unroll
      for (int e = 0; e < 8; ++e) o0[e] = f2bf(ftile[rr * 64 + cb + e]);
#pragma unroll
      for (int e = 0; e < 8; ++e) o1[e] = f2bf(ftile[rr * 64 + cb + 8 + e]);
    } else {                                  // odd -> transposed (right operand)
#pragma unroll
      for (int e = 0; e < 8; ++e) o0[e] = f2bf(ftile[(cb + e) * 64 + rr]);
#pragma unroll
      for (int e = 0; e < 8; ++e) o1[e] = f2bf(ftile[(cb + 8 + e) * 64 + rr]);
    }
    *reinterpret_cast<u16x8*>(node + rr * 64 + cb) = o0;
    *reinterpret_cast<u16x8*>(node + rr * 64 + cb + 8) = o1;
    if (tid == 0) leafsc[nn * 256 + leaf] = m;
  }
}

// ---------------- tree combine: C = M_left * M_right (64x64x64), renorm, layout by parity ----

__global__ __launch_bounds__(256) void comb_k(const u16* __restrict__ src,
                                              const float* __restrict__ scs,
                                              u16* __restrict__ dst,
                                              float* __restrict__ scd, int U) {
  const int n = blockIdx.x / U, u = blockIdx.x % U;
  __shared__ char lds[16384];
  __shared__ float wmax[4];
  const int tid = threadIdx.x, lane = tid & 63, wid = tid >> 6;
  const u16* Anode = src + ((size_t)(n * 2 * U + 2 * u)) * 4096;
  const u16* Bnode = src + ((size_t)(n * 2 * U + 2 * u + 1)) * 4096;

  const int sr = tid >> 3, scb = (tid & 7) * 16;
#pragma unroll
  for (int rep = 0; rep < 2; ++rep) {
    const int r = rep * 32 + sr;
    const bh8 va = *reinterpret_cast<const bh8*>(Anode + r * 64 + (scb >> 1));
    *reinterpret_cast<bh8*>(&lds[r * 128 + (scb ^ ((r & 7) << 4))]) = va;
    const bh8 vb = *reinterpret_cast<const bh8*>(Bnode + r * 64 + (scb >> 1));
    *reinterpret_cast<bh8*>(&lds[8192 + r * 128 + (scb ^ ((r & 7) << 4))]) = vb;
  }
  __syncthreads();

  f32x4 acc[4];
#pragma unroll
  for (int i = 0; i < 4; ++i) acc[i] = (f32x4){0.f, 0.f, 0.f, 0.f};
  const int ra = wid * 16 + (lane & 15), rb0 = lane & 15, ko = (lane >> 4) * 8;
#pragma unroll
  for (int kk = 0; kk < 64; kk += 32) {
    const int kb = (kk + ko) * 2;
    const bh8 af = *reinterpret_cast<const bh8*>(&lds[ra * 128 + (kb ^ ((ra & 7) << 4))]);
#pragma unroll
    for (int nj = 0; nj < 4; ++nj) {
      const int rb = nj * 16 + rb0;
      const bh8 bf = *reinterpret_cast<const bh8*>(&lds[8192 + rb * 128 + (kb ^ ((rb & 7) << 4))]);
      acc[nj] = __builtin_amdgcn_mfma_f32_16x16x32_bf16(af, bf, acc[nj], 0, 0, 0);
    }
  }
  __syncthreads();

  const int g = lane >> 4, c0 = lane & 15;
  float mx = 0.f;
#pragma unroll
  for (int nj = 0; nj < 4; ++nj)
#pragma unroll
    for (int reg = 0; reg < 4; ++reg) mx = fmaxf(mx, acc[nj][reg]);
#pragma unroll
  for (int off = 1; off < 64; off <<= 1) mx = fmaxf(mx, __shfl_xor(mx, off, 64));
  if (lane == 0) wmax[wid] = mx;
  __syncthreads();
  const float m = fmaxf(fmaxf(wmax[0], wmax[1]), fmaxf(wmax[2], wmax[3]));
  const float inv = 1.0f / m;
  float* ftile = reinterpret_cast<float*>(lds);
#pragma unroll
  for (int nj = 0; nj < 4; ++nj)
#pragma unroll
    for (int reg = 0; reg < 4; ++reg)
      ftile[(wid * 16 + g * 4 + reg) * 64 + nj * 16 + c0] = acc[nj][reg] * inv;
  __syncthreads();

  u16* node = dst + ((size_t)(n * U + u)) * 4096;
  const int rr = tid >> 2, cb = (tid & 3) * 16;
  u16x8 o0, o1;
  if ((u & 1) == 0) {
#pragma unroll
    for (int e = 0; e < 8; ++e) o0[e] = f2bf(ftile[rr * 64 + cb + e]);
#pragma unroll
    for (int e = 0; e < 8; ++e) o1[e] = f2bf(ftile[rr * 64 + cb + 8 + e]);
  } else {
#pragma unroll
    for (int e = 0; e < 8; ++e) o0[e] = f2bf(ftile[(cb + e) * 64 + rr]);
#pragma unroll
    for (int e = 0; e < 8; ++e) o1[e] = f2bf(ftile[(cb + 8 + e) * 64 + rr]);
  }
  *reinterpret_cast<u16x8*>(node + rr * 64 + cb) = o0;
  *reinterpret_cast<u16x8*>(node + rr * 64 + cb + 8) = o1;
  if (tid == 0)
    scd[n * U + u] = scs[n * 2 * U + 2 * u] + scs[n * 2 * U + 2 * u + 1] + logf(m);
}

// ---------------- final: out[n] = m0 + scale + log(sum_i a0lin[i] * rowsum_i(P)) -------------

__global__ __launch_bounds__(64) void final_k(const u16* __restrict__ root,
                                              const float* __restrict__ rsc,
                                              const float* __restrict__ hlog,
                                              const float* __restrict__ hlse,
                                              const float* __restrict__ emitb,
                                              const int* __restrict__ text,
                                              const int* __restrict__ w2c,
                                              float* __restrict__ out) {
  const int n = blockIdx.x, i = threadIdx.x;
  const int w0 = text[n * TT];
  float a0 = hlog[w2c[w0] * 64 + i] - hlse[0] + emitb[((size_t)(n * TT)) * 64 + i];
  float m0 = a0;
  for (int off = 32; off; off >>= 1) m0 = fmaxf(m0, __shfl_xor(m0, off, 64));
  const float lin = expf(a0 - m0);
  const u16* row = root + (size_t)n * 4096 + i * 64;   // root: row-major (even index)
  float rs = 0.f;
#pragma unroll
  for (int e8 = 0; e8 < 8; ++e8) {
    const u16x8 v = *reinterpret_cast<const u16x8*>(row + e8 * 8);
#pragma unroll
    for (int e = 0; e < 8; ++e) rs += bf2f(v[e]);
  }
  float v = lin * rs;
  for (int off = 32; off; off >>= 1) v += __shfl_xor(v, off, 64);
  if (i == 0) out[n] = m0 + rsc[n] + logf(v);
}

// ---------------- emission GEMM: per 64-word block of a cluster ----------------

__global__ __launch_bounds__(256) void emis_k(
    const u16* __restrict__ Wpb, const u16* __restrict__ PHb,
    const float* __restrict__ bp,
    const int* __restrict__ offs, const int* __restrict__ wlist,
    const int* __restrict__ map,
    float* __restrict__ esum, float* __restrict__ logits_all) {
  const int ent = map[blockIdx.x];
  if (ent < 0) return;
  const int c = ent >> 8, blk = ent & 255;
  __shared__ char lds[16384];
  __shared__ int wid_s[64];
  const int tid = threadIdx.x, lane = tid & 63, wid = tid >> 6;
  const int st = offs[c], cnt = offs[c + 1] - st;
  if (tid < 64) {
    const int idx = blk * 64 + tid;
    wid_s[tid] = (idx < cnt) ? wlist[st + idx] : -1;
  }
  __syncthreads();

  f32x4 acc[4];
#pragma unroll
  for (int i = 0; i < 4; ++i) acc[i] = (f32x4){0.f, 0.f, 0.f, 0.f};

  const int sr = tid >> 3;
  const int scb = (tid & 7) * 16;
  const int ra = wid * 16 + (lane & 15);
  const int rb0 = lane & 15;
  const int ko = (lane >> 4) * 8;
  const u16* Bg = PHb + (size_t)(c * 64) * HD;

  for (int kc = 0; kc < HD; kc += 64) {
#pragma unroll
    for (int rep = 0; rep < 2; ++rep) {
      const int r = rep * 32 + sr;
      const int w = max(wid_s[r], 0);
      const bh8 va = *reinterpret_cast<const bh8*>(Wpb + (size_t)w * HD + kc + (scb >> 1));
      *reinterpret_cast<bh8*>(&lds[r * 128 + (scb ^ ((r & 7) << 4))]) = va;
      const bh8 vb = *reinterpret_cast<const bh8*>(Bg + r * HD + kc + (scb >> 1));
      *reinterpret_cast<bh8*>(&lds[8192 + r * 128 + (scb ^ ((r & 7) << 4))]) = vb;
    }
    __syncthreads();
#pragma unroll
    for (int kk = 0; kk < 64; kk += 32) {
      const int kb = (kk + ko) * 2;
      const bh8 af = *reinterpret_cast<const bh8*>(&lds[ra * 128 + (kb ^ ((ra & 7) << 4))]);
#pragma unroll
      for (int nj = 0; nj < 4; ++nj) {
        const int rb = nj * 16 + rb0;
        const bh8 bf = *reinterpret_cast<const bh8*>(&lds[8192 + rb * 128 + (kb ^ ((rb & 7) << 4))]);
        acc[nj] = __builtin_amdgcn_mfma_f32_16x16x32_bf16(af, bf, acc[nj], 0, 0, 0);
      }
    }
    __syncthreads();
  }

  const int g = lane >> 4, c0 = lane & 15;
#pragma unroll
  for (int nj = 0; nj < 4; ++nj) {
    float se = 0.f;
#pragma unroll
    for (int reg = 0; reg < 4; ++reg) {
      const int row = wid * 16 + g * 4 + reg;
      const int w = wid_s[row];
      if (w >= 0) {
        const float lg = acc[nj][reg] + bp[w];
        logits_all[(size_t)w * 64 + nj * 16 + c0] = lg;
        se += expf(lg);
      }
    }
    se += __shfl_xor(se, 16, 64);
    se += __shfl_xor(se, 32, 64);
    if (g == 0) atomicAdd(&esum[c * 64 + nj * 16 + c0], se);
  }
}

// ---------------- start head ----------------

__global__ __launch_bounds__(256) void head_dot_k(const float* __restrict__ sh,
                                                  const float* __restrict__ wv,
                                                  const float* __restrict__ bv,
                                                  float* __restrict__ logits) {
  const int tid = threadIdx.x, lane = tid & 63, wid = tid >> 6;
  const int row = blockIdx.x * 4 + wid;
  float s = 0.f;
#pragma unroll
  for (int q = 0; q < 4; ++q)
    s += sh[(size_t)row * HD + q * 64 + lane] * wv[q * 64 + lane];
  for (int off = 32; off; off >>= 1) s += __shfl_xor(s, off, 64);
  if (lane == 0) logits[row] = s + bv[0];
}

__global__ __launch_bounds__(1024) void head_lse_k(const float* __restrict__ logits,
                                                   float* __restrict__ out_lse) {
  __shared__ float red[16];
  __shared__ float mshared;
  const int tid = threadIdx.x;
  float m = -1e30f;
  for (int i = tid; i < CS; i += 1024) m = fmaxf(m, logits[i]);
  for (int off = 32; off; off >>= 1) m = fmaxf(m, __shfl_xor(m, off, 64));
  if ((tid & 63) == 0) red[tid >> 6] = m;
  __syncthreads();
  if (tid == 0) {
    float x = red[0];
    for (int i = 1; i < 16; ++i) x = fmaxf(x, red[i]);
    mshared = x;
  }
  __syncthreads();
  const float M = mshared;
  float s = 0.f;
  for (int i = tid; i < CS; i += 1024) s += expf(logits[i] - M);
  for (int off = 32; off; off >>= 1) s += __shfl_xor(s, off, 64);
  if ((tid & 63) == 0) red[tid >> 6] = s;
  __syncthreads();
  if (tid == 0) {
    float x = 0.f;
    for (int i = 0; i < 16; ++i) x += red[i];
    out_lse[0] = M + logf(x);
  }
}

__global__ void emit_k(const int* __restrict__ text, const int* __restrict__ w2c,
                       const float* __restrict__ lall, const float* __restrict__ lterm,
                       float* __restrict__ emitb) {
  const int idx = blockIdx.x * 256 + threadIdx.x;  // NB*TT*64
  const int s = idx & 63, nt = idx >> 6;
  const int w = text[nt];
  emitb[idx] = lall[(size_t)w * 64 + s] - lterm[w2c[w] * 64 + s];
}

// ---------------- host orchestration ----------------

extern "C" void kernel_launch(void* const* d_in, const int* in_sizes, int n_in,
                              void* d_out, int out_size, void* d_ws, size_t ws_size,
                              hipStream_t stream) {
  (void)in_sizes; (void)n_in; (void)out_size; (void)ws_size;
  const int* text = (const int*)d_in[0];
  const int* w2c  = (const int*)d_in[1];
  const float* sec = (const float*)d_in[2];
  const float* ses = (const float*)d_in[3];
  const float* stc = (const float*)d_in[4];
  const float* sts = (const float*)d_in[5];
  const float* nec = (const float*)d_in[6];
  const float* nes = (const float*)d_in[7];
  const float* pec = (const float*)d_in[8];
  const float* pes = (const float*)d_in[9];
  const float* srw1 = (const float*)d_in[10];
  const float* srb1 = (const float*)d_in[11];
  const float* srw2 = (const float*)d_in[12];
  const float* srb2 = (const float*)d_in[13];
  const float* trw1 = (const float*)d_in[14];
  const float* trb1 = (const float*)d_in[15];
  const float* trw2 = (const float*)d_in[16];
  const float* trb2 = (const float*)d_in[17];
  const float* tew1 = (const float*)d_in[18];
  const float* teb1 = (const float*)d_in[19];
  const float* tew2 = (const float*)d_in[20];
  const float* teb2 = (const float*)d_in[21];
  const float* sow = (const float*)d_in[22];
  const float* sob = (const float*)d_in[23];
  const float* tpw = (const float*)d_in[24];
  const float* tpb = (const float*)d_in[25];
  float* out = (float*)d_out;

  char* p = (char*)d_ws;
  auto carve = [&](size_t bytes) -> char* {
    char* r = p; p += (bytes + 255) & ~(size_t)255; return r;
  };
  float* Ef   = (float*)carve((size_t)CS * HD * 4);
  u16*   Ebf  = (u16*)  carve((size_t)CS * HD * 2);
  u16*   Hbf  = (u16*)  carve((size_t)CS * HD * 2);
  float* SHf  = (float*)carve((size_t)CS * HD * 4);
  u16*   Xbf  = (u16*)  carve((size_t)CS * HD * 2);
  u16*   NSEb = (u16*)  carve((size_t)CS * HD * 2);
  u16*   PHb  = (u16*)  carve((size_t)CS * HD * 2);
  u16*   Wpb  = (u16*)  carve((size_t)VV * HD * 2);
  u16*   Wb[6];
  for (int i = 0; i < 6; ++i) Wb[i] = (u16*)carve((size_t)HD * HD * 2);
  float* hlog  = (float*)carve(CS * 4);
  float* hlse  = (float*)carve(256);
  float* part  = (float*)carve((size_t)64 * CS * 4);
  float* rlse  = (float*)carve(CS * 4);
  int* counts  = (int*)carve(KCL * 4);
  int* offs    = (int*)carve((KCL + 1) * 4);
  int* curs    = (int*)carve(KCL * 4);
  int* wlist   = (int*)carve(VV * 4);
  int* bmap    = (int*)carve(MAXB * 4);
  float* esum  = (float*)carve(CS * 4);
  float* lterm = (float*)carve(CS * 4);
  float* lall  = (float*)carve((size_t)VV * 64 * 4);
  float* emitb = (float*)carve((size_t)NB * TT * 64 * 4);
  u16*   bufA  = (u16*)carve((size_t)NB * 256 * 4096 * 2);   // tree ping (leaves)
  u16*   bufB  = (u16*)carve((size_t)NB * 128 * 4096 * 2);   // tree pong
  float* scA   = (float*)carve((size_t)NB * 256 * 4);
  float* scB   = (float*)carve((size_t)NB * 128 * 4);

  hipMemsetAsync(esum, 0, CS * 4, stream);
  hipMemsetAsync(counts, 0, KCL * 4, stream);

  // weight conversions
  const float* wsrc[6] = {srw1, srw2, trw1, trw2, tew1, tew2};
  for (int i = 0; i < 6; ++i)
    cvt_k<<<(HD * HD + 255) / 256, 256, 0, stream>>>(wsrc[i], Wb[i], HD * HD);
  cvt_k<<<(VV * HD + 255) / 256, 256, 0, stream>>>(tpw, Wpb, VV * HD);

  // CSR cluster->words + block map
  count_k<<<(VV + 255) / 256, 256, 0, stream>>>(w2c, counts);
  csr_scan_k<<<1, 64, 0, stream>>>(counts, offs, curs);
  fill_k<<<(VV + 255) / 256, 256, 0, stream>>>(w2c, curs, wlist);
  map_k<<<1, 64, 0, stream>>>(offs, bmap);

  const dim3 gMLP(4, 128);

  // start: sh = residual(emb) ; head logits ; lse
  emb_k<<<CS * HD / 256, 256, 0, stream>>>(sec, ses, Ef, Ebf);
  gemm64<0><<<gMLP, 256, 0, stream>>>(Ebf, Wb[0], CS, HD, HD, srb1, nullptr,
      nullptr, Hbf, nullptr, nullptr, nullptr, nullptr, nullptr, nullptr);
  gemm64<0><<<gMLP, 256, 0, stream>>>(Hbf, Wb[1], CS, HD, HD, srb2, Ef,
      SHf, nullptr, nullptr, nullptr, nullptr, nullptr, nullptr, nullptr);
  head_dot_k<<<CS / 4, 256, 0, stream>>>(SHf, sow, sob, hlog);
  head_lse_k<<<1, 1024, 0, stream>>>(hlog, hlse);

  // trans: x = residual(emb(state)); nse = emb(next)
  emb_k<<<CS * HD / 256, 256, 0, stream>>>(stc, sts, Ef, Ebf);
  gemm64<0><<<gMLP, 256, 0, stream>>>(Ebf, Wb[2], CS, HD, HD, trb1, nullptr,
      nullptr, Hbf, nullptr, nullptr, nullptr, nullptr, nullptr, nullptr);
  gemm64<0><<<gMLP, 256, 0, stream>>>(Hbf, Wb[3], CS, HD, HD, trb2, Ef,
      nullptr, Xbf, nullptr, nullptr, nullptr, nullptr, nullptr, nullptr);
  emb_k<<<CS * HD / 256, 256, 0, stream>>>(nec, nes, Ef, NSEb);  // Ef is scratch here

  // term: ph = residual(emb(pre)) -> bf16
  emb_k<<<CS * HD / 256, 256, 0, stream>>>(pec, pes, Ef, Ebf);
  gemm64<0><<<gMLP, 256, 0, stream>>>(Ebf, Wb[4], CS, HD, HD, teb1, nullptr,
      nullptr, Hbf, nullptr, nullptr, nullptr, nullptr, nullptr, nullptr);
  gemm64<0><<<gMLP, 256, 0, stream>>>(Hbf, Wb[5], CS, HD, HD, teb2, Ef,
      nullptr, PHb, nullptr, nullptr, nullptr, nullptr, nullptr, nullptr);

  // transition row-logsumexp: 128x128 tiles + reduce
  rlse_k<<<4096, 256, 0, stream>>>(Xbf, NSEb, part);
  rred_k<<<CS / 256, 256, 0, stream>>>(part, rlse);

  // emission: MFMA tiles + masked lse
  emis_k<<<MAXB, 256, 0, stream>>>(Wpb, PHb, tpb, offs, wlist, bmap, esum, lall);
  log_k<<<CS / 256, 256, 0, stream>>>(esum, lterm, CS);
  emit_k<<<NB * TT * 64 / 256, 256, 0, stream>>>(text, w2c, lall, lterm, emitb);

  // leaves: 255 real + 1 identity per sequence
  idleaf_k<<<NB, 64, 0, stream>>>(bufA, scA);
  gemm64<2><<<dim3(NB * (TT - 1)), 256, 0, stream>>>(Xbf, NSEb, CS, CS, HD, nullptr,
      nullptr, nullptr, nullptr, rlse, emitb, text, w2c, bufA, scA);

  // balanced-tree product reduction: 256 -> 1 per sequence
  u16* s = bufA;  float* ss = scA;
  u16* d = bufB;  float* ds = scB;
  for (int U = 128; U >= 1; U >>= 1) {
    comb_k<<<NB * U, 256, 0, stream>>>(s, ss, d, ds, U);
    u16* tn = s; s = d; d = tn;
    float* tf = ss; ss = ds; ds = tf;
  }
  final_k<<<NB, 64, 0, stream>>>(s, ss, hlog, hlse, emitb, text, w2c, out);
}

// Round 5
// 261.131 us; speedup vs baseline: 2.6680x; 1.2042x over previous
//
#include <hip/hip_runtime.h>
#include <hip/hip_bf16.h>

// FactoredHmmLm forward on MI355X.
//  1. fused cvt (all weights -> bf16), fused emb (4 embeddings -> bf16)
//  2. residual MLPs via gemm64 (global_load_lds staging), bf16 skip
//  3. transition row-logsumexp: 128x128-tile GEMM (gl2lds, XCD swizzle, exp2)
//  4. emission: CSR (one-block build), MFMA 64-word blocks + atomic exp-sum
//  5. per-(n,t) leaf matrices M_t = exp(tr + emit - m), bf16, parity layout
//  6. quad-tree product reduction: 4 levels of (M0*M1)*(M2*M3) per block + final

using u16 = unsigned short;
typedef __attribute__((ext_vector_type(8))) short bh8;     // 8 bf16 (4 VGPRs)
typedef __attribute__((ext_vector_type(4))) float f32x4;
typedef __attribute__((ext_vector_type(8))) unsigned short u16x8;

#define HD 256
#define TT 256
#define NB 16
#define KCL 128
#define CS 8192
#define VV 10000
#define MAXB 320
#define LOG2E 1.44269504f

__device__ __forceinline__ u16 f2bf(float v) {
  union { float f; unsigned int i; } u; u.f = v;
  unsigned int r = u.i + 0x7fffu + ((u.i >> 16) & 1u);   // RNE
  return (u16)(r >> 16);
}
__device__ __forceinline__ float bf2f(u16 u) {
  union { unsigned int i; float f; } x; x.i = ((unsigned int)u) << 16; return x.f;
}
__device__ __forceinline__ void gl2lds16(const u16* g, u16* l) {
  __builtin_amdgcn_global_load_lds(
      (const __attribute__((address_space(1))) unsigned int*)g,
      (__attribute__((address_space(3))) unsigned int*)l, 16, 0, 0);
}

// ---------------- fused conversions ----------------

// dstW: contiguous [6*65536 weights | VV*HD term_proj] bf16
__global__ void cvt_all_k(const float* __restrict__ w0, const float* __restrict__ w1,
                          const float* __restrict__ w2, const float* __restrict__ w3,
                          const float* __restrict__ w4, const float* __restrict__ w5,
                          const float* __restrict__ tpw, u16* __restrict__ dstW) {
  const int idx = blockIdx.x * 256 + threadIdx.x;
  const int WTOT = 6 * 65536;
  float v;
  if (idx < WTOT) {
    const int i = idx >> 16, o = idx & 65535;
    const float* s = i == 0 ? w0 : i == 1 ? w1 : i == 2 ? w2 : i == 3 ? w3 : i == 4 ? w4 : w5;
    v = s[o];
  } else {
    const int o = idx - WTOT;
    if (o >= VV * HD) return;
    v = tpw[o];
  }
  dstW[idx] = f2bf(v);
}

// 4 embeddings -> bf16: E[k*64+s][h] = ec[k][h] + es[s][h]
__global__ void emb_all_k(const float* __restrict__ ec0, const float* __restrict__ es0, u16* __restrict__ d0,
                          const float* __restrict__ ec1, const float* __restrict__ es1, u16* __restrict__ d1,
                          const float* __restrict__ ec2, const float* __restrict__ es2, u16* __restrict__ d2,
                          const float* __restrict__ ec3, const float* __restrict__ es3, u16* __restrict__ d3) {
  const int idx = blockIdx.x * 256 + threadIdx.x;   // 4 * CS*HD
  const int seg = idx >> 21;
  const int off = idx & ((CS * HD) - 1);
  const int h = off & 255, row = off >> 8;
  const int k = row >> 6, s = row & 63;
  const float* ec = seg == 0 ? ec0 : seg == 1 ? ec1 : seg == 2 ? ec2 : ec3;
  const float* es = seg == 0 ? es0 : seg == 1 ? es1 : seg == 2 ? es2 : es3;
  u16* d = seg == 0 ? d0 : seg == 1 ? d1 : seg == 2 ? d2 : d3;
  d[off] = f2bf(ec[k * HD + h] + es[s * HD + h]);
}

// ---------------- CSR build (single block) ----------------

__global__ __launch_bounds__(256) void csr_all_k(const int* __restrict__ w2c,
                                                 int* __restrict__ offs,
                                                 int* __restrict__ wlist,
                                                 int* __restrict__ bmap) {
  __shared__ int cnt[KCL], cur[KCL], off_s[KCL + 1];
  const int tid = threadIdx.x;
  if (tid < KCL) cnt[tid] = 0;
  __syncthreads();
  for (int w = tid; w < VV; w += 256) atomicAdd(&cnt[w2c[w]], 1);
  __syncthreads();
  if (tid == 0) {
    int acc = 0;
    for (int c = 0; c < KCL; ++c) { off_s[c] = acc; acc += cnt[c]; }
    off_s[KCL] = acc;
    int idx = 0;
    for (int c = 0; c < KCL; ++c) {
      const int nb = (cnt[c] + 63) >> 6;
      for (int b = 0; b < nb; ++b) bmap[idx++] = (c << 8) | b;
    }
    for (; idx < MAXB; ++idx) bmap[idx] = -1;
  }
  __syncthreads();
  if (tid < KCL) cur[tid] = off_s[tid];
  if (tid <= KCL) offs[tid] = off_s[tid];
  __syncthreads();
  for (int w = tid; w < VV; w += 256) {
    const int p = atomicAdd(&cur[w2c[w]], 1);
    wlist[p] = w;
  }
}

// identity leaf at position 255 of each sequence (odd index -> transposed; I^T = I)
__global__ void idleaf_k(u16* __restrict__ buf, float* __restrict__ sc) {
  const int n = blockIdx.x, t = threadIdx.x;
  u16* node = buf + ((size_t)n * 256 + 255) * 4096;
  for (int c = 0; c < 64; ++c) node[t * 64 + c] = (c == t) ? (u16)0x3F80 : (u16)0;
  if (t == 0) sc[n * 256 + 255] = 0.f;
}

// ---------------- transition row-lse: 128x128-tile GEMM ----------

__global__ __launch_bounds__(256) void rlse_k(const u16* __restrict__ A,
                                              const u16* __restrict__ B,
                                              float* __restrict__ part) {
  __shared__ char lds[32768];
  const int tid = threadIdx.x;
  const int lane = tid & 63, w = tid >> 6;
  const int wr = w >> 1, wc = w & 1;
  const int c0 = lane & 15, g = lane >> 4;

  int bid = blockIdx.x;
  bid = (bid & 7) * 512 + (bid >> 3);   // XCD swizzle (4096 % 8 == 0)
  const int by = bid >> 6, bx = bid & 63;
  const int rm = by * 128, cn = bx * 128;

  f32x4 acc[4][4];
#pragma unroll
  for (int i = 0; i < 4; ++i)
#pragma unroll
    for (int j = 0; j < 4; ++j) acc[i][j] = (f32x4){0.f, 0.f, 0.f, 0.f};

  for (int kc = 0; kc < HD; kc += 64) {
    if (kc) __syncthreads();
#pragma unroll
    for (int i = 0; i < 4; ++i) {
      const int c = i * 256 + tid;
      const int r = c >> 3, cb = c & 7;
      const int gq = cb ^ (r & 7);
      gl2lds16(A + (size_t)(rm + r) * HD + kc + gq * 8, (u16*)&lds[c * 16]);
      gl2lds16(B + (size_t)(cn + r) * HD + kc + gq * 8, (u16*)&lds[16384 + c * 16]);
    }
    __syncthreads();
#pragma unroll
    for (int kk = 0; kk < 64; kk += 32) {
      const int kb = (kk + g * 8) * 2;
      bh8 af[4], bf[4];
#pragma unroll
      for (int mi = 0; mi < 4; ++mi) {
        const int ar = wr * 64 + mi * 16 + c0;
        af[mi] = *reinterpret_cast<const bh8*>(&lds[ar * 128 + (kb ^ ((ar & 7) << 4))]);
      }
#pragma unroll
      for (int nj = 0; nj < 4; ++nj) {
        const int br = wc * 64 + nj * 16 + c0;
        bf[nj] = *reinterpret_cast<const bh8*>(&lds[16384 + br * 128 + (kb ^ ((br & 7) << 4))]);
      }
#pragma unroll
      for (int mi = 0; mi < 4; ++mi)
#pragma unroll
        for (int nj = 0; nj < 4; ++nj)
          acc[mi][nj] = __builtin_amdgcn_mfma_f32_16x16x32_bf16(af[mi], bf[nj], acc[mi][nj], 0, 0, 0);
    }
  }

  float rs[4][4];
#pragma unroll
  for (int mi = 0; mi < 4; ++mi)
#pragma unroll
    for (int reg = 0; reg < 4; ++reg) {
      float s = 0.f;
#pragma unroll
      for (int nj = 0; nj < 4; ++nj) s += exp2f(acc[mi][nj][reg] * LOG2E);
      rs[mi][reg] = s;
    }
#pragma unroll
  for (int off = 1; off < 16; off <<= 1)
#pragma unroll
    for (int mi = 0; mi < 4; ++mi)
#pragma unroll
      for (int reg = 0; reg < 4; ++reg)
        rs[mi][reg] += __shfl_xor(rs[mi][reg], off, 64);
  __syncthreads();
  float* Lf = reinterpret_cast<float*>(lds);
  if (c0 == 0) {
#pragma unroll
    for (int mi = 0; mi < 4; ++mi)
#pragma unroll
      for (int reg = 0; reg < 4; ++reg)
        Lf[(wr * 64 + mi * 16 + g * 4 + reg) * 2 + wc] = rs[mi][reg];
  }
  __syncthreads();
  if (tid < 128)
    part[(size_t)bx * CS + rm + tid] = Lf[tid * 2] + Lf[tid * 2 + 1];
}

__global__ void rred_k(const float* __restrict__ part, float* __restrict__ rlse) {
  const int i = blockIdx.x * 256 + threadIdx.x;
  float s = 0.f;
#pragma unroll 8
  for (int b = 0; b < 64; ++b) s += part[(size_t)b * CS + i];
  rlse[i] = logf(s);
}

// ---------------- MFMA GEMM 64x64 tile (gl2lds staging) ----------------
// MODE 0: out = relu(acc + bias[n] (+ bf16 skip)) -> f32 and/or bf16
// MODE 2: leaf: M = exp(acc - row_lse[m] + emit - max), bf16, parity layout

template<int MODE>
__global__ __launch_bounds__(256) void gemm64(
    const u16* __restrict__ A, const u16* __restrict__ B,
    int N, int K,
    const float* __restrict__ bias, const u16* __restrict__ skip,
    float* __restrict__ outf, u16* __restrict__ outbf,
    const float* __restrict__ row_lse, const float* __restrict__ emitb,
    const int* __restrict__ text, const int* __restrict__ w2c,
    u16* __restrict__ leafb, float* __restrict__ leafsc) {
  __shared__ char lds[16384];
  __shared__ float wmax[4];
  const int tid = threadIdx.x;
  const int lane = tid & 63;
  const int wid = tid >> 6;

  int rm, cn, nn = 0, ttv = 0;
  if (MODE == 2) {
    const int bi = blockIdx.x;
    nn = bi / (TT - 1);
    ttv = bi % (TT - 1) + 1;
    rm = w2c[text[nn * TT + ttv - 1]] * 64;
    cn = w2c[text[nn * TT + ttv]] * 64;
  } else {
    rm = blockIdx.y * 64;
    cn = blockIdx.x * 64;
  }
  const u16* Ag = A + (size_t)rm * K;
  const u16* Bg = B + (size_t)cn * K;

  f32x4 acc[4];
#pragma unroll
  for (int i = 0; i < 4; ++i) acc[i] = (f32x4){0.f, 0.f, 0.f, 0.f};

  const int ra = wid * 16 + (lane & 15);
  const int rb0 = lane & 15;
  const int ko = (lane >> 4) * 8;

  for (int kc = 0; kc < K; kc += 64) {
    if (kc) __syncthreads();
#pragma unroll
    for (int i = 0; i < 2; ++i) {
      const int c = i * 256 + tid;          // chunk 0..511
      const int r = c >> 3, cb = c & 7;
      const int gq = cb ^ (r & 7);
      gl2lds16(Ag + (size_t)r * K + kc + gq * 8, (u16*)&lds[c * 16]);
      gl2lds16(Bg + (size_t)r * K + kc + gq * 8, (u16*)&lds[8192 + c * 16]);
    }
    __syncthreads();
#pragma unroll
    for (int kk = 0; kk < 64; kk += 32) {
      const int kb = (kk + ko) * 2;
      const bh8 af = *reinterpret_cast<const bh8*>(&lds[ra * 128 + (kb ^ ((ra & 7) << 4))]);
#pragma unroll
      for (int nj = 0; nj < 4; ++nj) {
        const int rb = nj * 16 + rb0;
        const bh8 bf = *reinterpret_cast<const bh8*>(&lds[8192 + rb * 128 + (kb ^ ((rb & 7) << 4))]);
        acc[nj] = __builtin_amdgcn_mfma_f32_16x16x32_bf16(af, bf, acc[nj], 0, 0, 0);
      }
    }
  }

  const int g = lane >> 4, c0 = lane & 15;

  if (MODE == 0) {
#pragma unroll
    for (int nj = 0; nj < 4; ++nj) {
      const int nidx = cn + nj * 16 + c0;
      const float bv = bias[nidx];
#pragma unroll
      for (int reg = 0; reg < 4; ++reg) {
        const int midx = rm + wid * 16 + g * 4 + reg;
        float v = acc[nj][reg] + bv;
        if (skip) v += bf2f(skip[(size_t)midx * 256 + nidx]);
        v = fmaxf(v, 0.f);
        if (outf) outf[(size_t)midx * N + nidx] = v;
        if (outbf) outbf[(size_t)midx * N + nidx] = f2bf(v);
      }
    }
  } else {
    float L[4][4];
    float mx = -1e30f;
#pragma unroll
    for (int nj = 0; nj < 4; ++nj) {
      const float ev = emitb[((size_t)(nn * TT + ttv)) * 64 + nj * 16 + c0];
#pragma unroll
      for (int reg = 0; reg < 4; ++reg) {
        const float l = acc[nj][reg] - row_lse[rm + wid * 16 + g * 4 + reg] + ev;
        L[nj][reg] = l;
        mx = fmaxf(mx, l);
      }
    }
#pragma unroll
    for (int off = 1; off < 64; off <<= 1) mx = fmaxf(mx, __shfl_xor(mx, off, 64));
    if (lane == 0) wmax[wid] = mx;
    __syncthreads();
    const float m = fmaxf(fmaxf(wmax[0], wmax[1]), fmaxf(wmax[2], wmax[3]));
    float* ftile = reinterpret_cast<float*>(lds);
#pragma unroll
    for (int nj = 0; nj < 4; ++nj)
#pragma unroll
      for (int reg = 0; reg < 4; ++reg)
        ftile[(wid * 16 + g * 4 + reg) * 64 + nj * 16 + c0] = exp2f((L[nj][reg] - m) * LOG2E);
    __syncthreads();
    const int leaf = ttv - 1;
    u16* node = leafb + ((size_t)nn * 256 + leaf) * 4096;
    const int rr = tid >> 2, cb = (tid & 3) * 16;
    u16x8 o0, o1;
    if ((leaf & 1) == 0) {
#pragma unroll
      for (int e = 0; e < 8; ++e) o0[e] = f2bf(ftile[rr * 64 + cb + e]);
#pragma unroll
      for (int e = 0; e < 8; ++e) o1[e] = f2bf(ftile[rr * 64 + cb + 8 + e]);
    } else {
#pragma unroll
      for (int e = 0; e < 8; ++e) o0[e] = f2bf(ftile[(cb + e) * 64 + rr]);
#pragma unroll
      for (int e = 0; e < 8; ++e) o1[e] = f2bf(ftile[(cb + 8 + e) * 64 + rr]);
    }
    *reinterpret_cast<u16x8*>(node + rr * 64 + cb) = o0;
    *reinterpret_cast<u16x8*>(node + rr * 64 + cb + 8) = o1;
    if (tid == 0) leafsc[nn * 256 + leaf] = m;
  }
}

// ---------------- quad-tree combine: out = (M0*M1)*(M2*M3) ----------------
// src: 4U nodes/seq (even=row-major, odd=transposed). dst: U nodes/seq (parity of u).

__global__ __launch_bounds__(256) void comb4_k(const u16* __restrict__ src,
                                               const float* __restrict__ scs,
                                               u16* __restrict__ dst,
                                               float* __restrict__ scd, int U) {
  const int n = blockIdx.x / U, u = blockIdx.x % U;
  __shared__ char lds[49152];   // M0@0 M1@8K M2@16K M3@24K | P1@32K P2@40K
  __shared__ float wpm[8];
  const int tid = threadIdx.x, lane = tid & 63, w = tid >> 6;
  const u16* base = src + ((size_t)(n * 4 * U + 4 * u)) * 4096;
  const int sr = tid >> 3, scb = (tid & 7) * 16;
#pragma unroll
  for (int nd = 0; nd < 4; ++nd)
#pragma unroll
    for (int rep = 0; rep < 2; ++rep) {
      const int r = rep * 32 + sr;
      const bh8 v = *reinterpret_cast<const bh8*>(base + nd * 4096 + r * 64 + (scb >> 1));
      *reinterpret_cast<bh8*>(&lds[nd * 8192 + r * 128 + (scb ^ ((r & 7) << 4))]) = v;
    }
  __syncthreads();

  // step A: waves 0,1 -> P1 = M0*M1 (rows h*32..+32); waves 2,3 -> P2 = M2*M3
  const int p = w >> 1, h = w & 1;
  const int abase = p * 16384, bbase = abase + 8192;
  const int c0 = lane & 15, g = lane >> 4;
  f32x4 a2[2][4];
#pragma unroll
  for (int mi = 0; mi < 2; ++mi)
#pragma unroll
    for (int nj = 0; nj < 4; ++nj) a2[mi][nj] = (f32x4){0.f, 0.f, 0.f, 0.f};
#pragma unroll
  for (int kk = 0; kk < 64; kk += 32) {
    const int kb = (kk + g * 8) * 2;
    bh8 af[2], bf[4];
#pragma unroll
    for (int mi = 0; mi < 2; ++mi) {
      const int ar = h * 32 + mi * 16 + c0;
      af[mi] = *reinterpret_cast<const bh8*>(&lds[abase + ar * 128 + (kb ^ ((ar & 7) << 4))]);
    }
#pragma unroll
    for (int nj = 0; nj < 4; ++nj) {
      const int br = nj * 16 + c0;
      bf[nj] = *reinterpret_cast<const bh8*>(&lds[bbase + br * 128 + (kb ^ ((br & 7) << 4))]);
    }
#pragma unroll
    for (int mi = 0; mi < 2; ++mi)
#pragma unroll
      for (int nj = 0; nj < 4; ++nj)
        a2[mi][nj] = __builtin_amdgcn_mfma_f32_16x16x32_bf16(af[mi], bf[nj], a2[mi][nj], 0, 0, 0);
  }
  float mx = 0.f;
#pragma unroll
  for (int mi = 0; mi < 2; ++mi)
#pragma unroll
    for (int nj = 0; nj < 4; ++nj)
#pragma unroll
      for (int reg = 0; reg < 4; ++reg) mx = fmaxf(mx, a2[mi][nj][reg]);
#pragma unroll
  for (int off = 1; off < 64; off <<= 1) mx = fmaxf(mx, __shfl_xor(mx, off, 64));
  if (lane == 0) wpm[w] = mx;
  __syncthreads();
  const float mp = fmaxf(wpm[p * 2], wpm[p * 2 + 1]);
  const float invp = 1.0f / mp;
#pragma unroll
  for (int mi = 0; mi < 2; ++mi)
#pragma unroll
    for (int nj = 0; nj < 4; ++nj)
#pragma unroll
      for (int reg = 0; reg < 4; ++reg) {
        const int row = h * 32 + mi * 16 + g * 4 + reg;
        const int col = nj * 16 + c0;
        const u16 val = f2bf(a2[mi][nj][reg] * invp);
        if (p == 0)    // P1 row-major (A operand)
          *reinterpret_cast<u16*>(&lds[32768 + row * 128 + ((col * 2) ^ ((row & 7) << 4))]) = val;
        else           // P2 transposed (B operand)
          *reinterpret_cast<u16*>(&lds[40960 + col * 128 + ((row * 2) ^ ((col & 7) << 4))]) = val;
      }
  __syncthreads();

  // step B: P = P1 * P2 (full 64x64, all 4 waves)
  f32x4 acc[4];
#pragma unroll
  for (int i = 0; i < 4; ++i) acc[i] = (f32x4){0.f, 0.f, 0.f, 0.f};
  const int ra = w * 16 + c0;
#pragma unroll
  for (int kk = 0; kk < 64; kk += 32) {
    const int kb = (kk + g * 8) * 2;
    const bh8 af = *reinterpret_cast<const bh8*>(&lds[32768 + ra * 128 + (kb ^ ((ra & 7) << 4))]);
#pragma unroll
    for (int nj = 0; nj < 4; ++nj) {
      const int rb = nj * 16 + c0;
      const bh8 bf = *reinterpret_cast<const bh8*>(&lds[40960 + rb * 128 + (kb ^ ((rb & 7) << 4))]);
      acc[nj] = __builtin_amdgcn_mfma_f32_16x16x32_bf16(af, bf, acc[nj], 0, 0, 0);
    }
  }
  float mx2 = 0.f;
#pragma unroll
  for (int nj = 0; nj < 4; ++nj)
#pragma unroll
    for (int reg = 0; reg < 4; ++reg) mx2 = fmaxf(mx2, acc[nj][reg]);
#pragma unroll
  for (int off = 1; off < 64; off <<= 1) mx2 = fmaxf(mx2, __shfl_xor(mx2, off, 64));
  if (lane == 0) wpm[4 + w] = mx2;
  __syncthreads();
  const float m = fmaxf(fmaxf(wpm[4], wpm[5]), fmaxf(wpm[6], wpm[7]));
  const float inv = 1.0f / m;
  float* ftile = reinterpret_cast<float*>(lds);   // reuse M0/M1 region (16KB)
#pragma unroll
  for (int nj = 0; nj < 4; ++nj)
#pragma unroll
    for (int reg = 0; reg < 4; ++reg)
      ftile[(w * 16 + g * 4 + reg) * 64 + nj * 16 + c0] = acc[nj][reg] * inv;
  __syncthreads();
  u16* node = dst + ((size_t)(n * U + u)) * 4096;
  const int rr = tid >> 2, cb = (tid & 3) * 16;
  u16x8 o0, o1;
  if ((u & 1) == 0) {
#pragma unroll
    for (int e = 0; e < 8; ++e) o0[e] = f2bf(ftile[rr * 64 + cb + e]);
#pragma unroll
    for (int e = 0; e < 8; ++e) o1[e] = f2bf(ftile[rr * 64 + cb + 8 + e]);
  } else {
#pragma unroll
    for (int e = 0; e < 8; ++e) o0[e] = f2bf(ftile[(cb + e) * 64 + rr]);
#pragma unroll
    for (int e = 0; e < 8; ++e) o1[e] = f2bf(ftile[(cb + 8 + e) * 64 + rr]);
  }
  *reinterpret_cast<u16x8*>(node + rr * 64 + cb) = o0;
  *reinterpret_cast<u16x8*>(node + rr * 64 + cb + 8) = o1;
  if (tid == 0)
    scd[n * U + u] = scs[n * 4 * U + 4 * u] + scs[n * 4 * U + 4 * u + 1]
                   + scs[n * 4 * U + 4 * u + 2] + scs[n * 4 * U + 4 * u + 3]
                   + logf(fmaxf(wpm[0], wpm[1])) + logf(fmaxf(wpm[2], wpm[3])) + logf(m);
}

// ---------------- final ----------------

__global__ __launch_bounds__(64) void final_k(const u16* __restrict__ root,
                                              const float* __restrict__ rsc,
                                              const float* __restrict__ hlog,
                                              const float* __restrict__ hlse,
                                              const float* __restrict__ emitb,
                                              const int* __restrict__ text,
                                              const int* __restrict__ w2c,
                                              float* __restrict__ out) {
  const int n = blockIdx.x, i = threadIdx.x;
  const int w0 = text[n * TT];
  float a0 = hlog[w2c[w0] * 64 + i] - hlse[0] + emitb[((size_t)(n * TT)) * 64 + i];
  float m0 = a0;
  for (int off = 32; off; off >>= 1) m0 = fmaxf(m0, __shfl_xor(m0, off, 64));
  const float lin = expf(a0 - m0);
  const u16* row = root + (size_t)n * 4096 + i * 64;
  float rs = 0.f;
#pragma unroll
  for (int e8 = 0; e8 < 8; ++e8) {
    const u16x8 v = *reinterpret_cast<const u16x8*>(row + e8 * 8);
#pragma unroll
    for (int e = 0; e < 8; ++e) rs += bf2f(v[e]);
  }
  float v = lin * rs;
  for (int off = 32; off; off >>= 1) v += __shfl_xor(v, off, 64);
  if (i == 0) out[n] = m0 + rsc[n] + logf(v);
}

// ---------------- emission GEMM ----------------

__global__ __launch_bounds__(256) void emis_k(
    const u16* __restrict__ Wpb, const u16* __restrict__ PHb,
    const float* __restrict__ bp,
    const int* __restrict__ offs, const int* __restrict__ wlist,
    const int* __restrict__ map,
    float* __restrict__ esum, float* __restrict__ logits_all) {
  const int ent = map[blockIdx.x];
  if (ent < 0) return;
  const int c = ent >> 8, blk = ent & 255;
  __shared__ char lds[16384];
  __shared__ int wid_s[64];
  const int tid = threadIdx.x, lane = tid & 63, wid = tid >> 6;
  const int st = offs[c], cnt = offs[c + 1] - st;
  if (tid < 64) {
    const int idx = blk * 64 + tid;
    wid_s[tid] = (idx < cnt) ? wlist[st + idx] : -1;
  }
  __syncthreads();

  f32x4 acc[4];
#pragma unroll
  for (int i = 0; i < 4; ++i) acc[i] = (f32x4){0.f, 0.f, 0.f, 0.f};

  const int sr = tid >> 3;
  const int scb = (tid & 7) * 16;
  const int ra = wid * 16 + (lane & 15);
  const int rb0 = lane & 15;
  const int ko = (lane >> 4) * 8;
  const u16* Bg = PHb + (size_t)(c * 64) * HD;

  for (int kc = 0; kc < HD; kc += 64) {
#pragma unroll
    for (int rep = 0; rep < 2; ++rep) {
      const int r = rep * 32 + sr;
      const int w = max(wid_s[r], 0);
      const bh8 va = *reinterpret_cast<const bh8*>(Wpb + (size_t)w * HD + kc + (scb >> 1));
      *reinterpret_cast<bh8*>(&lds[r * 128 + (scb ^ ((r & 7) << 4))]) = va;
      const bh8 vb = *reinterpret_cast<const bh8*>(Bg + r * HD + kc + (scb >> 1));
      *reinterpret_cast<bh8*>(&lds[8192 + r * 128 + (scb ^ ((r & 7) << 4))]) = vb;
    }
    __syncthreads();
#pragma unroll
    for (int kk = 0; kk < 64; kk += 32) {
      const int kb = (kk + ko) * 2;
      const bh8 af = *reinterpret_cast<const bh8*>(&lds[ra * 128 + (kb ^ ((ra & 7) << 4))]);
#pragma unroll
      for (int nj = 0; nj < 4; ++nj) {
        const int rb = nj * 16 + rb0;
        const bh8 bf = *reinterpret_cast<const bh8*>(&lds[8192 + rb * 128 + (kb ^ ((rb & 7) << 4))]);
        acc[nj] = __builtin_amdgcn_mfma_f32_16x16x32_bf16(af, bf, acc[nj], 0, 0, 0);
      }
    }
    __syncthreads();
  }

  const int g = lane >> 4, c0 = lane & 15;
#pragma unroll
  for (int nj = 0; nj < 4; ++nj) {
    float se = 0.f;
#pragma unroll
    for (int reg = 0; reg < 4; ++reg) {
      const int row = wid * 16 + g * 4 + reg;
      const int w = wid_s[row];
      if (w >= 0) {
        const float lg = acc[nj][reg] + bp[w];
        logits_all[(size_t)w * 64 + nj * 16 + c0] = lg;
        se += expf(lg);
      }
    }
    se += __shfl_xor(se, 16, 64);
    se += __shfl_xor(se, 32, 64);
    if (g == 0) atomicAdd(&esum[c * 64 + nj * 16 + c0], se);
  }
}

// ---------------- start head ----------------

__global__ __launch_bounds__(256) void head_dot_k(const float* __restrict__ sh,
                                                  const float* __restrict__ wv,
                                                  const float* __restrict__ bv,
                                                  float* __restrict__ logits) {
  const int tid = threadIdx.x, lane = tid & 63, wid = tid >> 6;
  const int row = blockIdx.x * 4 + wid;
  float s = 0.f;
#pragma unroll
  for (int q = 0; q < 4; ++q)
    s += sh[(size_t)row * HD + q * 64 + lane] * wv[q * 64 + lane];
  for (int off = 32; off; off >>= 1) s += __shfl_xor(s, off, 64);
  if (lane == 0) logits[row] = s + bv[0];
}

__global__ __launch_bounds__(1024) void head_lse_k(const float* __restrict__ logits,
                                                   float* __restrict__ out_lse) {
  __shared__ float red[16];
  __shared__ float mshared;
  const int tid = threadIdx.x;
  float m = -1e30f;
  for (int i = tid; i < CS; i += 1024) m = fmaxf(m, logits[i]);
  for (int off = 32; off; off >>= 1) m = fmaxf(m, __shfl_xor(m, off, 64));
  if ((tid & 63) == 0) red[tid >> 6] = m;
  __syncthreads();
  if (tid == 0) {
    float x = red[0];
    for (int i = 1; i < 16; ++i) x = fmaxf(x, red[i]);
    mshared = x;
  }
  __syncthreads();
  const float M = mshared;
  float s = 0.f;
  for (int i = tid; i < CS; i += 1024) s += expf(logits[i] - M);
  for (int off = 32; off; off >>= 1) s += __shfl_xor(s, off, 64);
  if ((tid & 63) == 0) red[tid >> 6] = s;
  __syncthreads();
  if (tid == 0) {
    float x = 0.f;
    for (int i = 0; i < 16; ++i) x += red[i];
    out_lse[0] = M + logf(x);
  }
}

__global__ void emit_k(const int* __restrict__ text, const int* __restrict__ w2c,
                       const float* __restrict__ lall, const float* __restrict__ esum,
                       float* __restrict__ emitb) {
  const int idx = blockIdx.x * 256 + threadIdx.x;
  const int s = idx & 63, nt = idx >> 6;
  const int w = text[nt];
  emitb[idx] = lall[(size_t)w * 64 + s] - logf(esum[w2c[w] * 64 + s]);
}

// ---------------- host orchestration ----------------

extern "C" void kernel_launch(void* const* d_in, const int* in_sizes, int n_in,
                              void* d_out, int out_size, void* d_ws, size_t ws_size,
                              hipStream_t stream) {
  (void)in_sizes; (void)n_in; (void)out_size; (void)ws_size;
  const int* text = (const int*)d_in[0];
  const int* w2c  = (const int*)d_in[1];
  const float* sec = (const float*)d_in[2];
  const float* ses = (const float*)d_in[3];
  const float* stc = (const float*)d_in[4];
  const float* sts = (const float*)d_in[5];
  const float* nec = (const float*)d_in[6];
  const float* nes = (const float*)d_in[7];
  const float* pec = (const float*)d_in[8];
  const float* pes = (const float*)d_in[9];
  const float* srw1 = (const float*)d_in[10];
  const float* srb1 = (const float*)d_in[11];
  const float* srw2 = (const float*)d_in[12];
  const float* srb2 = (const float*)d_in[13];
  const float* trw1 = (const float*)d_in[14];
  const float* trb1 = (const float*)d_in[15];
  const float* trw2 = (const float*)d_in[16];
  const float* trb2 = (const float*)d_in[17];
  const float* tew1 = (const float*)d_in[18];
  const float* teb1 = (const float*)d_in[19];
  const float* tew2 = (const float*)d_in[20];
  const float* teb2 = (const float*)d_in[21];
  const float* sow = (const float*)d_in[22];
  const float* sob = (const float*)d_in[23];
  const float* tpw = (const float*)d_in[24];
  const float* tpb = (const float*)d_in[25];
  float* out = (float*)d_out;

  char* p = (char*)d_ws;
  auto carve = [&](size_t bytes) -> char* {
    char* r = p; p += (bytes + 255) & ~(size_t)255; return r;
  };
  const int WTOT = 6 * 65536;
  u16* Wall = (u16*)carve(((size_t)WTOT + (size_t)VV * HD) * 2);  // 6 MLP weights + Wp
  u16* Wpb  = Wall + WTOT;
  u16* EbS  = (u16*)carve((size_t)CS * HD * 2);
  u16* EbT  = (u16*)carve((size_t)CS * HD * 2);
  u16* NSEb = (u16*)carve((size_t)CS * HD * 2);
  u16* EbP  = (u16*)carve((size_t)CS * HD * 2);
  u16* Hbf  = (u16*)carve((size_t)CS * HD * 2);
  float* SHf = (float*)carve((size_t)CS * HD * 4);
  u16* Xbf  = (u16*)carve((size_t)CS * HD * 2);
  u16* PHb  = (u16*)carve((size_t)CS * HD * 2);
  float* hlog  = (float*)carve(CS * 4);
  float* hlse  = (float*)carve(256);
  float* part  = (float*)carve((size_t)64 * CS * 4);
  float* rlse  = (float*)carve(CS * 4);
  int* offs    = (int*)carve((KCL + 1) * 4);
  int* wlist   = (int*)carve(VV * 4);
  int* bmap    = (int*)carve(MAXB * 4);
  float* esum  = (float*)carve(CS * 4);
  float* lall  = (float*)carve((size_t)VV * 64 * 4);
  float* emitb = (float*)carve((size_t)NB * TT * 64 * 4);
  u16*   bufA  = (u16*)carve((size_t)NB * 256 * 4096 * 2);
  u16*   bufB  = (u16*)carve((size_t)NB * 64 * 4096 * 2);
  float* scA   = (float*)carve((size_t)NB * 256 * 4);
  float* scB   = (float*)carve((size_t)NB * 256 * 4);

  hipMemsetAsync(esum, 0, CS * 4, stream);

  cvt_all_k<<<(WTOT + VV * HD + 255) / 256, 256, 0, stream>>>(
      srw1, srw2, trw1, trw2, tew1, tew2, tpw, Wall);
  csr_all_k<<<1, 256, 0, stream>>>(w2c, offs, wlist, bmap);
  emb_all_k<<<4 * CS * HD / 256, 256, 0, stream>>>(
      sec, ses, EbS, stc, sts, EbT, nec, nes, NSEb, pec, pes, EbP);

  const dim3 gMLP(4, 128);

  // start chain
  gemm64<0><<<gMLP, 256, 0, stream>>>(EbS, Wall + 0 * 65536, HD, HD, srb1, nullptr,
      nullptr, Hbf, nullptr, nullptr, nullptr, nullptr, nullptr, nullptr);
  gemm64<0><<<gMLP, 256, 0, stream>>>(Hbf, Wall + 1 * 65536, HD, HD, srb2, EbS,
      SHf, nullptr, nullptr, nullptr, nullptr, nullptr, nullptr, nullptr);
  head_dot_k<<<CS / 4, 256, 0, stream>>>(SHf, sow, sob, hlog);
  head_lse_k<<<1, 1024, 0, stream>>>(hlog, hlse);

  // trans chain
  gemm64<0><<<gMLP, 256, 0, stream>>>(EbT, Wall + 2 * 65536, HD, HD, trb1, nullptr,
      nullptr, Hbf, nullptr, nullptr, nullptr, nullptr, nullptr, nullptr);
  gemm64<0><<<gMLP, 256, 0, stream>>>(Hbf, Wall + 3 * 65536, HD, HD, trb2, EbT,
      nullptr, Xbf, nullptr, nullptr, nullptr, nullptr, nullptr, nullptr);

  // term chain
  gemm64<0><<<gMLP, 256, 0, stream>>>(EbP, Wall + 4 * 65536, HD, HD, teb1, nullptr,
      nullptr, Hbf, nullptr, nullptr, nullptr, nullptr, nullptr, nullptr);
  gemm64<0><<<gMLP, 256, 0, stream>>>(Hbf, Wall + 5 * 65536, HD, HD, teb2, EbP,
      nullptr, PHb, nullptr, nullptr, nullptr, nullptr, nullptr, nullptr);

  // transition row-logsumexp
  rlse_k<<<4096, 256, 0, stream>>>(Xbf, NSEb, part);
  rred_k<<<CS / 256, 256, 0, stream>>>(part, rlse);

  // emission
  emis_k<<<MAXB, 256, 0, stream>>>(Wpb, PHb, tpb, offs, wlist, bmap, esum, lall);
  emit_k<<<NB * TT * 64 / 256, 256, 0, stream>>>(text, w2c, lall, esum, emitb);

  // leaves
  idleaf_k<<<NB, 64, 0, stream>>>(bufA, scA);
  gemm64<2><<<dim3(NB * (TT - 1)), 256, 0, stream>>>(Xbf, NSEb, CS, HD, nullptr, nullptr,
      nullptr, nullptr, rlse, emitb, text, w2c, bufA, scA);

  // quad-tree product reduction: 256 -> 64 -> 16 -> 4 -> 1
  comb4_k<<<NB * 64, 256, 0, stream>>>(bufA, scA, bufB, scB, 64);
  comb4_k<<<NB * 16, 256, 0, stream>>>(bufB, scB, bufA, scA, 16);
  comb4_k<<<NB * 4, 256, 0, stream>>>(bufA, scA, bufB, scB, 4);
  comb4_k<<<NB * 1, 256, 0, stream>>>(bufB, scB, bufA, scA, 1);
  final_k<<<NB, 64, 0, stream>>>(bufA, scA, hlog, hlse, emitb, text, w2c, out);
}

// Round 6
// 251.510 us; speedup vs baseline: 2.7701x; 1.0383x over previous
//
#include <hip/hip_runtime.h>
#include <hip/hip_bf16.h>

// FactoredHmmLm forward on MI355X.
//  1. prep_k: fused weight-cvt + 4-embedding build + CSR (single launch)
//  2. residual MLPs via gemm64 (global_load_lds staging)
//  3. transition row-logsumexp: 256x256-tile 8-wave GEMM, 2-phase prefetch
//     (issue next K-tile gl2lds before MFMA, counted drain at tile end)
//  4. emission: MFMA 64-word blocks + atomic exp-sum
//  5. per-(n,t) leaf matrices M_t = exp(tr + emit - m), bf16 (identity leaf folded in)
//  6. quad-tree product reduction + final

using u16 = unsigned short;
typedef __attribute__((ext_vector_type(8))) short bh8;     // 8 bf16 (4 VGPRs)
typedef __attribute__((ext_vector_type(4))) float f32x4;
typedef __attribute__((ext_vector_type(8))) unsigned short u16x8;

#define HD 256
#define TT 256
#define NB 16
#define KCL 128
#define CS 8192
#define VV 10000
#define MAXB 320
#define LOG2E 1.44269504f
#define WTOT (6 * 65536)
#define NCVT ((WTOT + VV * HD) / 256)        // 11536 (exact)
#define NEMB (4 * CS * HD / 256)             // 32768

__device__ __forceinline__ u16 f2bf(float v) {
  union { float f; unsigned int i; } u; u.f = v;
  unsigned int r = u.i + 0x7fffu + ((u.i >> 16) & 1u);   // RNE
  return (u16)(r >> 16);
}
__device__ __forceinline__ float bf2f(u16 u) {
  union { unsigned int i; float f; } x; x.i = ((unsigned int)u) << 16; return x.f;
}
__device__ __forceinline__ void gl2lds16(const u16* g, u16* l) {
  __builtin_amdgcn_global_load_lds(
      (const __attribute__((address_space(1))) unsigned int*)g,
      (__attribute__((address_space(3))) unsigned int*)l, 16, 0, 0);
}

// ---------------- prep: weights->bf16, embeddings, CSR ----------------

__global__ __launch_bounds__(256) void prep_k(
    const float* __restrict__ w0, const float* __restrict__ w1,
    const float* __restrict__ w2, const float* __restrict__ w3,
    const float* __restrict__ w4, const float* __restrict__ w5,
    const float* __restrict__ tpw, u16* __restrict__ dstW,
    const float* __restrict__ ec0, const float* __restrict__ es0, u16* __restrict__ d0,
    const float* __restrict__ ec1, const float* __restrict__ es1, u16* __restrict__ d1,
    const float* __restrict__ ec2, const float* __restrict__ es2, u16* __restrict__ d2,
    const float* __restrict__ ec3, const float* __restrict__ es3, u16* __restrict__ d3,
    const int* __restrict__ w2c, int* __restrict__ offs,
    int* __restrict__ wlist, int* __restrict__ bmap) {
  const int b = blockIdx.x, tid = threadIdx.x;
  if (b < NCVT) {
    const int idx = b * 256 + tid;
    float v;
    if (idx < WTOT) {
      const int i = idx >> 16, o = idx & 65535;
      const float* s = i == 0 ? w0 : i == 1 ? w1 : i == 2 ? w2 : i == 3 ? w3 : i == 4 ? w4 : w5;
      v = s[o];
    } else {
      v = tpw[idx - WTOT];
    }
    dstW[idx] = f2bf(v);
  } else if (b < NCVT + NEMB) {
    const int idx = (b - NCVT) * 256 + tid;
    const int seg = idx >> 21;
    const int off = idx & ((CS * HD) - 1);
    const int h = off & 255, row = off >> 8;
    const int k = row >> 6, s = row & 63;
    const float* ec = seg == 0 ? ec0 : seg == 1 ? ec1 : seg == 2 ? ec2 : ec3;
    const float* es = seg == 0 ? es0 : seg == 1 ? es1 : seg == 2 ? es2 : es3;
    u16* d = seg == 0 ? d0 : seg == 1 ? d1 : seg == 2 ? d2 : d3;
    d[off] = f2bf(ec[k * HD + h] + es[s * HD + h]);
  } else {
    __shared__ int cnt[KCL], cur[KCL], off_s[KCL + 1];
    if (tid < KCL) cnt[tid] = 0;
    __syncthreads();
    for (int w = tid; w < VV; w += 256) atomicAdd(&cnt[w2c[w]], 1);
    __syncthreads();
    if (tid == 0) {
      int acc = 0;
      for (int c = 0; c < KCL; ++c) { off_s[c] = acc; acc += cnt[c]; }
      off_s[KCL] = acc;
      int idx = 0;
      for (int c = 0; c < KCL; ++c) {
        const int nb = (cnt[c] + 63) >> 6;
        for (int bb = 0; bb < nb; ++bb) bmap[idx++] = (c << 8) | bb;
      }
      for (; idx < MAXB; ++idx) bmap[idx] = -1;
    }
    __syncthreads();
    if (tid < KCL) cur[tid] = off_s[tid];
    if (tid <= KCL) offs[tid] = off_s[tid];
    __syncthreads();
    for (int w = tid; w < VV; w += 256) {
      const int p = atomicAdd(&cur[w2c[w]], 1);
      wlist[p] = w;
    }
  }
}

// ---------------- transition row-lse: 256x256-tile, 8-wave, 2-phase prefetch ----------

__global__ __launch_bounds__(512) void rlse_k(const u16* __restrict__ A,
                                              const u16* __restrict__ B,
                                              float* __restrict__ part) {
  __shared__ char lds[131072];   // [2 bufs][ A 32KB | B 32KB ]
  const int tid = threadIdx.x;
  const int lane = tid & 63, w = tid >> 6;   // 8 waves
  const int wr = w >> 2, wc = w & 3;          // 2M x 4N
  const int c0 = lane & 15, g = lane >> 4;

  int bid = blockIdx.x;                        // 1024 = 32x32; %8==0 -> bijective
  bid = (bid & 7) * 128 + (bid >> 3);
  const int by = bid >> 5, bx = bid & 31;
  const int rm = by * 256, cn = bx * 256;

  f32x4 acc[8][4];
#pragma unroll
  for (int i = 0; i < 8; ++i)
#pragma unroll
    for (int j = 0; j < 4; ++j) acc[i][j] = (f32x4){0.f, 0.f, 0.f, 0.f};

  // stage K-tile kt into buffer hb: LDS[r][cb] = G[r][cb ^ (r&7)] (16B chunks)
  auto STAGE = [&](int kt, int hb) {
    const int kc = kt * 64;
    const int bo = hb * 65536;
#pragma unroll
    for (int q = 0; q < 4; ++q) {
      const int c = q * 512 + tid;            // chunk 0..2047
      const int r = c >> 3, cb = c & 7;
      const int gq = cb ^ (r & 7);
      gl2lds16(A + (size_t)(rm + r) * HD + kc + gq * 8, (u16*)&lds[bo + c * 16]);
    }
#pragma unroll
    for (int q = 0; q < 4; ++q) {
      const int c = q * 512 + tid;
      const int r = c >> 3, cb = c & 7;
      const int gq = cb ^ (r & 7);
      gl2lds16(B + (size_t)(cn + r) * HD + kc + gq * 8, (u16*)&lds[bo + 32768 + c * 16]);
    }
  };

  STAGE(0, 0);
  asm volatile("s_waitcnt vmcnt(0)" ::: "memory");
  __builtin_amdgcn_s_barrier();

  int cur = 0;
  for (int kt = 0; kt < 4; ++kt) {
    if (kt < 3) STAGE(kt + 1, cur ^ 1);
    const int bo = cur * 65536;
    __builtin_amdgcn_s_setprio(1);
#pragma unroll
    for (int kk = 0; kk < 64; kk += 32) {
      const int kb = (kk + g * 8) * 2;
      bh8 af[8], bf[4];
#pragma unroll
      for (int mi = 0; mi < 8; ++mi) {
        const int ar = wr * 128 + mi * 16 + c0;
        af[mi] = *reinterpret_cast<const bh8*>(&lds[bo + ar * 128 + (kb ^ ((ar & 7) << 4))]);
      }
#pragma unroll
      for (int nj = 0; nj < 4; ++nj) {
        const int br = wc * 64 + nj * 16 + c0;
        bf[nj] = *reinterpret_cast<const bh8*>(&lds[bo + 32768 + br * 128 + (kb ^ ((br & 7) << 4))]);
      }
#pragma unroll
      for (int mi = 0; mi < 8; ++mi)
#pragma unroll
        for (int nj = 0; nj < 4; ++nj)
          acc[mi][nj] = __builtin_amdgcn_mfma_f32_16x16x32_bf16(af[mi], bf[nj], acc[mi][nj], 0, 0, 0);
    }
    __builtin_amdgcn_s_setprio(0);
    asm volatile("s_waitcnt vmcnt(0) lgkmcnt(0)" ::: "memory");
    __builtin_amdgcn_s_barrier();
    cur ^= 1;
  }

  // epilogue: per-row sum of exp over this block's 256 cols
  float rs[8][4];
#pragma unroll
  for (int mi = 0; mi < 8; ++mi)
#pragma unroll
    for (int reg = 0; reg < 4; ++reg) {
      float s = 0.f;
#pragma unroll
      for (int nj = 0; nj < 4; ++nj) s += exp2f(acc[mi][nj][reg] * LOG2E);
      rs[mi][reg] = s;
    }
#pragma unroll
  for (int off = 1; off < 16; off <<= 1)
#pragma unroll
    for (int mi = 0; mi < 8; ++mi)
#pragma unroll
      for (int reg = 0; reg < 4; ++reg)
        rs[mi][reg] += __shfl_xor(rs[mi][reg], off, 64);

  float* Lf = reinterpret_cast<float*>(lds);   // [256][4]
  if (c0 == 0) {
#pragma unroll
    for (int mi = 0; mi < 8; ++mi)
#pragma unroll
      for (int reg = 0; reg < 4; ++reg)
        Lf[(wr * 128 + mi * 16 + g * 4 + reg) * 4 + wc] = rs[mi][reg];
  }
  __syncthreads();
  if (tid < 256)
    part[(size_t)bx * CS + rm + tid] = Lf[tid * 4] + Lf[tid * 4 + 1] + Lf[tid * 4 + 2] + Lf[tid * 4 + 3];
}

__global__ void rred_k(const float* __restrict__ part, float* __restrict__ rlse) {
  const int i = blockIdx.x * 256 + threadIdx.x;
  float s = 0.f;
#pragma unroll 8
  for (int b = 0; b < 32; ++b) s += part[(size_t)b * CS + i];
  rlse[i] = logf(s);
}

// ---------------- MFMA GEMM 64x64 tile (gl2lds staging) ----------------
// MODE 0: out = relu(acc + bias[n] (+ bf16 skip)) -> f32 and/or bf16
// MODE 2: leaf: M = exp(acc - row_lse[m] + emit - max), bf16, parity layout
//         blocks >= NB*(TT-1) write the identity leaf (slot 255).

template<int MODE>
__global__ __launch_bounds__(256) void gemm64(
    const u16* __restrict__ A, const u16* __restrict__ B,
    int N, int K,
    const float* __restrict__ bias, const u16* __restrict__ skip,
    float* __restrict__ outf, u16* __restrict__ outbf,
    const float* __restrict__ row_lse, const float* __restrict__ emitb,
    const int* __restrict__ text, const int* __restrict__ w2c,
    u16* __restrict__ leafb, float* __restrict__ leafsc) {
  __shared__ char lds[16384];
  __shared__ float wmax[4];
  const int tid = threadIdx.x;
  const int lane = tid & 63;
  const int wid = tid >> 6;

  int rm, cn, nn = 0, ttv = 0;
  if (MODE == 2) {
    const int bi = blockIdx.x;
    if (bi >= NB * (TT - 1)) {               // identity leaf
      const int n = bi - NB * (TT - 1);
      if (n < NB) {
        u16* node = leafb + ((size_t)n * 256 + 255) * 4096;
        for (int c = tid; c < 4096; c += 256) node[c] = ((c >> 6) == (c & 63)) ? (u16)0x3F80 : (u16)0;
        if (tid == 0) leafsc[n * 256 + 255] = 0.f;
      }
      return;
    }
    nn = bi / (TT - 1);
    ttv = bi % (TT - 1) + 1;
    rm = w2c[text[nn * TT + ttv - 1]] * 64;
    cn = w2c[text[nn * TT + ttv]] * 64;
  } else {
    rm = blockIdx.y * 64;
    cn = blockIdx.x * 64;
  }
  const u16* Ag = A + (size_t)rm * K;
  const u16* Bg = B + (size_t)cn * K;

  f32x4 acc[4];
#pragma unroll
  for (int i = 0; i < 4; ++i) acc[i] = (f32x4){0.f, 0.f, 0.f, 0.f};

  const int ra = wid * 16 + (lane & 15);
  const int rb0 = lane & 15;
  const int ko = (lane >> 4) * 8;

  for (int kc = 0; kc < K; kc += 64) {
    if (kc) __syncthreads();
#pragma unroll
    for (int i = 0; i < 2; ++i) {
      const int c = i * 256 + tid;          // chunk 0..511
      const int r = c >> 3, cb = c & 7;
      const int gq = cb ^ (r & 7);
      gl2lds16(Ag + (size_t)r * K + kc + gq * 8, (u16*)&lds[c * 16]);
      gl2lds16(Bg + (size_t)r * K + kc + gq * 8, (u16*)&lds[8192 + c * 16]);
    }
    __syncthreads();
#pragma unroll
    for (int kk = 0; kk < 64; kk += 32) {
      const int kb = (kk + ko) * 2;
      const bh8 af = *reinterpret_cast<const bh8*>(&lds[ra * 128 + (kb ^ ((ra & 7) << 4))]);
#pragma unroll
      for (int nj = 0; nj < 4; ++nj) {
        const int rb = nj * 16 + rb0;
        const bh8 bf = *reinterpret_cast<const bh8*>(&lds[8192 + rb * 128 + (kb ^ ((rb & 7) << 4))]);
        acc[nj] = __builtin_amdgcn_mfma_f32_16x16x32_bf16(af, bf, acc[nj], 0, 0, 0);
      }
    }
  }

  const int g = lane >> 4, c0 = lane & 15;

  if (MODE == 0) {
#pragma unroll
    for (int nj = 0; nj < 4; ++nj) {
      const int nidx = cn + nj * 16 + c0;
      const float bv = bias[nidx];
#pragma unroll
      for (int reg = 0; reg < 4; ++reg) {
        const int midx = rm + wid * 16 + g * 4 + reg;
        float v = acc[nj][reg] + bv;
        if (skip) v += bf2f(skip[(size_t)midx * 256 + nidx]);
        v = fmaxf(v, 0.f);
        if (outf) outf[(size_t)midx * N + nidx] = v;
        if (outbf) outbf[(size_t)midx * N + nidx] = f2bf(v);
      }
    }
  } else {
    float L[4][4];
    float mx = -1e30f;
#pragma unroll
    for (int nj = 0; nj < 4; ++nj) {
      const float ev = emitb[((size_t)(nn * TT + ttv)) * 64 + nj * 16 + c0];
#pragma unroll
      for (int reg = 0; reg < 4; ++reg) {
        const float l = acc[nj][reg] - row_lse[rm + wid * 16 + g * 4 + reg] + ev;
        L[nj][reg] = l;
        mx = fmaxf(mx, l);
      }
    }
#pragma unroll
    for (int off = 1; off < 64; off <<= 1) mx = fmaxf(mx, __shfl_xor(mx, off, 64));
    if (lane == 0) wmax[wid] = mx;
    __syncthreads();
    const float m = fmaxf(fmaxf(wmax[0], wmax[1]), fmaxf(wmax[2], wmax[3]));
    float* ftile = reinterpret_cast<float*>(lds);
#pragma unroll
    for (int nj = 0; nj < 4; ++nj)
#pragma unroll
      for (int reg = 0; reg < 4; ++reg)
        ftile[(wid * 16 + g * 4 + reg) * 64 + nj * 16 + c0] = exp2f((L[nj][reg] - m) * LOG2E);
    __syncthreads();
    const int leaf = ttv - 1;
    u16* node = leafb + ((size_t)nn * 256 + leaf) * 4096;
    const int rr = tid >> 2, cb = (tid & 3) * 16;
    u16x8 o0, o1;
    if ((leaf & 1) == 0) {
#pragma unroll
      for (int e = 0; e < 8; ++e) o0[e] = f2bf(ftile[rr * 64 + cb + e]);
#pragma unroll
      for (int e = 0; e < 8; ++e) o1[e] = f2bf(ftile[rr * 64 + cb + 8 + e]);
    } else {
#pragma unroll
      for (int e = 0; e < 8; ++e) o0[e] = f2bf(ftile[(cb + e) * 64 + rr]);
#pragma unroll
      for (int e = 0; e < 8; ++e) o1[e] = f2bf(ftile[(cb + 8 + e) * 64 + rr]);
    }
    *reinterpret_cast<u16x8*>(node + rr * 64 + cb) = o0;
    *reinterpret_cast<u16x8*>(node + rr * 64 + cb + 8) = o1;
    if (tid == 0) leafsc[nn * 256 + leaf] = m;
  }
}

// ---------------- quad-tree combine: out = (M0*M1)*(M2*M3) ----------------

__global__ __launch_bounds__(256) void comb4_k(const u16* __restrict__ src,
                                               const float* __restrict__ scs,
                                               u16* __restrict__ dst,
                                               float* __restrict__ scd, int U) {
  const int n = blockIdx.x / U, u = blockIdx.x % U;
  __shared__ char lds[49152];   // M0@0 M1@8K M2@16K M3@24K | P1@32K P2@40K
  __shared__ float wpm[8];
  const int tid = threadIdx.x, lane = tid & 63, w = tid >> 6;
  const u16* base = src + ((size_t)(n * 4 * U + 4 * u)) * 4096;
  const int sr = tid >> 3, scb = (tid & 7) * 16;
#pragma unroll
  for (int nd = 0; nd < 4; ++nd)
#pragma unroll
    for (int rep = 0; rep < 2; ++rep) {
      const int r = rep * 32 + sr;
      const bh8 v = *reinterpret_cast<const bh8*>(base + nd * 4096 + r * 64 + (scb >> 1));
      *reinterpret_cast<bh8*>(&lds[nd * 8192 + r * 128 + (scb ^ ((r & 7) << 4))]) = v;
    }
  __syncthreads();

  const int p = w >> 1, h = w & 1;
  const int abase = p * 16384, bbase = abase + 8192;
  const int c0 = lane & 15, g = lane >> 4;
  f32x4 a2[2][4];
#pragma unroll
  for (int mi = 0; mi < 2; ++mi)
#pragma unroll
    for (int nj = 0; nj < 4; ++nj) a2[mi][nj] = (f32x4){0.f, 0.f, 0.f, 0.f};
#pragma unroll
  for (int kk = 0; kk < 64; kk += 32) {
    const int kb = (kk + g * 8) * 2;
    bh8 af[2], bf[4];
#pragma unroll
    for (int mi = 0; mi < 2; ++mi) {
      const int ar = h * 32 + mi * 16 + c0;
      af[mi] = *reinterpret_cast<const bh8*>(&lds[abase + ar * 128 + (kb ^ ((ar & 7) << 4))]);
    }
#pragma unroll
    for (int nj = 0; nj < 4; ++nj) {
      const int br = nj * 16 + c0;
      bf[nj] = *reinterpret_cast<const bh8*>(&lds[bbase + br * 128 + (kb ^ ((br & 7) << 4))]);
    }
#pragma unroll
    for (int mi = 0; mi < 2; ++mi)
#pragma unroll
      for (int nj = 0; nj < 4; ++nj)
        a2[mi][nj] = __builtin_amdgcn_mfma_f32_16x16x32_bf16(af[mi], bf[nj], a2[mi][nj], 0, 0, 0);
  }
  float mx = 0.f;
#pragma unroll
  for (int mi = 0; mi < 2; ++mi)
#pragma unroll
    for (int nj = 0; nj < 4; ++nj)
#pragma unroll
      for (int reg = 0; reg < 4; ++reg) mx = fmaxf(mx, a2[mi][nj][reg]);
#pragma unroll
  for (int off = 1; off < 64; off <<= 1) mx = fmaxf(mx, __shfl_xor(mx, off, 64));
  if (lane == 0) wpm[w] = mx;
  __syncthreads();
  const float mp = fmaxf(wpm[p * 2], wpm[p * 2 + 1]);
  const float invp = 1.0f / mp;
#pragma unroll
  for (int mi = 0; mi < 2; ++mi)
#pragma unroll
    for (int nj = 0; nj < 4; ++nj)
#pragma unroll
      for (int reg = 0; reg < 4; ++reg) {
        const int row = h * 32 + mi * 16 + g * 4 + reg;
        const int col = nj * 16 + c0;
        const u16 val = f2bf(a2[mi][nj][reg] * invp);
        if (p == 0)
          *reinterpret_cast<u16*>(&lds[32768 + row * 128 + ((col * 2) ^ ((row & 7) << 4))]) = val;
        else
          *reinterpret_cast<u16*>(&lds[40960 + col * 128 + ((row * 2) ^ ((col & 7) << 4))]) = val;
      }
  __syncthreads();

  f32x4 acc[4];
#pragma unroll
  for (int i = 0; i < 4; ++i) acc[i] = (f32x4){0.f, 0.f, 0.f, 0.f};
  const int ra = w * 16 + c0;
#pragma unroll
  for (int kk = 0; kk < 64; kk += 32) {
    const int kb = (kk + g * 8) * 2;
    const bh8 af = *reinterpret_cast<const bh8*>(&lds[32768 + ra * 128 + (kb ^ ((ra & 7) << 4))]);
#pragma unroll
    for (int nj = 0; nj < 4; ++nj) {
      const int rb = nj * 16 + c0;
      const bh8 bf = *reinterpret_cast<const bh8*>(&lds[40960 + rb * 128 + (kb ^ ((rb & 7) << 4))]);
      acc[nj] = __builtin_amdgcn_mfma_f32_16x16x32_bf16(af, bf, acc[nj], 0, 0, 0);
    }
  }
  float mx2 = 0.f;
#pragma unroll
  for (int nj = 0; nj < 4; ++nj)
#pragma unroll
    for (int reg = 0; reg < 4; ++reg) mx2 = fmaxf(mx2, acc[nj][reg]);
#pragma unroll
  for (int off = 1; off < 64; off <<= 1) mx2 = fmaxf(mx2, __shfl_xor(mx2, off, 64));
  if (lane == 0) wpm[4 + w] = mx2;
  __syncthreads();
  const float m = fmaxf(fmaxf(wpm[4], wpm[5]), fmaxf(wpm[6], wpm[7]));
  const float inv = 1.0f / m;
  float* ftile = reinterpret_cast<float*>(lds);
#pragma unroll
  for (int nj = 0; nj < 4; ++nj)
#pragma unroll
    for (int reg = 0; reg < 4; ++reg)
      ftile[(w * 16 + g * 4 + reg) * 64 + nj * 16 + c0] = acc[nj][reg] * inv;
  __syncthreads();
  u16* node = dst + ((size_t)(n * U + u)) * 4096;
  const int rr = tid >> 2, cb = (tid & 3) * 16;
  u16x8 o0, o1;
  if ((u & 1) == 0) {
#pragma unroll
    for (int e = 0; e < 8; ++e) o0[e] = f2bf(ftile[rr * 64 + cb + e]);
#pragma unroll
    for (int e = 0; e < 8; ++e) o1[e] = f2bf(ftile[rr * 64 + cb + 8 + e]);
  } else {
#pragma unroll
    for (int e = 0; e < 8; ++e) o0[e] = f2bf(ftile[(cb + e) * 64 + rr]);
#pragma unroll
    for (int e = 0; e < 8; ++e) o1[e] = f2bf(ftile[(cb + 8 + e) * 64 + rr]);
  }
  *reinterpret_cast<u16x8*>(node + rr * 64 + cb) = o0;
  *reinterpret_cast<u16x8*>(node + rr * 64 + cb + 8) = o1;
  if (tid == 0)
    scd[n * U + u] = scs[n * 4 * U + 4 * u] + scs[n * 4 * U + 4 * u + 1]
                   + scs[n * 4 * U + 4 * u + 2] + scs[n * 4 * U + 4 * u + 3]
                   + logf(fmaxf(wpm[0], wpm[1])) + logf(fmaxf(wpm[2], wpm[3])) + logf(m);
}

// ---------------- final ----------------

__global__ __launch_bounds__(64) void final_k(const u16* __restrict__ root,
                                              const float* __restrict__ rsc,
                                              const float* __restrict__ hlog,
                                              const float* __restrict__ hlse,
                                              const float* __restrict__ emitb,
                                              const int* __restrict__ text,
                                              const int* __restrict__ w2c,
                                              float* __restrict__ out) {
  const int n = blockIdx.x, i = threadIdx.x;
  const int w0 = text[n * TT];
  float a0 = hlog[w2c[w0] * 64 + i] - hlse[0] + emitb[((size_t)(n * TT)) * 64 + i];
  float m0 = a0;
  for (int off = 32; off; off >>= 1) m0 = fmaxf(m0, __shfl_xor(m0, off, 64));
  const float lin = expf(a0 - m0);
  const u16* row = root + (size_t)n * 4096 + i * 64;
  float rs = 0.f;
#pragma unroll
  for (int e8 = 0; e8 < 8; ++e8) {
    const u16x8 v = *reinterpret_cast<const u16x8*>(row + e8 * 8);
#pragma unroll
    for (int e = 0; e < 8; ++e) rs += bf2f(v[e]);
  }
  float v = lin * rs;
  for (int off = 32; off; off >>= 1) v += __shfl_xor(v, off, 64);
  if (i == 0) out[n] = m0 + rsc[n] + logf(v);
}

// ---------------- emission GEMM ----------------

__global__ __launch_bounds__(256) void emis_k(
    const u16* __restrict__ Wpb, const u16* __restrict__ PHb,
    const float* __restrict__ bp,
    const int* __restrict__ offs, const int* __restrict__ wlist,
    const int* __restrict__ map,
    float* __restrict__ esum, float* __restrict__ logits_all) {
  const int ent = map[blockIdx.x];
  if (ent < 0) return;
  const int c = ent >> 8, blk = ent & 255;
  __shared__ char lds[16384];
  __shared__ int wid_s[64];
  const int tid = threadIdx.x, lane = tid & 63, wid = tid >> 6;
  const int st = offs[c], cnt = offs[c + 1] - st;
  if (tid < 64) {
    const int idx = blk * 64 + tid;
    wid_s[tid] = (idx < cnt) ? wlist[st + idx] : -1;
  }
  __syncthreads();

  f32x4 acc[4];
#pragma unroll
  for (int i = 0; i < 4; ++i) acc[i] = (f32x4){0.f, 0.f, 0.f, 0.f};

  const int sr = tid >> 3;
  const int scb = (tid & 7) * 16;
  const int ra = wid * 16 + (lane & 15);
  const int rb0 = lane & 15;
  const int ko = (lane >> 4) * 8;
  const u16* Bg = PHb + (size_t)(c * 64) * HD;

  for (int kc = 0; kc < HD; kc += 64) {
#pragma unroll
    for (int rep = 0; rep < 2; ++rep) {
      const int r = rep * 32 + sr;
      const int w = max(wid_s[r], 0);
      const bh8 va = *reinterpret_cast<const bh8*>(Wpb + (size_t)w * HD + kc + (scb >> 1));
      *reinterpret_cast<bh8*>(&lds[r * 128 + (scb ^ ((r & 7) << 4))]) = va;
      const bh8 vb = *reinterpret_cast<const bh8*>(Bg + r * HD + kc + (scb >> 1));
      *reinterpret_cast<bh8*>(&lds[8192 + r * 128 + (scb ^ ((r & 7) << 4))]) = vb;
    }
    __syncthreads();
#pragma unroll
    for (int kk = 0; kk < 64; kk += 32) {
      const int kb = (kk + ko) * 2;
      const bh8 af = *reinterpret_cast<const bh8*>(&lds[ra * 128 + (kb ^ ((ra & 7) << 4))]);
#pragma unroll
      for (int nj = 0; nj < 4; ++nj) {
        const int rb = nj * 16 + rb0;
        const bh8 bf = *reinterpret_cast<const bh8*>(&lds[8192 + rb * 128 + (kb ^ ((rb & 7) << 4))]);
        acc[nj] = __builtin_amdgcn_mfma_f32_16x16x32_bf16(af, bf, acc[nj], 0, 0, 0);
      }
    }
    __syncthreads();
  }

  const int g = lane >> 4, c0 = lane & 15;
#pragma unroll
  for (int nj = 0; nj < 4; ++nj) {
    float se = 0.f;
#pragma unroll
    for (int reg = 0; reg < 4; ++reg) {
      const int row = wid * 16 + g * 4 + reg;
      const int w = wid_s[row];
      if (w >= 0) {
        const float lg = acc[nj][reg] + bp[w];
        logits_all[(size_t)w * 64 + nj * 16 + c0] = lg;
        se += expf(lg);
      }
    }
    se += __shfl_xor(se, 16, 64);
    se += __shfl_xor(se, 32, 64);
    if (g == 0) atomicAdd(&esum[c * 64 + nj * 16 + c0], se);
  }
}

// ---------------- start head ----------------

__global__ __launch_bounds__(256) void head_dot_k(const float* __restrict__ sh,
                                                  const float* __restrict__ wv,
                                                  const float* __restrict__ bv,
                                                  float* __restrict__ logits) {
  const int tid = threadIdx.x, lane = tid & 63, wid = tid >> 6;
  const int row = blockIdx.x * 4 + wid;
  float s = 0.f;
#pragma unroll
  for (int q = 0; q < 4; ++q)
    s += sh[(size_t)row * HD + q * 64 + lane] * wv[q * 64 + lane];
  for (int off = 32; off; off >>= 1) s += __shfl_xor(s, off, 64);
  if (lane == 0) logits[row] = s + bv[0];
}

__global__ __launch_bounds__(1024) void head_lse_k(const float* __restrict__ logits,
                                                   float* __restrict__ out_lse) {
  __shared__ float red[16];
  __shared__ float mshared;
  const int tid = threadIdx.x;
  float m = -1e30f;
  for (int i = tid; i < CS; i += 1024) m = fmaxf(m, logits[i]);
  for (int off = 32; off; off >>= 1) m = fmaxf(m, __shfl_xor(m, off, 64));
  if ((tid & 63) == 0) red[tid >> 6] = m;
  __syncthreads();
  if (tid == 0) {
    float x = red[0];
    for (int i = 1; i < 16; ++i) x = fmaxf(x, red[i]);
    mshared = x;
  }
  __syncthreads();
  const float M = mshared;
  float s = 0.f;
  for (int i = tid; i < CS; i += 1024) s += expf(logits[i] - M);
  for (int off = 32; off; off >>= 1) s += __shfl_xor(s, off, 64);
  if ((tid & 63) == 0) red[tid >> 6] = s;
  __syncthreads();
  if (tid == 0) {
    float x = 0.f;
    for (int i = 0; i < 16; ++i) x += red[i];
    out_lse[0] = M + logf(x);
  }
}

__global__ void emit_k(const int* __restrict__ text, const int* __restrict__ w2c,
                       const float* __restrict__ lall, const float* __restrict__ esum,
                       float* __restrict__ emitb) {
  const int idx = blockIdx.x * 256 + threadIdx.x;
  const int s = idx & 63, nt = idx >> 6;
  const int w = text[nt];
  emitb[idx] = lall[(size_t)w * 64 + s] - logf(esum[w2c[w] * 64 + s]);
}

// ---------------- host orchestration ----------------

extern "C" void kernel_launch(void* const* d_in, const int* in_sizes, int n_in,
                              void* d_out, int out_size, void* d_ws, size_t ws_size,
                              hipStream_t stream) {
  (void)in_sizes; (void)n_in; (void)out_size; (void)ws_size;
  const int* text = (const int*)d_in[0];
  const int* w2c  = (const int*)d_in[1];
  const float* sec = (const float*)d_in[2];
  const float* ses = (const float*)d_in[3];
  const float* stc = (const float*)d_in[4];
  const float* sts = (const float*)d_in[5];
  const float* nec = (const float*)d_in[6];
  const float* nes = (const float*)d_in[7];
  const float* pec = (const float*)d_in[8];
  const float* pes = (const float*)d_in[9];
  const float* srw1 = (const float*)d_in[10];
  const float* srb1 = (const float*)d_in[11];
  const float* srw2 = (const float*)d_in[12];
  const float* srb2 = (const float*)d_in[13];
  const float* trw1 = (const float*)d_in[14];
  const float* trb1 = (const float*)d_in[15];
  const float* trw2 = (const float*)d_in[16];
  const float* trb2 = (const float*)d_in[17];
  const float* tew1 = (const float*)d_in[18];
  const float* teb1 = (const float*)d_in[19];
  const float* tew2 = (const float*)d_in[20];
  const float* teb2 = (const float*)d_in[21];
  const float* sow = (const float*)d_in[22];
  const float* sob = (const float*)d_in[23];
  const float* tpw = (const float*)d_in[24];
  const float* tpb = (const float*)d_in[25];
  float* out = (float*)d_out;

  char* p = (char*)d_ws;
  auto carve = [&](size_t bytes) -> char* {
    char* r = p; p += (bytes + 255) & ~(size_t)255; return r;
  };
  u16* Wall = (u16*)carve(((size_t)WTOT + (size_t)VV * HD) * 2);
  u16* Wpb  = Wall + WTOT;
  u16* EbS  = (u16*)carve((size_t)CS * HD * 2);
  u16* EbT  = (u16*)carve((size_t)CS * HD * 2);
  u16* NSEb = (u16*)carve((size_t)CS * HD * 2);
  u16* EbP  = (u16*)carve((size_t)CS * HD * 2);
  u16* Hbf  = (u16*)carve((size_t)CS * HD * 2);
  float* SHf = (float*)carve((size_t)CS * HD * 4);
  u16* Xbf  = (u16*)carve((size_t)CS * HD * 2);
  u16* PHb  = (u16*)carve((size_t)CS * HD * 2);
  float* hlog  = (float*)carve(CS * 4);
  float* hlse  = (float*)carve(256);
  float* part  = (float*)carve((size_t)32 * CS * 4);
  float* rlse  = (float*)carve(CS * 4);
  int* offs    = (int*)carve((KCL + 1) * 4);
  int* wlist   = (int*)carve(VV * 4);
  int* bmap    = (int*)carve(MAXB * 4);
  float* esum  = (float*)carve(CS * 4);
  float* lall  = (float*)carve((size_t)VV * 64 * 4);
  float* emitb = (float*)carve((size_t)NB * TT * 64 * 4);
  u16*   bufA  = (u16*)carve((size_t)NB * 256 * 4096 * 2);
  u16*   bufB  = (u16*)carve((size_t)NB * 64 * 4096 * 2);
  float* scA   = (float*)carve((size_t)NB * 256 * 4);
  float* scB   = (float*)carve((size_t)NB * 256 * 4);

  hipMemsetAsync(esum, 0, CS * 4, stream);

  prep_k<<<NCVT + NEMB + 1, 256, 0, stream>>>(
      srw1, srw2, trw1, trw2, tew1, tew2, tpw, Wall,
      sec, ses, EbS, stc, sts, EbT, nec, nes, NSEb, pec, pes, EbP,
      w2c, offs, wlist, bmap);

  const dim3 gMLP(4, 128);

  // start chain
  gemm64<0><<<gMLP, 256, 0, stream>>>(EbS, Wall + 0 * 65536, HD, HD, srb1, nullptr,
      nullptr, Hbf, nullptr, nullptr, nullptr, nullptr, nullptr, nullptr);
  gemm64<0><<<gMLP, 256, 0, stream>>>(Hbf, Wall + 1 * 65536, HD, HD, srb2, EbS,
      SHf, nullptr, nullptr, nullptr, nullptr, nullptr, nullptr, nullptr);
  head_dot_k<<<CS / 4, 256, 0, stream>>>(SHf, sow, sob, hlog);
  head_lse_k<<<1, 1024, 0, stream>>>(hlog, hlse);

  // trans chain
  gemm64<0><<<gMLP, 256, 0, stream>>>(EbT, Wall + 2 * 65536, HD, HD, trb1, nullptr,
      nullptr, Hbf, nullptr, nullptr, nullptr, nullptr, nullptr, nullptr);
  gemm64<0><<<gMLP, 256, 0, stream>>>(Hbf, Wall + 3 * 65536, HD, HD, trb2, EbT,
      nullptr, Xbf, nullptr, nullptr, nullptr, nullptr, nullptr, nullptr);

  // term chain
  gemm64<0><<<gMLP, 256, 0, stream>>>(EbP, Wall + 4 * 65536, HD, HD, teb1, nullptr,
      nullptr, Hbf, nullptr, nullptr, nullptr, nullptr, nullptr, nullptr);
  gemm64<0><<<gMLP, 256, 0, stream>>>(Hbf, Wall + 5 * 65536, HD, HD, teb2, EbP,
      nullptr, PHb, nullptr, nullptr, nullptr, nullptr, nullptr, nullptr);

  // transition row-logsumexp: 256x256 tiles + reduce
  rlse_k<<<1024, 512, 0, stream>>>(Xbf, NSEb, part);
  rred_k<<<CS / 256, 256, 0, stream>>>(part, rlse);

  // emission
  emis_k<<<MAXB, 256, 0, stream>>>(Wpb, PHb, tpb, offs, wlist, bmap, esum, lall);
  emit_k<<<NB * TT * 64 / 256, 256, 0, stream>>>(text, w2c, lall, esum, emitb);

  // leaves (incl. identity leaves in the same grid)
  gemm64<2><<<dim3(NB * (TT - 1) + NB), 256, 0, stream>>>(Xbf, NSEb, CS, HD, nullptr, nullptr,
      nullptr, nullptr, rlse, emitb, text, w2c, bufA, scA);

  // quad-tree product reduction: 256 -> 64 -> 16 -> 4 -> 1
  comb4_k<<<NB * 64, 256, 0, stream>>>(bufA, scA, bufB, scB, 64);
  comb4_k<<<NB * 16, 256, 0, stream>>>(bufB, scB, bufA, scA, 16);
  comb4_k<<<NB * 4, 256, 0, stream>>>(bufA, scA, bufB, scB, 4);
  comb4_k<<<NB * 1, 256, 0, stream>>>(bufB, scB, bufA, scA, 1);
  final_k<<<NB, 64, 0, stream>>>(bufA, scA, hlog, hlse, emitb, text, w2c, out);
}

// Round 7
// 240.310 us; speedup vs baseline: 2.8992x; 1.0466x over previous
//
#include <hip/hip_runtime.h>
#include <hip/hip_bf16.h>

// FactoredHmmLm forward on MI355X.
//  1. prep_k: fused weight-cvt + 4-embedding build + CSR (vectorized, 8 elem/thread)
//  2. residual MLPs via gemm64 (global_load_lds staging)
//  3. transition row-logsumexp: 256x256-tile 8-wave GEMM, 2-phase prefetch
//  4. emission: MFMA 64-word blocks + atomic exp-sum
//  5. per-(n,t) leaf matrices M_t = exp(tr + emit - m), bf16 (identity leaf folded in)
//  6. quad-tree product reduction + final

using u16 = unsigned short;
typedef __attribute__((ext_vector_type(8))) short bh8;     // 8 bf16 (4 VGPRs)
typedef __attribute__((ext_vector_type(4))) float f32x4;
typedef __attribute__((ext_vector_type(8))) unsigned short u16x8;

#define HD 256
#define TT 256
#define NB 16
#define KCL 128
#define CS 8192
#define VV 10000
#define MAXB 320
#define LOG2E 1.44269504f
#define WTOT (6 * 65536)
#define WT2  (WTOT + VV * HD)                 // 2,953,216 (mult of 2048)
#define NCVT (WT2 / 2048)                     // 1442 blocks (8 elem/thread)
#define NEMB (4 * CS * HD / 2048)             // 4096 blocks

__device__ __forceinline__ u16 f2bf(float v) {
  union { float f; unsigned int i; } u; u.f = v;
  unsigned int r = u.i + 0x7fffu + ((u.i >> 16) & 1u);   // RNE
  return (u16)(r >> 16);
}
__device__ __forceinline__ float bf2f(u16 u) {
  union { unsigned int i; float f; } x; x.i = ((unsigned int)u) << 16; return x.f;
}
__device__ __forceinline__ void gl2lds16(const u16* g, u16* l) {
  __builtin_amdgcn_global_load_lds(
      (const __attribute__((address_space(1))) unsigned int*)g,
      (__attribute__((address_space(3))) unsigned int*)l, 16, 0, 0);
}
__device__ __forceinline__ u16x8 cvt8(const float* __restrict__ s) {
  const float4 a = *reinterpret_cast<const float4*>(s);
  const float4 b = *reinterpret_cast<const float4*>(s + 4);
  u16x8 o;
  o[0] = f2bf(a.x); o[1] = f2bf(a.y); o[2] = f2bf(a.z); o[3] = f2bf(a.w);
  o[4] = f2bf(b.x); o[5] = f2bf(b.y); o[6] = f2bf(b.z); o[7] = f2bf(b.w);
  return o;
}
__device__ __forceinline__ u16x8 add_cvt8(const float* __restrict__ s0,
                                          const float* __restrict__ s1) {
  const float4 a0 = *reinterpret_cast<const float4*>(s0);
  const float4 b0 = *reinterpret_cast<const float4*>(s0 + 4);
  const float4 a1 = *reinterpret_cast<const float4*>(s1);
  const float4 b1 = *reinterpret_cast<const float4*>(s1 + 4);
  u16x8 o;
  o[0] = f2bf(a0.x + a1.x); o[1] = f2bf(a0.y + a1.y);
  o[2] = f2bf(a0.z + a1.z); o[3] = f2bf(a0.w + a1.w);
  o[4] = f2bf(b0.x + b1.x); o[5] = f2bf(b0.y + b1.y);
  o[6] = f2bf(b0.z + b1.z); o[7] = f2bf(b0.w + b1.w);
  return o;
}

// ---------------- prep: weights->bf16, embeddings, CSR (8 elem/thread) ----------------

__global__ __launch_bounds__(256) void prep_k(
    const float* __restrict__ w0, const float* __restrict__ w1,
    const float* __restrict__ w2, const float* __restrict__ w3,
    const float* __restrict__ w4, const float* __restrict__ w5,
    const float* __restrict__ tpw, u16* __restrict__ dstW,
    const float* __restrict__ ec0, const float* __restrict__ es0, u16* __restrict__ d0,
    const float* __restrict__ ec1, const float* __restrict__ es1, u16* __restrict__ d1,
    const float* __restrict__ ec2, const float* __restrict__ es2, u16* __restrict__ d2,
    const float* __restrict__ ec3, const float* __restrict__ es3, u16* __restrict__ d3,
    const int* __restrict__ w2c, int* __restrict__ offs,
    int* __restrict__ wlist, int* __restrict__ bmap) {
  const int b = blockIdx.x, tid = threadIdx.x;
  if (b < NCVT) {
    const int idx = (b * 256 + tid) * 8;      // 8 consecutive elems, same segment
    const float* src;
    if (idx < WTOT) {
      const int i = idx >> 16;
      const float* s = i == 0 ? w0 : i == 1 ? w1 : i == 2 ? w2 : i == 3 ? w3 : i == 4 ? w4 : w5;
      src = s + (idx & 65535);
    } else {
      src = tpw + (idx - WTOT);
    }
    *reinterpret_cast<u16x8*>(dstW + idx) = cvt8(src);
  } else if (b < NCVT + NEMB) {
    const int idx = ((b - NCVT) * 256 + tid) * 8;
    const int seg = idx >> 21;
    const int off = idx & ((CS * HD) - 1);
    const int h = off & 255, row = off >> 8;
    const int k = row >> 6, s = row & 63;
    const float* ec = seg == 0 ? ec0 : seg == 1 ? ec1 : seg == 2 ? ec2 : ec3;
    const float* es = seg == 0 ? es0 : seg == 1 ? es1 : seg == 2 ? es2 : es3;
    u16* d = seg == 0 ? d0 : seg == 1 ? d1 : seg == 2 ? d2 : d3;
    *reinterpret_cast<u16x8*>(d + off) = add_cvt8(ec + k * HD + h, es + s * HD + h);
  } else {
    __shared__ int cnt[KCL], cur[KCL], off_s[KCL + 1];
    if (tid < KCL) cnt[tid] = 0;
    __syncthreads();
    for (int w = tid; w < VV; w += 256) atomicAdd(&cnt[w2c[w]], 1);
    __syncthreads();
    if (tid == 0) {
      int acc = 0;
      for (int c = 0; c < KCL; ++c) { off_s[c] = acc; acc += cnt[c]; }
      off_s[KCL] = acc;
      int idx = 0;
      for (int c = 0; c < KCL; ++c) {
        const int nb = (cnt[c] + 63) >> 6;
        for (int bb = 0; bb < nb; ++bb) bmap[idx++] = (c << 8) | bb;
      }
      for (; idx < MAXB; ++idx) bmap[idx] = -1;
    }
    __syncthreads();
    if (tid < KCL) cur[tid] = off_s[tid];
    if (tid <= KCL) offs[tid] = off_s[tid];
    __syncthreads();
    for (int w = tid; w < VV; w += 256) {
      const int p = atomicAdd(&cur[w2c[w]], 1);
      wlist[p] = w;
    }
  }
}

// ---------------- transition row-lse: 256x256-tile, 8-wave, 2-phase prefetch ----------

__global__ __launch_bounds__(512) void rlse_k(const u16* __restrict__ A,
                                              const u16* __restrict__ B,
                                              float* __restrict__ part) {
  __shared__ char lds[131072];   // [2 bufs][ A 32KB | B 32KB ]
  const int tid = threadIdx.x;
  const int lane = tid & 63, w = tid >> 6;   // 8 waves
  const int wr = w >> 2, wc = w & 3;          // 2M x 4N
  const int c0 = lane & 15, g = lane >> 4;

  int bid = blockIdx.x;                        // 1024 = 32x32; %8==0 -> bijective
  bid = (bid & 7) * 128 + (bid >> 3);
  const int by = bid >> 5, bx = bid & 31;
  const int rm = by * 256, cn = bx * 256;

  f32x4 acc[8][4];
#pragma unroll
  for (int i = 0; i < 8; ++i)
#pragma unroll
    for (int j = 0; j < 4; ++j) acc[i][j] = (f32x4){0.f, 0.f, 0.f, 0.f};

  auto STAGE = [&](int kt, int hb) {
    const int kc = kt * 64;
    const int bo = hb * 65536;
#pragma unroll
    for (int q = 0; q < 4; ++q) {
      const int c = q * 512 + tid;
      const int r = c >> 3, cb = c & 7;
      const int gq = cb ^ (r & 7);
      gl2lds16(A + (size_t)(rm + r) * HD + kc + gq * 8, (u16*)&lds[bo + c * 16]);
    }
#pragma unroll
    for (int q = 0; q < 4; ++q) {
      const int c = q * 512 + tid;
      const int r = c >> 3, cb = c & 7;
      const int gq = cb ^ (r & 7);
      gl2lds16(B + (size_t)(cn + r) * HD + kc + gq * 8, (u16*)&lds[bo + 32768 + c * 16]);
    }
  };

  STAGE(0, 0);
  asm volatile("s_waitcnt vmcnt(0)" ::: "memory");
  __builtin_amdgcn_s_barrier();

  int cur = 0;
  for (int kt = 0; kt < 4; ++kt) {
    if (kt < 3) STAGE(kt + 1, cur ^ 1);
    const int bo = cur * 65536;
    __builtin_amdgcn_s_setprio(1);
#pragma unroll
    for (int kk = 0; kk < 64; kk += 32) {
      const int kb = (kk + g * 8) * 2;
      bh8 af[8], bf[4];
#pragma unroll
      for (int mi = 0; mi < 8; ++mi) {
        const int ar = wr * 128 + mi * 16 + c0;
        af[mi] = *reinterpret_cast<const bh8*>(&lds[bo + ar * 128 + (kb ^ ((ar & 7) << 4))]);
      }
#pragma unroll
      for (int nj = 0; nj < 4; ++nj) {
        const int br = wc * 64 + nj * 16 + c0;
        bf[nj] = *reinterpret_cast<const bh8*>(&lds[bo + 32768 + br * 128 + (kb ^ ((br & 7) << 4))]);
      }
#pragma unroll
      for (int mi = 0; mi < 8; ++mi)
#pragma unroll
        for (int nj = 0; nj < 4; ++nj)
          acc[mi][nj] = __builtin_amdgcn_mfma_f32_16x16x32_bf16(af[mi], bf[nj], acc[mi][nj], 0, 0, 0);
    }
    __builtin_amdgcn_s_setprio(0);
    asm volatile("s_waitcnt vmcnt(0) lgkmcnt(0)" ::: "memory");
    __builtin_amdgcn_s_barrier();
    cur ^= 1;
  }

  float rs[8][4];
#pragma unroll
  for (int mi = 0; mi < 8; ++mi)
#pragma unroll
    for (int reg = 0; reg < 4; ++reg) {
      float s = 0.f;
#pragma unroll
      for (int nj = 0; nj < 4; ++nj) s += exp2f(acc[mi][nj][reg] * LOG2E);
      rs[mi][reg] = s;
    }
#pragma unroll
  for (int off = 1; off < 16; off <<= 1)
#pragma unroll
    for (int mi = 0; mi < 8; ++mi)
#pragma unroll
      for (int reg = 0; reg < 4; ++reg)
        rs[mi][reg] += __shfl_xor(rs[mi][reg], off, 64);

  float* Lf = reinterpret_cast<float*>(lds);   // [256][4]
  if (c0 == 0) {
#pragma unroll
    for (int mi = 0; mi < 8; ++mi)
#pragma unroll
      for (int reg = 0; reg < 4; ++reg)
        Lf[(wr * 128 + mi * 16 + g * 4 + reg) * 4 + wc] = rs[mi][reg];
  }
  __syncthreads();
  if (tid < 256)
    part[(size_t)bx * CS + rm + tid] = Lf[tid * 4] + Lf[tid * 4 + 1] + Lf[tid * 4 + 2] + Lf[tid * 4 + 3];
}

__global__ void rred_k(const float* __restrict__ part, float* __restrict__ rlse) {
  const int i = blockIdx.x * 256 + threadIdx.x;
  float s = 0.f;
#pragma unroll 8
  for (int b = 0; b < 32; ++b) s += part[(size_t)b * CS + i];
  rlse[i] = logf(s);
}

// ---------------- MFMA GEMM 64x64 tile (gl2lds staging) ----------------

template<int MODE>
__global__ __launch_bounds__(256) void gemm64(
    const u16* __restrict__ A, const u16* __restrict__ B,
    int N, int K,
    const float* __restrict__ bias, const u16* __restrict__ skip,
    float* __restrict__ outf, u16* __restrict__ outbf,
    const float* __restrict__ row_lse, const float* __restrict__ emitb,
    const int* __restrict__ text, const int* __restrict__ w2c,
    u16* __restrict__ leafb, float* __restrict__ leafsc) {
  __shared__ char lds[16384];
  __shared__ float wmax[4];
  const int tid = threadIdx.x;
  const int lane = tid & 63;
  const int wid = tid >> 6;

  int rm, cn, nn = 0, ttv = 0;
  if (MODE == 2) {
    const int bi = blockIdx.x;
    if (bi >= NB * (TT - 1)) {               // identity leaf
      const int n = bi - NB * (TT - 1);
      if (n < NB) {
        u16* node = leafb + ((size_t)n * 256 + 255) * 4096;
        for (int c = tid; c < 4096; c += 256) node[c] = ((c >> 6) == (c & 63)) ? (u16)0x3F80 : (u16)0;
        if (tid == 0) leafsc[n * 256 + 255] = 0.f;
      }
      return;
    }
    nn = bi / (TT - 1);
    ttv = bi % (TT - 1) + 1;
    rm = w2c[text[nn * TT + ttv - 1]] * 64;
    cn = w2c[text[nn * TT + ttv]] * 64;
  } else {
    rm = blockIdx.y * 64;
    cn = blockIdx.x * 64;
  }
  const u16* Ag = A + (size_t)rm * K;
  const u16* Bg = B + (size_t)cn * K;

  f32x4 acc[4];
#pragma unroll
  for (int i = 0; i < 4; ++i) acc[i] = (f32x4){0.f, 0.f, 0.f, 0.f};

  const int ra = wid * 16 + (lane & 15);
  const int rb0 = lane & 15;
  const int ko = (lane >> 4) * 8;

  for (int kc = 0; kc < K; kc += 64) {
    if (kc) __syncthreads();
#pragma unroll
    for (int i = 0; i < 2; ++i) {
      const int c = i * 256 + tid;
      const int r = c >> 3, cb = c & 7;
      const int gq = cb ^ (r & 7);
      gl2lds16(Ag + (size_t)r * K + kc + gq * 8, (u16*)&lds[c * 16]);
      gl2lds16(Bg + (size_t)r * K + kc + gq * 8, (u16*)&lds[8192 + c * 16]);
    }
    __syncthreads();
#pragma unroll
    for (int kk = 0; kk < 64; kk += 32) {
      const int kb = (kk + ko) * 2;
      const bh8 af = *reinterpret_cast<const bh8*>(&lds[ra * 128 + (kb ^ ((ra & 7) << 4))]);
#pragma unroll
      for (int nj = 0; nj < 4; ++nj) {
        const int rb = nj * 16 + rb0;
        const bh8 bf = *reinterpret_cast<const bh8*>(&lds[8192 + rb * 128 + (kb ^ ((rb & 7) << 4))]);
        acc[nj] = __builtin_amdgcn_mfma_f32_16x16x32_bf16(af, bf, acc[nj], 0, 0, 0);
      }
    }
  }

  const int g = lane >> 4, c0 = lane & 15;

  if (MODE == 0) {
#pragma unroll
    for (int nj = 0; nj < 4; ++nj) {
      const int nidx = cn + nj * 16 + c0;
      const float bv = bias[nidx];
#pragma unroll
      for (int reg = 0; reg < 4; ++reg) {
        const int midx = rm + wid * 16 + g * 4 + reg;
        float v = acc[nj][reg] + bv;
        if (skip) v += bf2f(skip[(size_t)midx * 256 + nidx]);
        v = fmaxf(v, 0.f);
        if (outf) outf[(size_t)midx * N + nidx] = v;
        if (outbf) outbf[(size_t)midx * N + nidx] = f2bf(v);
      }
    }
  } else {
    float L[4][4];
    float mx = -1e30f;
#pragma unroll
    for (int nj = 0; nj < 4; ++nj) {
      const float ev = emitb[((size_t)(nn * TT + ttv)) * 64 + nj * 16 + c0];
#pragma unroll
      for (int reg = 0; reg < 4; ++reg) {
        const float l = acc[nj][reg] - row_lse[rm + wid * 16 + g * 4 + reg] + ev;
        L[nj][reg] = l;
        mx = fmaxf(mx, l);
      }
    }
#pragma unroll
    for (int off = 1; off < 64; off <<= 1) mx = fmaxf(mx, __shfl_xor(mx, off, 64));
    if (lane == 0) wmax[wid] = mx;
    __syncthreads();
    const float m = fmaxf(fmaxf(wmax[0], wmax[1]), fmaxf(wmax[2], wmax[3]));
    float* ftile = reinterpret_cast<float*>(lds);
#pragma unroll
    for (int nj = 0; nj < 4; ++nj)
#pragma unroll
      for (int reg = 0; reg < 4; ++reg)
        ftile[(wid * 16 + g * 4 + reg) * 64 + nj * 16 + c0] = exp2f((L[nj][reg] - m) * LOG2E);
    __syncthreads();
    const int leaf = ttv - 1;
    u16* node = leafb + ((size_t)nn * 256 + leaf) * 4096;
    const int rr = tid >> 2, cb = (tid & 3) * 16;
    u16x8 o0, o1;
    if ((leaf & 1) == 0) {
#pragma unroll
      for (int e = 0; e < 8; ++e) o0[e] = f2bf(ftile[rr * 64 + cb + e]);
#pragma unroll
      for (int e = 0; e < 8; ++e) o1[e] = f2bf(ftile[rr * 64 + cb + 8 + e]);
    } else {
#pragma unroll
      for (int e = 0; e < 8; ++e) o0[e] = f2bf(ftile[(cb + e) * 64 + rr]);
#pragma unroll
      for (int e = 0; e < 8; ++e) o1[e] = f2bf(ftile[(cb + 8 + e) * 64 + rr]);
    }
    *reinterpret_cast<u16x8*>(node + rr * 64 + cb) = o0;
    *reinterpret_cast<u16x8*>(node + rr * 64 + cb + 8) = o1;
    if (tid == 0) leafsc[nn * 256 + leaf] = m;
  }
}

// ---------------- quad-tree combine: out = (M0*M1)*(M2*M3) ----------------

__global__ __launch_bounds__(256) void comb4_k(const u16* __restrict__ src,
                                               const float* __restrict__ scs,
                                               u16* __restrict__ dst,
                                               float* __restrict__ scd, int U) {
  const int n = blockIdx.x / U, u = blockIdx.x % U;
  __shared__ char lds[49152];   // M0@0 M1@8K M2@16K M3@24K | P1@32K P2@40K
  __shared__ float wpm[8];
  const int tid = threadIdx.x, lane = tid & 63, w = tid >> 6;
  const u16* base = src + ((size_t)(n * 4 * U + 4 * u)) * 4096;
  const int sr = tid >> 3, scb = (tid & 7) * 16;
#pragma unroll
  for (int nd = 0; nd < 4; ++nd)
#pragma unroll
    for (int rep = 0; rep < 2; ++rep) {
      const int r = rep * 32 + sr;
      const bh8 v = *reinterpret_cast<const bh8*>(base + nd * 4096 + r * 64 + (scb >> 1));
      *reinterpret_cast<bh8*>(&lds[nd * 8192 + r * 128 + (scb ^ ((r & 7) << 4))]) = v;
    }
  __syncthreads();

  const int p = w >> 1, h = w & 1;
  const int abase = p * 16384, bbase = abase + 8192;
  const int c0 = lane & 15, g = lane >> 4;
  f32x4 a2[2][4];
#pragma unroll
  for (int mi = 0; mi < 2; ++mi)
#pragma unroll
    for (int nj = 0; nj < 4; ++nj) a2[mi][nj] = (f32x4){0.f, 0.f, 0.f, 0.f};
#pragma unroll
  for (int kk = 0; kk < 64; kk += 32) {
    const int kb = (kk + g * 8) * 2;
    bh8 af[2], bf[4];
#pragma unroll
    for (int mi = 0; mi < 2; ++mi) {
      const int ar = h * 32 + mi * 16 + c0;
      af[mi] = *reinterpret_cast<const bh8*>(&lds[abase + ar * 128 + (kb ^ ((ar & 7) << 4))]);
    }
#pragma unroll
    for (int nj = 0; nj < 4; ++nj) {
      const int br = nj * 16 + c0;
      bf[nj] = *reinterpret_cast<const bh8*>(&lds[bbase + br * 128 + (kb ^ ((br & 7) << 4))]);
    }
#pragma unroll
    for (int mi = 0; mi < 2; ++mi)
#pragma unroll
      for (int nj = 0; nj < 4; ++nj)
        a2[mi][nj] = __builtin_amdgcn_mfma_f32_16x16x32_bf16(af[mi], bf[nj], a2[mi][nj], 0, 0, 0);
  }
  float mx = 0.f;
#pragma unroll
  for (int mi = 0; mi < 2; ++mi)
#pragma unroll
    for (int nj = 0; nj < 4; ++nj)
#pragma unroll
      for (int reg = 0; reg < 4; ++reg) mx = fmaxf(mx, a2[mi][nj][reg]);
#pragma unroll
  for (int off = 1; off < 64; off <<= 1) mx = fmaxf(mx, __shfl_xor(mx, off, 64));
  if (lane == 0) wpm[w] = mx;
  __syncthreads();
  const float mp = fmaxf(wpm[p * 2], wpm[p * 2 + 1]);
  const float invp = 1.0f / mp;
#pragma unroll
  for (int mi = 0; mi < 2; ++mi)
#pragma unroll
    for (int nj = 0; nj < 4; ++nj)
#pragma unroll
      for (int reg = 0; reg < 4; ++reg) {
        const int row = h * 32 + mi * 16 + g * 4 + reg;
        const int col = nj * 16 + c0;
        const u16 val = f2bf(a2[mi][nj][reg] * invp);
        if (p == 0)
          *reinterpret_cast<u16*>(&lds[32768 + row * 128 + ((col * 2) ^ ((row & 7) << 4))]) = val;
        else
          *reinterpret_cast<u16*>(&lds[40960 + col * 128 + ((row * 2) ^ ((col & 7) << 4))]) = val;
      }
  __syncthreads();

  f32x4 acc[4];
#pragma unroll
  for (int i = 0; i < 4; ++i) acc[i] = (f32x4){0.f, 0.f, 0.f, 0.f};
  const int ra = w * 16 + c0;
#pragma unroll
  for (int kk = 0; kk < 64; kk += 32) {
    const int kb = (kk + g * 8) * 2;
    const bh8 af = *reinterpret_cast<const bh8*>(&lds[32768 + ra * 128 + (kb ^ ((ra & 7) << 4))]);
#pragma unroll
    for (int nj = 0; nj < 4; ++nj) {
      const int rb = nj * 16 + c0;
      const bh8 bf = *reinterpret_cast<const bh8*>(&lds[40960 + rb * 128 + (kb ^ ((rb & 7) << 4))]);
      acc[nj] = __builtin_amdgcn_mfma_f32_16x16x32_bf16(af, bf, acc[nj], 0, 0, 0);
    }
  }
  float mx2 = 0.f;
#pragma unroll
  for (int nj = 0; nj < 4; ++nj)
#pragma unroll
    for (int reg = 0; reg < 4; ++reg) mx2 = fmaxf(mx2, acc[nj][reg]);
#pragma unroll
  for (int off = 1; off < 64; off <<= 1) mx2 = fmaxf(mx2, __shfl_xor(mx2, off, 64));
  if (lane == 0) wpm[4 + w] = mx2;
  __syncthreads();
  const float m = fmaxf(fmaxf(wpm[4], wpm[5]), fmaxf(wpm[6], wpm[7]));
  const float inv = 1.0f / m;
  float* ftile = reinterpret_cast<float*>(lds);
#pragma unroll
  for (int nj = 0; nj < 4; ++nj)
#pragma unroll
    for (int reg = 0; reg < 4; ++reg)
      ftile[(w * 16 + g * 4 + reg) * 64 + nj * 16 + c0] = acc[nj][reg] * inv;
  __syncthreads();
  u16* node = dst + ((size_t)(n * U + u)) * 4096;
  const int rr = tid >> 2, cb = (tid & 3) * 16;
  u16x8 o0, o1;
  if ((u & 1) == 0) {
#pragma unroll
    for (int e = 0; e < 8; ++e) o0[e] = f2bf(ftile[rr * 64 + cb + e]);
#pragma unroll
    for (int e = 0; e < 8; ++e) o1[e] = f2bf(ftile[rr * 64 + cb + 8 + e]);
  } else {
#pragma unroll
    for (int e = 0; e < 8; ++e) o0[e] = f2bf(ftile[(cb + e) * 64 + rr]);
#pragma unroll
    for (int e = 0; e < 8; ++e) o1[e] = f2bf(ftile[(cb + 8 + e) * 64 + rr]);
  }
  *reinterpret_cast<u16x8*>(node + rr * 64 + cb) = o0;
  *reinterpret_cast<u16x8*>(node + rr * 64 + cb + 8) = o1;
  if (tid == 0)
    scd[n * U + u] = scs[n * 4 * U + 4 * u] + scs[n * 4 * U + 4 * u + 1]
                   + scs[n * 4 * U + 4 * u + 2] + scs[n * 4 * U + 4 * u + 3]
                   + logf(fmaxf(wpm[0], wpm[1])) + logf(fmaxf(wpm[2], wpm[3])) + logf(m);
}

// ---------------- final ----------------

__global__ __launch_bounds__(64) void final_k(const u16* __restrict__ root,
                                              const float* __restrict__ rsc,
                                              const float* __restrict__ hlog,
                                              const float* __restrict__ hlse,
                                              const float* __restrict__ emitb,
                                              const int* __restrict__ text,
                                              const int* __restrict__ w2c,
                                              float* __restrict__ out) {
  const int n = blockIdx.x, i = threadIdx.x;
  const int w0 = text[n * TT];
  float a0 = hlog[w2c[w0] * 64 + i] - hlse[0] + emitb[((size_t)(n * TT)) * 64 + i];
  float m0 = a0;
  for (int off = 32; off; off >>= 1) m0 = fmaxf(m0, __shfl_xor(m0, off, 64));
  const float lin = expf(a0 - m0);
  const u16* row = root + (size_t)n * 4096 + i * 64;
  float rs = 0.f;
#pragma unroll
  for (int e8 = 0; e8 < 8; ++e8) {
    const u16x8 v = *reinterpret_cast<const u16x8*>(row + e8 * 8);
#pragma unroll
    for (int e = 0; e < 8; ++e) rs += bf2f(v[e]);
  }
  float v = lin * rs;
  for (int off = 32; off; off >>= 1) v += __shfl_xor(v, off, 64);
  if (i == 0) out[n] = m0 + rsc[n] + logf(v);
}

// ---------------- emission GEMM ----------------

__global__ __launch_bounds__(256) void emis_k(
    const u16* __restrict__ Wpb, const u16* __restrict__ PHb,
    const float* __restrict__ bp,
    const int* __restrict__ offs, const int* __restrict__ wlist,
    const int* __restrict__ map,
    float* __restrict__ esum, float* __restrict__ logits_all) {
  const int ent = map[blockIdx.x];
  if (ent < 0) return;
  const int c = ent >> 8, blk = ent & 255;
  __shared__ char lds[16384];
  __shared__ int wid_s[64];
  const int tid = threadIdx.x, lane = tid & 63, wid = tid >> 6;
  const int st = offs[c], cnt = offs[c + 1] - st;
  if (tid < 64) {
    const int idx = blk * 64 + tid;
    wid_s[tid] = (idx < cnt) ? wlist[st + idx] : -1;
  }
  __syncthreads();

  f32x4 acc[4];
#pragma unroll
  for (int i = 0; i < 4; ++i) acc[i] = (f32x4){0.f, 0.f, 0.f, 0.f};

  const int sr = tid >> 3;
  const int scb = (tid & 7) * 16;
  const int ra = wid * 16 + (lane & 15);
  const int rb0 = lane & 15;
  const int ko = (lane >> 4) * 8;
  const u16* Bg = PHb + (size_t)(c * 64) * HD;

  for (int kc = 0; kc < HD; kc += 64) {
#pragma unroll
    for (int rep = 0; rep < 2; ++rep) {
      const int r = rep * 32 + sr;
      const int w = max(wid_s[r], 0);
      const bh8 va = *reinterpret_cast<const bh8*>(Wpb + (size_t)w * HD + kc + (scb >> 1));
      *reinterpret_cast<bh8*>(&lds[r * 128 + (scb ^ ((r & 7) << 4))]) = va;
      const bh8 vb = *reinterpret_cast<const bh8*>(Bg + r * HD + kc + (scb >> 1));
      *reinterpret_cast<bh8*>(&lds[8192 + r * 128 + (scb ^ ((r & 7) << 4))]) = vb;
    }
    __syncthreads();
#pragma unroll
    for (int kk = 0; kk < 64; kk += 32) {
      const int kb = (kk + ko) * 2;
      const bh8 af = *reinterpret_cast<const bh8*>(&lds[ra * 128 + (kb ^ ((ra & 7) << 4))]);
#pragma unroll
      for (int nj = 0; nj < 4; ++nj) {
        const int rb = nj * 16 + rb0;
        const bh8 bf = *reinterpret_cast<const bh8*>(&lds[8192 + rb * 128 + (kb ^ ((rb & 7) << 4))]);
        acc[nj] = __builtin_amdgcn_mfma_f32_16x16x32_bf16(af, bf, acc[nj], 0, 0, 0);
      }
    }
    __syncthreads();
  }

  const int g = lane >> 4, c0 = lane & 15;
#pragma unroll
  for (int nj = 0; nj < 4; ++nj) {
    float se = 0.f;
#pragma unroll
    for (int reg = 0; reg < 4; ++reg) {
      const int row = wid * 16 + g * 4 + reg;
      const int w = wid_s[row];
      if (w >= 0) {
        const float lg = acc[nj][reg] + bp[w];
        logits_all[(size_t)w * 64 + nj * 16 + c0] = lg;
        se += expf(lg);
      }
    }
    se += __shfl_xor(se, 16, 64);
    se += __shfl_xor(se, 32, 64);
    if (g == 0) atomicAdd(&esum[c * 64 + nj * 16 + c0], se);
  }
}

// ---------------- start head ----------------

__global__ __launch_bounds__(256) void head_dot_k(const float* __restrict__ sh,
                                                  const float* __restrict__ wv,
                                                  const float* __restrict__ bv,
                                                  float* __restrict__ logits) {
  const int tid = threadIdx.x, lane = tid & 63, wid = tid >> 6;
  const int row = blockIdx.x * 4 + wid;
  float s = 0.f;
#pragma unroll
  for (int q = 0; q < 4; ++q)
    s += sh[(size_t)row * HD + q * 64 + lane] * wv[q * 64 + lane];
  for (int off = 32; off; off >>= 1) s += __shfl_xor(s, off, 64);
  if (lane == 0) logits[row] = s + bv[0];
}

__global__ __launch_bounds__(1024) void head_lse_k(const float* __restrict__ logits,
                                                   float* __restrict__ out_lse) {
  __shared__ float red[16];
  __shared__ float mshared;
  const int tid = threadIdx.x;
  float m = -1e30f;
  for (int i = tid; i < CS; i += 1024) m = fmaxf(m, logits[i]);
  for (int off = 32; off; off >>= 1) m = fmaxf(m, __shfl_xor(m, off, 64));
  if ((tid & 63) == 0) red[tid >> 6] = m;
  __syncthreads();
  if (tid == 0) {
    float x = red[0];
    for (int i = 1; i < 16; ++i) x = fmaxf(x, red[i]);
    mshared = x;
  }
  __syncthreads();
  const float M = mshared;
  float s = 0.f;
  for (int i = tid; i < CS; i += 1024) s += expf(logits[i] - M);
  for (int off = 32; off; off >>= 1) s += __shfl_xor(s, off, 64);
  if ((tid & 63) == 0) red[tid >> 6] = s;
  __syncthreads();
  if (tid == 0) {
    float x = 0.f;
    for (int i = 0; i < 16; ++i) x += red[i];
    out_lse[0] = M + logf(x);
  }
}

__global__ void emit_k(const int* __restrict__ text, const int* __restrict__ w2c,
                       const float* __restrict__ lall, const float* __restrict__ esum,
                       float* __restrict__ emitb) {
  const int idx = blockIdx.x * 256 + threadIdx.x;
  const int s = idx & 63, nt = idx >> 6;
  const int w = text[nt];
  emitb[idx] = lall[(size_t)w * 64 + s] - logf(esum[w2c[w] * 64 + s]);
}

// ---------------- host orchestration ----------------

extern "C" void kernel_launch(void* const* d_in, const int* in_sizes, int n_in,
                              void* d_out, int out_size, void* d_ws, size_t ws_size,
                              hipStream_t stream) {
  (void)in_sizes; (void)n_in; (void)out_size; (void)ws_size;
  const int* text = (const int*)d_in[0];
  const int* w2c  = (const int*)d_in[1];
  const float* sec = (const float*)d_in[2];
  const float* ses = (const float*)d_in[3];
  const float* stc = (const float*)d_in[4];
  const float* sts = (const float*)d_in[5];
  const float* nec = (const float*)d_in[6];
  const float* nes = (const float*)d_in[7];
  const float* pec = (const float*)d_in[8];
  const float* pes = (const float*)d_in[9];
  const float* srw1 = (const float*)d_in[10];
  const float* srb1 = (const float*)d_in[11];
  const float* srw2 = (const float*)d_in[12];
  const float* srb2 = (const float*)d_in[13];
  const float* trw1 = (const float*)d_in[14];
  const float* trb1 = (const float*)d_in[15];
  const float* trw2 = (const float*)d_in[16];
  const float* trb2 = (const float*)d_in[17];
  const float* tew1 = (const float*)d_in[18];
  const float* teb1 = (const float*)d_in[19];
  const float* tew2 = (const float*)d_in[20];
  const float* teb2 = (const float*)d_in[21];
  const float* sow = (const float*)d_in[22];
  const float* sob = (const float*)d_in[23];
  const float* tpw = (const float*)d_in[24];
  const float* tpb = (const float*)d_in[25];
  float* out = (float*)d_out;

  char* p = (char*)d_ws;
  auto carve = [&](size_t bytes) -> char* {
    char* r = p; p += (bytes + 255) & ~(size_t)255; return r;
  };
  u16* Wall = (u16*)carve((size_t)WT2 * 2);
  u16* Wpb  = Wall + WTOT;
  u16* EbS  = (u16*)carve((size_t)CS * HD * 2);
  u16* EbT  = (u16*)carve((size_t)CS * HD * 2);
  u16* NSEb = (u16*)carve((size_t)CS * HD * 2);
  u16* EbP  = (u16*)carve((size_t)CS * HD * 2);
  u16* Hbf  = (u16*)carve((size_t)CS * HD * 2);
  float* SHf = (float*)carve((size_t)CS * HD * 4);
  u16* Xbf  = (u16*)carve((size_t)CS * HD * 2);
  u16* PHb  = (u16*)carve((size_t)CS * HD * 2);
  float* hlog  = (float*)carve(CS * 4);
  float* hlse  = (float*)carve(256);
  float* part  = (float*)carve((size_t)32 * CS * 4);
  float* rlse  = (float*)carve(CS * 4);
  int* offs    = (int*)carve((KCL + 1) * 4);
  int* wlist   = (int*)carve(VV * 4);
  int* bmap    = (int*)carve(MAXB * 4);
  float* esum  = (float*)carve(CS * 4);
  float* lall  = (float*)carve((size_t)VV * 64 * 4);
  float* emitb = (float*)carve((size_t)NB * TT * 64 * 4);
  u16*   bufA  = (u16*)carve((size_t)NB * 256 * 4096 * 2);
  u16*   bufB  = (u16*)carve((size_t)NB * 64 * 4096 * 2);
  float* scA   = (float*)carve((size_t)NB * 256 * 4);
  float* scB   = (float*)carve((size_t)NB * 256 * 4);

  hipMemsetAsync(esum, 0, CS * 4, stream);

  prep_k<<<NCVT + NEMB + 1, 256, 0, stream>>>(
      srw1, srw2, trw1, trw2, tew1, tew2, tpw, Wall,
      sec, ses, EbS, stc, sts, EbT, nec, nes, NSEb, pec, pes, EbP,
      w2c, offs, wlist, bmap);

  const dim3 gMLP(4, 128);

  // start chain
  gemm64<0><<<gMLP, 256, 0, stream>>>(EbS, Wall + 0 * 65536, HD, HD, srb1, nullptr,
      nullptr, Hbf, nullptr, nullptr, nullptr, nullptr, nullptr, nullptr);
  gemm64<0><<<gMLP, 256, 0, stream>>>(Hbf, Wall + 1 * 65536, HD, HD, srb2, EbS,
      SHf, nullptr, nullptr, nullptr, nullptr, nullptr, nullptr, nullptr);
  head_dot_k<<<CS / 4, 256, 0, stream>>>(SHf, sow, sob, hlog);
  head_lse_k<<<1, 1024, 0, stream>>>(hlog, hlse);

  // trans chain
  gemm64<0><<<gMLP, 256, 0, stream>>>(EbT, Wall + 2 * 65536, HD, HD, trb1, nullptr,
      nullptr, Hbf, nullptr, nullptr, nullptr, nullptr, nullptr, nullptr);
  gemm64<0><<<gMLP, 256, 0, stream>>>(Hbf, Wall + 3 * 65536, HD, HD, trb2, EbT,
      nullptr, Xbf, nullptr, nullptr, nullptr, nullptr, nullptr, nullptr);

  // term chain
  gemm64<0><<<gMLP, 256, 0, stream>>>(EbP, Wall + 4 * 65536, HD, HD, teb1, nullptr,
      nullptr, Hbf, nullptr, nullptr, nullptr, nullptr, nullptr, nullptr);
  gemm64<0><<<gMLP, 256, 0, stream>>>(Hbf, Wall + 5 * 65536, HD, HD, teb2, EbP,
      nullptr, PHb, nullptr, nullptr, nullptr, nullptr, nullptr, nullptr);

  // transition row-logsumexp: 256x256 tiles + reduce
  rlse_k<<<1024, 512, 0, stream>>>(Xbf, NSEb, part);
  rred_k<<<CS / 256, 256, 0, stream>>>(part, rlse);

  // emission
  emis_k<<<MAXB, 256, 0, stream>>>(Wpb, PHb, tpb, offs, wlist, bmap, esum, lall);
  emit_k<<<NB * TT * 64 / 256, 256, 0, stream>>>(text, w2c, lall, esum, emitb);

  // leaves (incl. identity leaves in the same grid)
  gemm64<2><<<dim3(NB * (TT - 1) + NB), 256, 0, stream>>>(Xbf, NSEb, CS, HD, nullptr, nullptr,
      nullptr, nullptr, rlse, emitb, text, w2c, bufA, scA);

  // quad-tree product reduction: 256 -> 64 -> 16 -> 4 -> 1
  comb4_k<<<NB * 64, 256, 0, stream>>>(bufA, scA, bufB, scB, 64);
  comb4_k<<<NB * 16, 256, 0, stream>>>(bufB, scB, bufA, scA, 16);
  comb4_k<<<NB * 4, 256, 0, stream>>>(bufA, scA, bufB, scB, 4);
  comb4_k<<<NB * 1, 256, 0, stream>>>(bufB, scB, bufA, scA, 1);
  final_k<<<NB, 64, 0, stream>>>(bufA, scA, hlog, hlse, emitb, text, w2c, out);
}

// Round 8
// 217.860 us; speedup vs baseline: 3.1979x; 1.1031x over previous
//
#include <hip/hip_runtime.h>
#include <hip/hip_bf16.h>

// FactoredHmmLm forward on MI355X.
//  1. prep_k: fused weight-cvt + 4-embedding build + CSR (8 elem/thread)
//  2. residual MLPs: batched mlp_k<1>/<2> (blockIdx.z = chain), gl2lds staging
//  3. transition row-logsumexp: 256x256-tile 8-wave GEMM, counted-vmcnt(8) pipeline
//  4. emission: MFMA 64-word blocks + atomic exp-sum
//  5. per-(n,t) leaf matrices M_t = exp(tr + emit - m), bf16 (identity leaf folded in)
//  6. quad-tree product reduction + final

using u16 = unsigned short;
typedef __attribute__((ext_vector_type(8))) short bh8;     // 8 bf16 (4 VGPRs)
typedef __attribute__((ext_vector_type(4))) float f32x4;
typedef __attribute__((ext_vector_type(8))) unsigned short u16x8;

#define HD 256
#define TT 256
#define NB 16
#define KCL 128
#define CS 8192
#define VV 10000
#define MAXB 320
#define LOG2E 1.44269504f
#define WTOT (6 * 65536)
#define WT2  (WTOT + VV * HD)                 // 2,953,216 (mult of 2048)
#define NCVT (WT2 / 2048)                     // 1442 blocks (8 elem/thread)
#define NEMB (4 * CS * HD / 2048)             // 4096 blocks

__device__ __forceinline__ u16 f2bf(float v) {
  union { float f; unsigned int i; } u; u.f = v;
  unsigned int r = u.i + 0x7fffu + ((u.i >> 16) & 1u);   // RNE
  return (u16)(r >> 16);
}
__device__ __forceinline__ float bf2f(u16 u) {
  union { unsigned int i; float f; } x; x.i = ((unsigned int)u) << 16; return x.f;
}
__device__ __forceinline__ void gl2lds16(const u16* g, u16* l) {
  __builtin_amdgcn_global_load_lds(
      (const __attribute__((address_space(1))) unsigned int*)g,
      (__attribute__((address_space(3))) unsigned int*)l, 16, 0, 0);
}
__device__ __forceinline__ u16x8 cvt8(const float* __restrict__ s) {
  const float4 a = *reinterpret_cast<const float4*>(s);
  const float4 b = *reinterpret_cast<const float4*>(s + 4);
  u16x8 o;
  o[0] = f2bf(a.x); o[1] = f2bf(a.y); o[2] = f2bf(a.z); o[3] = f2bf(a.w);
  o[4] = f2bf(b.x); o[5] = f2bf(b.y); o[6] = f2bf(b.z); o[7] = f2bf(b.w);
  return o;
}
__device__ __forceinline__ u16x8 add_cvt8(const float* __restrict__ s0,
                                          const float* __restrict__ s1) {
  const float4 a0 = *reinterpret_cast<const float4*>(s0);
  const float4 b0 = *reinterpret_cast<const float4*>(s0 + 4);
  const float4 a1 = *reinterpret_cast<const float4*>(s1);
  const float4 b1 = *reinterpret_cast<const float4*>(s1 + 4);
  u16x8 o;
  o[0] = f2bf(a0.x + a1.x); o[1] = f2bf(a0.y + a1.y);
  o[2] = f2bf(a0.z + a1.z); o[3] = f2bf(a0.w + a1.w);
  o[4] = f2bf(b0.x + b1.x); o[5] = f2bf(b0.y + b1.y);
  o[6] = f2bf(b0.z + b1.z); o[7] = f2bf(b0.w + b1.w);
  return o;
}

// ---------------- prep: weights->bf16, embeddings, CSR (8 elem/thread) ----------------

__global__ __launch_bounds__(256) void prep_k(
    const float* __restrict__ w0, const float* __restrict__ w1,
    const float* __restrict__ w2, const float* __restrict__ w3,
    const float* __restrict__ w4, const float* __restrict__ w5,
    const float* __restrict__ tpw, u16* __restrict__ dstW,
    const float* __restrict__ ec0, const float* __restrict__ es0, u16* __restrict__ d0,
    const float* __restrict__ ec1, const float* __restrict__ es1, u16* __restrict__ d1,
    const float* __restrict__ ec2, const float* __restrict__ es2, u16* __restrict__ d2,
    const float* __restrict__ ec3, const float* __restrict__ es3, u16* __restrict__ d3,
    const int* __restrict__ w2c, int* __restrict__ offs,
    int* __restrict__ wlist, int* __restrict__ bmap) {
  const int b = blockIdx.x, tid = threadIdx.x;
  if (b < NCVT) {
    const int idx = (b * 256 + tid) * 8;
    const float* src;
    if (idx < WTOT) {
      const int i = idx >> 16;
      const float* s = i == 0 ? w0 : i == 1 ? w1 : i == 2 ? w2 : i == 3 ? w3 : i == 4 ? w4 : w5;
      src = s + (idx & 65535);
    } else {
      src = tpw + (idx - WTOT);
    }
    *reinterpret_cast<u16x8*>(dstW + idx) = cvt8(src);
  } else if (b < NCVT + NEMB) {
    const int idx = ((b - NCVT) * 256 + tid) * 8;
    const int seg = idx >> 21;
    const int off = idx & ((CS * HD) - 1);
    const int h = off & 255, row = off >> 8;
    const int k = row >> 6, s = row & 63;
    const float* ec = seg == 0 ? ec0 : seg == 1 ? ec1 : seg == 2 ? ec2 : ec3;
    const float* es = seg == 0 ? es0 : seg == 1 ? es1 : seg == 2 ? es2 : es3;
    u16* d = seg == 0 ? d0 : seg == 1 ? d1 : seg == 2 ? d2 : d3;
    *reinterpret_cast<u16x8*>(d + off) = add_cvt8(ec + k * HD + h, es + s * HD + h);
  } else {
    __shared__ int cnt[KCL], cur[KCL], off_s[KCL + 1];
    if (tid < KCL) cnt[tid] = 0;
    __syncthreads();
    for (int w = tid; w < VV; w += 256) atomicAdd(&cnt[w2c[w]], 1);
    __syncthreads();
    if (tid == 0) {
      int acc = 0;
      for (int c = 0; c < KCL; ++c) { off_s[c] = acc; acc += cnt[c]; }
      off_s[KCL] = acc;
      int idx = 0;
      for (int c = 0; c < KCL; ++c) {
        const int nb = (cnt[c] + 63) >> 6;
        for (int bb = 0; bb < nb; ++bb) bmap[idx++] = (c << 8) | bb;
      }
      for (; idx < MAXB; ++idx) bmap[idx] = -1;
    }
    __syncthreads();
    if (tid < KCL) cur[tid] = off_s[tid];
    if (tid <= KCL) offs[tid] = off_s[tid];
    __syncthreads();
    for (int w = tid; w < VV; w += 256) {
      const int p = atomicAdd(&cur[w2c[w]], 1);
      wlist[p] = w;
    }
  }
}

// ---------------- batched residual-MLP GEMMs: z = chain (start/trans/term) ----------

template<int LAYER>
__global__ __launch_bounds__(256) void mlp_k(
    const u16* __restrict__ E0, const u16* __restrict__ E1, const u16* __restrict__ E2,
    u16* __restrict__ H0, u16* __restrict__ H1, u16* __restrict__ H2,
    const u16* __restrict__ Wall,
    const float* __restrict__ bb0, const float* __restrict__ bb1, const float* __restrict__ bb2,
    float* __restrict__ SHf, u16* __restrict__ Xbf, u16* __restrict__ PHb) {
  __shared__ char lds[16384];
  const int tid = threadIdx.x, lane = tid & 63, wid = tid >> 6;
  const int z = blockIdx.z;
  const u16* Eb = z == 0 ? E0 : z == 1 ? E1 : E2;
  u16* Hb = z == 0 ? H0 : z == 1 ? H1 : H2;
  const u16* A = (LAYER == 1) ? Eb : (const u16*)Hb;
  const u16* B = Wall + (size_t)(2 * z + (LAYER - 1)) * 65536;
  const float* bias = z == 0 ? bb0 : z == 1 ? bb1 : bb2;

  const int rm = blockIdx.y * 64, cn = blockIdx.x * 64;
  const u16* Ag = A + (size_t)rm * HD;
  const u16* Bg = B + (size_t)cn * HD;

  f32x4 acc[4];
#pragma unroll
  for (int i = 0; i < 4; ++i) acc[i] = (f32x4){0.f, 0.f, 0.f, 0.f};
  const int ra = wid * 16 + (lane & 15);
  const int rb0 = lane & 15;
  const int ko = (lane >> 4) * 8;

  for (int kc = 0; kc < HD; kc += 64) {
    if (kc) __syncthreads();
#pragma unroll
    for (int i = 0; i < 2; ++i) {
      const int c = i * 256 + tid;
      const int r = c >> 3, cb = c & 7;
      const int gq = cb ^ (r & 7);
      gl2lds16(Ag + (size_t)r * HD + kc + gq * 8, (u16*)&lds[c * 16]);
      gl2lds16(Bg + (size_t)r * HD + kc + gq * 8, (u16*)&lds[8192 + c * 16]);
    }
    __syncthreads();
#pragma unroll
    for (int kk = 0; kk < 64; kk += 32) {
      const int kb = (kk + ko) * 2;
      const bh8 af = *reinterpret_cast<const bh8*>(&lds[ra * 128 + (kb ^ ((ra & 7) << 4))]);
#pragma unroll
      for (int nj = 0; nj < 4; ++nj) {
        const int rb = nj * 16 + rb0;
        const bh8 bf = *reinterpret_cast<const bh8*>(&lds[8192 + rb * 128 + (kb ^ ((rb & 7) << 4))]);
        acc[nj] = __builtin_amdgcn_mfma_f32_16x16x32_bf16(af, bf, acc[nj], 0, 0, 0);
      }
    }
  }

  const int g = lane >> 4, c0 = lane & 15;
#pragma unroll
  for (int nj = 0; nj < 4; ++nj) {
    const int nidx = cn + nj * 16 + c0;
    const float bv = bias[nidx];
#pragma unroll
    for (int reg = 0; reg < 4; ++reg) {
      const int midx = rm + wid * 16 + g * 4 + reg;
      float v = acc[nj][reg] + bv;
      if (LAYER == 2) v += bf2f(Eb[(size_t)midx * 256 + nidx]);
      v = fmaxf(v, 0.f);
      if (LAYER == 1) {
        Hb[(size_t)midx * 256 + nidx] = f2bf(v);
      } else {
        if (z == 0) SHf[(size_t)midx * 256 + nidx] = v;
        else if (z == 1) Xbf[(size_t)midx * 256 + nidx] = f2bf(v);
        else PHb[(size_t)midx * 256 + nidx] = f2bf(v);
      }
    }
  }
}

// ---------------- transition row-lse: 256x256-tile, 8-wave, counted-vmcnt pipeline -------

__global__ __launch_bounds__(512) void rlse_k(const u16* __restrict__ A,
                                              const u16* __restrict__ B,
                                              float* __restrict__ part) {
  __shared__ char lds[131072];   // [2 bufs][ A 32KB | B 32KB ]
  const int tid = threadIdx.x;
  const int lane = tid & 63, w = tid >> 6;   // 8 waves
  const int wr = w >> 2, wc = w & 3;          // 2M x 4N
  const int c0 = lane & 15, g = lane >> 4;

  int bid = blockIdx.x;                        // 1024 = 32x32; %8==0 -> bijective
  bid = (bid & 7) * 128 + (bid >> 3);
  const int by = bid >> 5, bx = bid & 31;
  const int rm = by * 256, cn = bx * 256;

  f32x4 acc[8][4];
#pragma unroll
  for (int i = 0; i < 8; ++i)
#pragma unroll
    for (int j = 0; j < 4; ++j) acc[i][j] = (f32x4){0.f, 0.f, 0.f, 0.f};

  // 8 gl2lds per thread per STAGE (4 A + 4 B) -> vmcnt counts 8 per tile per wave
  auto STAGE = [&](int kt, int hb) {
    const int kc = kt * 64;
    const int bo = hb * 65536;
#pragma unroll
    for (int q = 0; q < 4; ++q) {
      const int c = q * 512 + tid;
      const int r = c >> 3, cb = c & 7;
      const int gq = cb ^ (r & 7);
      gl2lds16(A + (size_t)(rm + r) * HD + kc + gq * 8, (u16*)&lds[bo + c * 16]);
    }
#pragma unroll
    for (int q = 0; q < 4; ++q) {
      const int c = q * 512 + tid;
      const int r = c >> 3, cb = c & 7;
      const int gq = cb ^ (r & 7);
      gl2lds16(B + (size_t)(cn + r) * HD + kc + gq * 8, (u16*)&lds[bo + 32768 + c * 16]);
    }
  };

  STAGE(0, 0);
  STAGE(1, 1);

  int cur = 0;
  for (int kt = 0; kt < 4; ++kt) {
    // wait ONLY for tile kt; the newest 8 prefetch ops stay in flight (T4)
    if (kt < 3) asm volatile("s_waitcnt vmcnt(8)" ::: "memory");
    else        asm volatile("s_waitcnt vmcnt(0)" ::: "memory");
    __builtin_amdgcn_sched_barrier(0);
    __builtin_amdgcn_s_barrier();
    const int bo = cur * 65536;
    __builtin_amdgcn_s_setprio(1);
#pragma unroll
    for (int kk = 0; kk < 64; kk += 32) {
      const int kb = (kk + g * 8) * 2;
      bh8 af[8], bf[4];
#pragma unroll
      for (int mi = 0; mi < 8; ++mi) {
        const int ar = wr * 128 + mi * 16 + c0;
        af[mi] = *reinterpret_cast<const bh8*>(&lds[bo + ar * 128 + (kb ^ ((ar & 7) << 4))]);
      }
#pragma unroll
      for (int nj = 0; nj < 4; ++nj) {
        const int br = wc * 64 + nj * 16 + c0;
        bf[nj] = *reinterpret_cast<const bh8*>(&lds[bo + 32768 + br * 128 + (kb ^ ((br & 7) << 4))]);
      }
#pragma unroll
      for (int mi = 0; mi < 8; ++mi)
#pragma unroll
        for (int nj = 0; nj < 4; ++nj)
          acc[mi][nj] = __builtin_amdgcn_mfma_f32_16x16x32_bf16(af[mi], bf[nj], acc[mi][nj], 0, 0, 0);
    }
    __builtin_amdgcn_s_setprio(0);
    __builtin_amdgcn_s_barrier();            // all waves done reading buf cur
    __builtin_amdgcn_sched_barrier(0);
    if (kt < 2) STAGE(kt + 2, cur);          // refill the freed buffer
    cur ^= 1;
  }

  float rs[8][4];
#pragma unroll
  for (int mi = 0; mi < 8; ++mi)
#pragma unroll
    for (int reg = 0; reg < 4; ++reg) {
      float s = 0.f;
#pragma unroll
      for (int nj = 0; nj < 4; ++nj) s += exp2f(acc[mi][nj][reg] * LOG2E);
      rs[mi][reg] = s;
    }
#pragma unroll
  for (int off = 1; off < 16; off <<= 1)
#pragma unroll
    for (int mi = 0; mi < 8; ++mi)
#pragma unroll
      for (int reg = 0; reg < 4; ++reg)
        rs[mi][reg] += __shfl_xor(rs[mi][reg], off, 64);

  float* Lf = reinterpret_cast<float*>(lds);   // [256][4]
  if (c0 == 0) {
#pragma unroll
    for (int mi = 0; mi < 8; ++mi)
#pragma unroll
      for (int reg = 0; reg < 4; ++reg)
        Lf[(wr * 128 + mi * 16 + g * 4 + reg) * 4 + wc] = rs[mi][reg];
  }
  __syncthreads();
  if (tid < 256)
    part[(size_t)bx * CS + rm + tid] = Lf[tid * 4] + Lf[tid * 4 + 1] + Lf[tid * 4 + 2] + Lf[tid * 4 + 3];
}

__global__ void rred_k(const float* __restrict__ part, float* __restrict__ rlse) {
  const int i = blockIdx.x * 256 + threadIdx.x;
  float s = 0.f;
#pragma unroll 8
  for (int b = 0; b < 32; ++b) s += part[(size_t)b * CS + i];
  rlse[i] = logf(s);
}

// ---------------- leaf-gen GEMM 64x64 tile (gl2lds staging) ----------------

__global__ __launch_bounds__(256) void leaf_k(
    const u16* __restrict__ A, const u16* __restrict__ B,
    const float* __restrict__ row_lse, const float* __restrict__ emitb,
    const int* __restrict__ text, const int* __restrict__ w2c,
    u16* __restrict__ leafb, float* __restrict__ leafsc) {
  __shared__ char lds[16384];
  __shared__ float wmax[4];
  const int tid = threadIdx.x;
  const int lane = tid & 63;
  const int wid = tid >> 6;

  const int bi = blockIdx.x;
  if (bi >= NB * (TT - 1)) {               // identity leaf
    const int n = bi - NB * (TT - 1);
    if (n < NB) {
      u16* node = leafb + ((size_t)n * 256 + 255) * 4096;
      for (int c = tid; c < 4096; c += 256) node[c] = ((c >> 6) == (c & 63)) ? (u16)0x3F80 : (u16)0;
      if (tid == 0) leafsc[n * 256 + 255] = 0.f;
    }
    return;
  }
  const int nn = bi / (TT - 1);
  const int ttv = bi % (TT - 1) + 1;
  const int rm = w2c[text[nn * TT + ttv - 1]] * 64;
  const int cn = w2c[text[nn * TT + ttv]] * 64;
  const u16* Ag = A + (size_t)rm * HD;
  const u16* Bg = B + (size_t)cn * HD;

  f32x4 acc[4];
#pragma unroll
  for (int i = 0; i < 4; ++i) acc[i] = (f32x4){0.f, 0.f, 0.f, 0.f};
  const int ra = wid * 16 + (lane & 15);
  const int rb0 = lane & 15;
  const int ko = (lane >> 4) * 8;

  for (int kc = 0; kc < HD; kc += 64) {
    if (kc) __syncthreads();
#pragma unroll
    for (int i = 0; i < 2; ++i) {
      const int c = i * 256 + tid;
      const int r = c >> 3, cb = c & 7;
      const int gq = cb ^ (r & 7);
      gl2lds16(Ag + (size_t)r * HD + kc + gq * 8, (u16*)&lds[c * 16]);
      gl2lds16(Bg + (size_t)r * HD + kc + gq * 8, (u16*)&lds[8192 + c * 16]);
    }
    __syncthreads();
#pragma unroll
    for (int kk = 0; kk < 64; kk += 32) {
      const int kb = (kk + ko) * 2;
      const bh8 af = *reinterpret_cast<const bh8*>(&lds[ra * 128 + (kb ^ ((ra & 7) << 4))]);
#pragma unroll
      for (int nj = 0; nj < 4; ++nj) {
        const int rb = nj * 16 + rb0;
        const bh8 bf = *reinterpret_cast<const bh8*>(&lds[8192 + rb * 128 + (kb ^ ((rb & 7) << 4))]);
        acc[nj] = __builtin_amdgcn_mfma_f32_16x16x32_bf16(af, bf, acc[nj], 0, 0, 0);
      }
    }
  }

  const int g = lane >> 4, c0 = lane & 15;
  float L[4][4];
  float mx = -1e30f;
#pragma unroll
  for (int nj = 0; nj < 4; ++nj) {
    const float ev = emitb[((size_t)(nn * TT + ttv)) * 64 + nj * 16 + c0];
#pragma unroll
    for (int reg = 0; reg < 4; ++reg) {
      const float l = acc[nj][reg] - row_lse[rm + wid * 16 + g * 4 + reg] + ev;
      L[nj][reg] = l;
      mx = fmaxf(mx, l);
    }
  }
#pragma unroll
  for (int off = 1; off < 64; off <<= 1) mx = fmaxf(mx, __shfl_xor(mx, off, 64));
  if (lane == 0) wmax[wid] = mx;
  __syncthreads();
  const float m = fmaxf(fmaxf(wmax[0], wmax[1]), fmaxf(wmax[2], wmax[3]));
  float* ftile = reinterpret_cast<float*>(lds);
#pragma unroll
  for (int nj = 0; nj < 4; ++nj)
#pragma unroll
    for (int reg = 0; reg < 4; ++reg)
      ftile[(wid * 16 + g * 4 + reg) * 64 + nj * 16 + c0] = exp2f((L[nj][reg] - m) * LOG2E);
  __syncthreads();
  const int leaf = ttv - 1;
  u16* node = leafb + ((size_t)nn * 256 + leaf) * 4096;
  const int rr = tid >> 2, cb = (tid & 3) * 16;
  u16x8 o0, o1;
  if ((leaf & 1) == 0) {
#pragma unroll
    for (int e = 0; e < 8; ++e) o0[e] = f2bf(ftile[rr * 64 + cb + e]);
#pragma unroll
    for (int e = 0; e < 8; ++e) o1[e] = f2bf(ftile[rr * 64 + cb + 8 + e]);
  } else {
#pragma unroll
    for (int e = 0; e < 8; ++e) o0[e] = f2bf(ftile[(cb + e) * 64 + rr]);
#pragma unroll
    for (int e = 0; e < 8; ++e) o1[e] = f2bf(ftile[(cb + 8 + e) * 64 + rr]);
  }
  *reinterpret_cast<u16x8*>(node + rr * 64 + cb) = o0;
  *reinterpret_cast<u16x8*>(node + rr * 64 + cb + 8) = o1;
  if (tid == 0) leafsc[nn * 256 + leaf] = m;
}

// ---------------- quad-tree combine: out = (M0*M1)*(M2*M3) ----------------

__global__ __launch_bounds__(256) void comb4_k(const u16* __restrict__ src,
                                               const float* __restrict__ scs,
                                               u16* __restrict__ dst,
                                               float* __restrict__ scd, int U) {
  const int n = blockIdx.x / U, u = blockIdx.x % U;
  __shared__ char lds[49152];   // M0@0 M1@8K M2@16K M3@24K | P1@32K P2@40K
  __shared__ float wpm[8];
  const int tid = threadIdx.x, lane = tid & 63, w = tid >> 6;
  const u16* base = src + ((size_t)(n * 4 * U + 4 * u)) * 4096;
  const int sr = tid >> 3, scb = (tid & 7) * 16;
#pragma unroll
  for (int nd = 0; nd < 4; ++nd)
#pragma unroll
    for (int rep = 0; rep < 2; ++rep) {
      const int r = rep * 32 + sr;
      const bh8 v = *reinterpret_cast<const bh8*>(base + nd * 4096 + r * 64 + (scb >> 1));
      *reinterpret_cast<bh8*>(&lds[nd * 8192 + r * 128 + (scb ^ ((r & 7) << 4))]) = v;
    }
  __syncthreads();

  const int p = w >> 1, h = w & 1;
  const int abase = p * 16384, bbase = abase + 8192;
  const int c0 = lane & 15, g = lane >> 4;
  f32x4 a2[2][4];
#pragma unroll
  for (int mi = 0; mi < 2; ++mi)
#pragma unroll
    for (int nj = 0; nj < 4; ++nj) a2[mi][nj] = (f32x4){0.f, 0.f, 0.f, 0.f};
#pragma unroll
  for (int kk = 0; kk < 64; kk += 32) {
    const int kb = (kk + g * 8) * 2;
    bh8 af[2], bf[4];
#pragma unroll
    for (int mi = 0; mi < 2; ++mi) {
      const int ar = h * 32 + mi * 16 + c0;
      af[mi] = *reinterpret_cast<const bh8*>(&lds[abase + ar * 128 + (kb ^ ((ar & 7) << 4))]);
    }
#pragma unroll
    for (int nj = 0; nj < 4; ++nj) {
      const int br = nj * 16 + c0;
      bf[nj] = *reinterpret_cast<const bh8*>(&lds[bbase + br * 128 + (kb ^ ((br & 7) << 4))]);
    }
#pragma unroll
    for (int mi = 0; mi < 2; ++mi)
#pragma unroll
      for (int nj = 0; nj < 4; ++nj)
        a2[mi][nj] = __builtin_amdgcn_mfma_f32_16x16x32_bf16(af[mi], bf[nj], a2[mi][nj], 0, 0, 0);
  }
  float mx = 0.f;
#pragma unroll
  for (int mi = 0; mi < 2; ++mi)
#pragma unroll
    for (int nj = 0; nj < 4; ++nj)
#pragma unroll
      for (int reg = 0; reg < 4; ++reg) mx = fmaxf(mx, a2[mi][nj][reg]);
#pragma unroll
  for (int off = 1; off < 64; off <<= 1) mx = fmaxf(mx, __shfl_xor(mx, off, 64));
  if (lane == 0) wpm[w] = mx;
  __syncthreads();
  const float mp = fmaxf(wpm[p * 2], wpm[p * 2 + 1]);
  const float invp = 1.0f / mp;
#pragma unroll
  for (int mi = 0; mi < 2; ++mi)
#pragma unroll
    for (int nj = 0; nj < 4; ++nj)
#pragma unroll
      for (int reg = 0; reg < 4; ++reg) {
        const int row = h * 32 + mi * 16 + g * 4 + reg;
        const int col = nj * 16 + c0;
        const u16 val = f2bf(a2[mi][nj][reg] * invp);
        if (p == 0)
          *reinterpret_cast<u16*>(&lds[32768 + row * 128 + ((col * 2) ^ ((row & 7) << 4))]) = val;
        else
          *reinterpret_cast<u16*>(&lds[40960 + col * 128 + ((row * 2) ^ ((col & 7) << 4))]) = val;
      }
  __syncthreads();

  f32x4 acc[4];
#pragma unroll
  for (int i = 0; i < 4; ++i) acc[i] = (f32x4){0.f, 0.f, 0.f, 0.f};
  const int ra = w * 16 + c0;
#pragma unroll
  for (int kk = 0; kk < 64; kk += 32) {
    const int kb = (kk + g * 8) * 2;
    const bh8 af = *reinterpret_cast<const bh8*>(&lds[32768 + ra * 128 + (kb ^ ((ra & 7) << 4))]);
#pragma unroll
    for (int nj = 0; nj < 4; ++nj) {
      const int rb = nj * 16 + c0;
      const bh8 bf = *reinterpret_cast<const bh8*>(&lds[40960 + rb * 128 + (kb ^ ((rb & 7) << 4))]);
      acc[nj] = __builtin_amdgcn_mfma_f32_16x16x32_bf16(af, bf, acc[nj], 0, 0, 0);
    }
  }
  float mx2 = 0.f;
#pragma unroll
  for (int nj = 0; nj < 4; ++nj)
#pragma unroll
    for (int reg = 0; reg < 4; ++reg) mx2 = fmaxf(mx2, acc[nj][reg]);
#pragma unroll
  for (int off = 1; off < 64; off <<= 1) mx2 = fmaxf(mx2, __shfl_xor(mx2, off, 64));
  if (lane == 0) wpm[4 + w] = mx2;
  __syncthreads();
  const float m = fmaxf(fmaxf(wpm[4], wpm[5]), fmaxf(wpm[6], wpm[7]));
  const float inv = 1.0f / m;
  float* ftile = reinterpret_cast<float*>(lds);
#pragma unroll
  for (int nj = 0; nj < 4; ++nj)
#pragma unroll
    for (int reg = 0; reg < 4; ++reg)
      ftile[(w * 16 + g * 4 + reg) * 64 + nj * 16 + c0] = acc[nj][reg] * inv;
  __syncthreads();
  u16* node = dst + ((size_t)(n * U + u)) * 4096;
  const int rr = tid >> 2, cb = (tid & 3) * 16;
  u16x8 o0, o1;
  if ((u & 1) == 0) {
#pragma unroll
    for (int e = 0; e < 8; ++e) o0[e] = f2bf(ftile[rr * 64 + cb + e]);
#pragma unroll
    for (int e = 0; e < 8; ++e) o1[e] = f2bf(ftile[rr * 64 + cb + 8 + e]);
  } else {
#pragma unroll
    for (int e = 0; e < 8; ++e) o0[e] = f2bf(ftile[(cb + e) * 64 + rr]);
#pragma unroll
    for (int e = 0; e < 8; ++e) o1[e] = f2bf(ftile[(cb + 8 + e) * 64 + rr]);
  }
  *reinterpret_cast<u16x8*>(node + rr * 64 + cb) = o0;
  *reinterpret_cast<u16x8*>(node + rr * 64 + cb + 8) = o1;
  if (tid == 0)
    scd[n * U + u] = scs[n * 4 * U + 4 * u] + scs[n * 4 * U + 4 * u + 1]
                   + scs[n * 4 * U + 4 * u + 2] + scs[n * 4 * U + 4 * u + 3]
                   + logf(fmaxf(wpm[0], wpm[1])) + logf(fmaxf(wpm[2], wpm[3])) + logf(m);
}

// ---------------- final ----------------

__global__ __launch_bounds__(64) void final_k(const u16* __restrict__ root,
                                              const float* __restrict__ rsc,
                                              const float* __restrict__ hlog,
                                              const float* __restrict__ hlse,
                                              const float* __restrict__ emitb,
                                              const int* __restrict__ text,
                                              const int* __restrict__ w2c,
                                              float* __restrict__ out) {
  const int n = blockIdx.x, i = threadIdx.x;
  const int w0 = text[n * TT];
  float a0 = hlog[w2c[w0] * 64 + i] - hlse[0] + emitb[((size_t)(n * TT)) * 64 + i];
  float m0 = a0;
  for (int off = 32; off; off >>= 1) m0 = fmaxf(m0, __shfl_xor(m0, off, 64));
  const float lin = expf(a0 - m0);
  const u16* row = root + (size_t)n * 4096 + i * 64;
  float rs = 0.f;
#pragma unroll
  for (int e8 = 0; e8 < 8; ++e8) {
    const u16x8 v = *reinterpret_cast<const u16x8*>(row + e8 * 8);
#pragma unroll
    for (int e = 0; e < 8; ++e) rs += bf2f(v[e]);
  }
  float v = lin * rs;
  for (int off = 32; off; off >>= 1) v += __shfl_xor(v, off, 64);
  if (i == 0) out[n] = m0 + rsc[n] + logf(v);
}

// ---------------- emission GEMM ----------------

__global__ __launch_bounds__(256) void emis_k(
    const u16* __restrict__ Wpb, const u16* __restrict__ PHb,
    const float* __restrict__ bp,
    const int* __restrict__ offs, const int* __restrict__ wlist,
    const int* __restrict__ map,
    float* __restrict__ esum, float* __restrict__ logits_all) {
  const int ent = map[blockIdx.x];
  if (ent < 0) return;
  const int c = ent >> 8, blk = ent & 255;
  __shared__ char lds[16384];
  __shared__ int wid_s[64];
  const int tid = threadIdx.x, lane = tid & 63, wid = tid >> 6;
  const int st = offs[c], cnt = offs[c + 1] - st;
  if (tid < 64) {
    const int idx = blk * 64 + tid;
    wid_s[tid] = (idx < cnt) ? wlist[st + idx] : -1;
  }
  __syncthreads();

  f32x4 acc[4];
#pragma unroll
  for (int i = 0; i < 4; ++i) acc[i] = (f32x4){0.f, 0.f, 0.f, 0.f};

  const int sr = tid >> 3;
  const int scb = (tid & 7) * 16;
  const int ra = wid * 16 + (lane & 15);
  const int rb0 = lane & 15;
  const int ko = (lane >> 4) * 8;
  const u16* Bg = PHb + (size_t)(c * 64) * HD;

  for (int kc = 0; kc < HD; kc += 64) {
#pragma unroll
    for (int rep = 0; rep < 2; ++rep) {
      const int r = rep * 32 + sr;
      const int w = max(wid_s[r], 0);
      const bh8 va = *reinterpret_cast<const bh8*>(Wpb + (size_t)w * HD + kc + (scb >> 1));
      *reinterpret_cast<bh8*>(&lds[r * 128 + (scb ^ ((r & 7) << 4))]) = va;
      const bh8 vb = *reinterpret_cast<const bh8*>(Bg + r * HD + kc + (scb >> 1));
      *reinterpret_cast<bh8*>(&lds[8192 + r * 128 + (scb ^ ((r & 7) << 4))]) = vb;
    }
    __syncthreads();
#pragma unroll
    for (int kk = 0; kk < 64; kk += 32) {
      const int kb = (kk + ko) * 2;
      const bh8 af = *reinterpret_cast<const bh8*>(&lds[ra * 128 + (kb ^ ((ra & 7) << 4))]);
#pragma unroll
      for (int nj = 0; nj < 4; ++nj) {
        const int rb = nj * 16 + rb0;
        const bh8 bf = *reinterpret_cast<const bh8*>(&lds[8192 + rb * 128 + (kb ^ ((rb & 7) << 4))]);
        acc[nj] = __builtin_amdgcn_mfma_f32_16x16x32_bf16(af, bf, acc[nj], 0, 0, 0);
      }
    }
    __syncthreads();
  }

  const int g = lane >> 4, c0 = lane & 15;
#pragma unroll
  for (int nj = 0; nj < 4; ++nj) {
    float se = 0.f;
#pragma unroll
    for (int reg = 0; reg < 4; ++reg) {
      const int row = wid * 16 + g * 4 + reg;
      const int w = wid_s[row];
      if (w >= 0) {
        const float lg = acc[nj][reg] + bp[w];
        logits_all[(size_t)w * 64 + nj * 16 + c0] = lg;
        se += expf(lg);
      }
    }
    se += __shfl_xor(se, 16, 64);
    se += __shfl_xor(se, 32, 64);
    if (g == 0) atomicAdd(&esum[c * 64 + nj * 16 + c0], se);
  }
}

// ---------------- start head ----------------

__global__ __launch_bounds__(256) void head_dot_k(const float* __restrict__ sh,
                                                  const float* __restrict__ wv,
                                                  const float* __restrict__ bv,
                                                  float* __restrict__ logits) {
  const int tid = threadIdx.x, lane = tid & 63, wid = tid >> 6;
  const int row = blockIdx.x * 4 + wid;
  float s = 0.f;
#pragma unroll
  for (int q = 0; q < 4; ++q)
    s += sh[(size_t)row * HD + q * 64 + lane] * wv[q * 64 + lane];
  for (int off = 32; off; off >>= 1) s += __shfl_xor(s, off, 64);
  if (lane == 0) logits[row] = s + bv[0];
}

__global__ __launch_bounds__(1024) void head_lse_k(const float* __restrict__ logits,
                                                   float* __restrict__ out_lse) {
  __shared__ float red[16];
  __shared__ float mshared;
  const int tid = threadIdx.x;
  float m = -1e30f;
  for (int i = tid; i < CS; i += 1024) m = fmaxf(m, logits[i]);
  for (int off = 32; off; off >>= 1) m = fmaxf(m, __shfl_xor(m, off, 64));
  if ((tid & 63) == 0) red[tid >> 6] = m;
  __syncthreads();
  if (tid == 0) {
    float x = red[0];
    for (int i = 1; i < 16; ++i) x = fmaxf(x, red[i]);
    mshared = x;
  }
  __syncthreads();
  const float M = mshared;
  float s = 0.f;
  for (int i = tid; i < CS; i += 1024) s += expf(logits[i] - M);
  for (int off = 32; off; off >>= 1) s += __shfl_xor(s, off, 64);
  if ((tid & 63) == 0) red[tid >> 6] = s;
  __syncthreads();
  if (tid == 0) {
    float x = 0.f;
    for (int i = 0; i < 16; ++i) x += red[i];
    out_lse[0] = M + logf(x);
  }
}

__global__ void emit_k(const int* __restrict__ text, const int* __restrict__ w2c,
                       const float* __restrict__ lall, const float* __restrict__ esum,
                       float* __restrict__ emitb) {
  const int idx = blockIdx.x * 256 + threadIdx.x;
  const int s = idx & 63, nt = idx >> 6;
  const int w = text[nt];
  emitb[idx] = lall[(size_t)w * 64 + s] - logf(esum[w2c[w] * 64 + s]);
}

// ---------------- host orchestration ----------------

extern "C" void kernel_launch(void* const* d_in, const int* in_sizes, int n_in,
                              void* d_out, int out_size, void* d_ws, size_t ws_size,
                              hipStream_t stream) {
  (void)in_sizes; (void)n_in; (void)out_size; (void)ws_size;
  const int* text = (const int*)d_in[0];
  const int* w2c  = (const int*)d_in[1];
  const float* sec = (const float*)d_in[2];
  const float* ses = (const float*)d_in[3];
  const float* stc = (const float*)d_in[4];
  const float* sts = (const float*)d_in[5];
  const float* nec = (const float*)d_in[6];
  const float* nes = (const float*)d_in[7];
  const float* pec = (const float*)d_in[8];
  const float* pes = (const float*)d_in[9];
  const float* srw1 = (const float*)d_in[10];
  const float* srb1 = (const float*)d_in[11];
  const float* srw2 = (const float*)d_in[12];
  const float* srb2 = (const float*)d_in[13];
  const float* trw1 = (const float*)d_in[14];
  const float* trb1 = (const float*)d_in[15];
  const float* trw2 = (const float*)d_in[16];
  const float* trb2 = (const float*)d_in[17];
  const float* tew1 = (const float*)d_in[18];
  const float* teb1 = (const float*)d_in[19];
  const float* tew2 = (const float*)d_in[20];
  const float* teb2 = (const float*)d_in[21];
  const float* sow = (const float*)d_in[22];
  const float* sob = (const float*)d_in[23];
  const float* tpw = (const float*)d_in[24];
  const float* tpb = (const float*)d_in[25];
  float* out = (float*)d_out;

  char* p = (char*)d_ws;
  auto carve = [&](size_t bytes) -> char* {
    char* r = p; p += (bytes + 255) & ~(size_t)255; return r;
  };
  u16* Wall = (u16*)carve((size_t)WT2 * 2);
  u16* Wpb  = Wall + WTOT;
  u16* EbS  = (u16*)carve((size_t)CS * HD * 2);
  u16* EbT  = (u16*)carve((size_t)CS * HD * 2);
  u16* NSEb = (u16*)carve((size_t)CS * HD * 2);
  u16* EbP  = (u16*)carve((size_t)CS * HD * 2);
  u16* Hb0  = (u16*)carve((size_t)CS * HD * 2);
  u16* Hb1  = (u16*)carve((size_t)CS * HD * 2);
  u16* Hb2  = (u16*)carve((size_t)CS * HD * 2);
  float* SHf = (float*)carve((size_t)CS * HD * 4);
  u16* Xbf  = (u16*)carve((size_t)CS * HD * 2);
  u16* PHb  = (u16*)carve((size_t)CS * HD * 2);
  float* hlog  = (float*)carve(CS * 4);
  float* hlse  = (float*)carve(256);
  float* part  = (float*)carve((size_t)32 * CS * 4);
  float* rlse  = (float*)carve(CS * 4);
  int* offs    = (int*)carve((KCL + 1) * 4);
  int* wlist   = (int*)carve(VV * 4);
  int* bmap    = (int*)carve(MAXB * 4);
  float* esum  = (float*)carve(CS * 4);
  float* lall  = (float*)carve((size_t)VV * 64 * 4);
  float* emitb = (float*)carve((size_t)NB * TT * 64 * 4);
  u16*   bufA  = (u16*)carve((size_t)NB * 256 * 4096 * 2);
  u16*   bufB  = (u16*)carve((size_t)NB * 64 * 4096 * 2);
  float* scA   = (float*)carve((size_t)NB * 256 * 4);
  float* scB   = (float*)carve((size_t)NB * 256 * 4);

  hipMemsetAsync(esum, 0, CS * 4, stream);

  prep_k<<<NCVT + NEMB + 1, 256, 0, stream>>>(
      srw1, srw2, trw1, trw2, tew1, tew2, tpw, Wall,
      sec, ses, EbS, stc, sts, EbT, nec, nes, NSEb, pec, pes, EbP,
      w2c, offs, wlist, bmap);

  // batched residual MLPs (z = start/trans/term)
  mlp_k<1><<<dim3(4, 128, 3), 256, 0, stream>>>(
      EbS, EbT, EbP, Hb0, Hb1, Hb2, Wall, srb1, trb1, teb1, nullptr, nullptr, nullptr);
  mlp_k<2><<<dim3(4, 128, 3), 256, 0, stream>>>(
      EbS, EbT, EbP, Hb0, Hb1, Hb2, Wall, srb2, trb2, teb2, SHf, Xbf, PHb);

  head_dot_k<<<CS / 4, 256, 0, stream>>>(SHf, sow, sob, hlog);
  head_lse_k<<<1, 1024, 0, stream>>>(hlog, hlse);

  // transition row-logsumexp: 256x256 tiles + reduce
  rlse_k<<<1024, 512, 0, stream>>>(Xbf, NSEb, part);
  rred_k<<<CS / 256, 256, 0, stream>>>(part, rlse);

  // emission
  emis_k<<<MAXB, 256, 0, stream>>>(Wpb, PHb, tpb, offs, wlist, bmap, esum, lall);
  emit_k<<<NB * TT * 64 / 256, 256, 0, stream>>>(text, w2c, lall, esum, emitb);

  // leaves (incl. identity leaves in the same grid)
  leaf_k<<<dim3(NB * (TT - 1) + NB), 256, 0, stream>>>(
      Xbf, NSEb, rlse, emitb, text, w2c, bufA, scA);

  // quad-tree product reduction: 256 -> 64 -> 16 -> 4 -> 1
  comb4_k<<<NB * 64, 256, 0, stream>>>(bufA, scA, bufB, scB, 64);
  comb4_k<<<NB * 16, 256, 0, stream>>>(bufB, scB, bufA, scA, 16);
  comb4_k<<<NB * 4, 256, 0, stream>>>(bufA, scA, bufB, scB, 4);
  comb4_k<<<NB * 1, 256, 0, stream>>>(bufB, scB, bufA, scA, 1);
  final_k<<<NB, 64, 0, stream>>>(bufA, scA, hlog, hlse, emitb, text, w2c, out);
}